// Round 1
// baseline (1891.673 us; speedup 1.0000x reference)
//
#include <hip/hip_runtime.h>
#include <math.h>

// GAT 2-layer: N=100000, E=1600000 (+N self loops), F_IN=128, HID=64, HEADS=2,
// OUT_HEADS=1, NUM_CLASS=18, NEG_SLOPE=0.2
// Round 0: correctness-first implementation. Edge softmax via atomic max/sum,
// aggregation via scattered atomicAdd.

#define NEG_SLOPE 0.2f

// ---- monotonic float<->uint encoding for atomicMax on floats ----
__device__ __forceinline__ unsigned fenc(float x) {
    unsigned b = __float_as_uint(x);
    return (b & 0x80000000u) ? ~b : (b | 0x80000000u);
}
__device__ __forceinline__ float fdec(unsigned k) {
    return __uint_as_float((k & 0x80000000u) ? (k ^ 0x80000000u) : ~k);
}
#define ENC_NEG_INF 0x007FFFFFu  // fenc(-inf)

// ---- init: zero accumulators, set running-max to -inf ----
__global__ void k_init(float* __restrict__ agg1, float* __restrict__ out2,
                       unsigned* __restrict__ m1, float* __restrict__ den1,
                       unsigned* __restrict__ m2, float* __restrict__ den2, int N) {
    int i = blockIdx.x * blockDim.x + threadIdx.x;
    if (i < N * 128) agg1[i] = 0.f;
    if (i < N * 18) out2[i] = 0.f;
    if (i < N * 2) { m1[i] = ENC_NEG_INF; den1[i] = 0.f; }
    if (i < N)     { m2[i] = ENC_NEG_INF; den2[i] = 0.f; }
}

// ---- h0 = relu(x @ W0 + b0); x[N,128], W0[128,64] ----
__global__ __launch_bounds__(256) void k_gemm1(const float* __restrict__ x,
                                               const float* __restrict__ W0,
                                               const float* __restrict__ b0,
                                               float* __restrict__ h0, int N) {
    __shared__ float w[128 * 64];
    for (int i = threadIdx.x; i < 128 * 64; i += 256) w[i] = W0[i];
    __syncthreads();
    int m = threadIdx.x & 63;
    int n = blockIdx.x * 4 + (threadIdx.x >> 6);
    if (n >= N) return;
    const float* xr = x + (size_t)n * 128;
    float acc = 0.f;
#pragma unroll 8
    for (int k = 0; k < 128; ++k) acc += xr[k] * w[k * 64 + m];
    acc += b0[m];
    h0[(size_t)n * 64 + m] = fmaxf(acc, 0.f);
}

// ---- h1 = h0 @ W1; h0[N,64], W1[64,128] ----
__global__ __launch_bounds__(256) void k_gemm2(const float* __restrict__ h0,
                                               const float* __restrict__ W1,
                                               float* __restrict__ h1, int N) {
    __shared__ float w[64 * 128];
    for (int i = threadIdx.x; i < 64 * 128; i += 256) w[i] = W1[i];
    __syncthreads();
    int m = threadIdx.x & 127;
    int n = blockIdx.x * 2 + (threadIdx.x >> 7);
    if (n >= N) return;
    const float* xr = h0 + (size_t)n * 64;
    float acc = 0.f;
#pragma unroll 8
    for (int k = 0; k < 64; ++k) acc += xr[k] * w[k * 128 + m];
    h1[(size_t)n * 128 + m] = acc;
}

// ---- per-node attention logits, layer 1: a_s[n,h], a_d[n,h] ----
__global__ void k_att1(const float* __restrict__ h1, const float* __restrict__ ws_g,
                       const float* __restrict__ wd_g, float* __restrict__ a_s,
                       float* __restrict__ a_d, int N) {
    int i = blockIdx.x * blockDim.x + threadIdx.x;  // i = n*2 + h
    if (i >= N * 2) return;
    int h = i & 1, n = i >> 1;
    const float* row = h1 + (size_t)n * 128 + h * 64;
    const float* ws = ws_g + h * 64;
    const float* wd = wd_g + h * 64;
    float s = 0.f, d = 0.f;
#pragma unroll 8
    for (int c = 0; c < 64; ++c) { float v = row[c]; s += v * ws[c]; d += v * wd[c]; }
    a_s[i] = s;
    a_d[i] = d;
}

// ---- edge pass 1a: e = leaky_relu(a_s[src]+a_d[dst]); running max per dst ----
__global__ void k_edge1_max(const int* __restrict__ ei, const float* __restrict__ a_s,
                            const float* __restrict__ a_d, float* __restrict__ e_out,
                            unsigned* __restrict__ m1, int E, int Etot) {
    int e = blockIdx.x * blockDim.x + threadIdx.x;
    if (e >= Etot) return;
    int src, dst;
    if (e < E) { src = ei[e]; dst = ei[E + e]; } else { src = dst = e - E; }
    float e0 = a_s[src * 2] + a_d[dst * 2];
    float e1 = a_s[src * 2 + 1] + a_d[dst * 2 + 1];
    e0 = e0 > 0.f ? e0 : NEG_SLOPE * e0;
    e1 = e1 > 0.f ? e1 : NEG_SLOPE * e1;
    e_out[(size_t)e * 2] = e0;
    e_out[(size_t)e * 2 + 1] = e1;
    atomicMax(&m1[dst * 2], fenc(e0));
    atomicMax(&m1[dst * 2 + 1], fenc(e1));
}

// ---- edge pass 1b: ex = exp(e - m[dst]); denom[dst] += ex ----
__global__ void k_edge1_expsum(const int* __restrict__ ei, float* __restrict__ e_buf,
                               const unsigned* __restrict__ m1, float* __restrict__ den1,
                               int E, int Etot) {
    int e = blockIdx.x * blockDim.x + threadIdx.x;
    if (e >= Etot) return;
    int dst = (e < E) ? ei[E + e] : (e - E);
    float ex0 = expf(e_buf[(size_t)e * 2] - fdec(m1[dst * 2]));
    float ex1 = expf(e_buf[(size_t)e * 2 + 1] - fdec(m1[dst * 2 + 1]));
    e_buf[(size_t)e * 2] = ex0;
    e_buf[(size_t)e * 2 + 1] = ex1;
    atomicAdd(&den1[dst * 2], ex0);
    atomicAdd(&den1[dst * 2 + 1], ex1);
}

// ---- edge pass 1c: agg[dst,f] += h1[src,f] * alpha(e, f/64) ----
__global__ __launch_bounds__(256) void k_edge1_agg(const int* __restrict__ ei,
                                                   const float* __restrict__ h1,
                                                   const float* __restrict__ ex,
                                                   const float* __restrict__ den,
                                                   float* __restrict__ agg,
                                                   int E, int Etot) {
    int t = blockIdx.x * 256 + threadIdx.x;
    int e = t >> 7;
    int f = t & 127;
    if (e >= Etot) return;
    int src, dst;
    if (e < E) { src = ei[e]; dst = ei[E + e]; } else { src = dst = e - E; }
    int h = f >> 6;
    float alpha = ex[(size_t)e * 2 + h] / den[dst * 2 + h];
    atomicAdd(&agg[(size_t)dst * 128 + f], h1[(size_t)src * 128 + f] * alpha);
}

// ---- bias + ELU in place ----
__global__ void k_bias_elu(float* __restrict__ agg, const float* __restrict__ b1, int N) {
    int i = blockIdx.x * blockDim.x + threadIdx.x;
    if (i >= N * 128) return;
    float v = agg[i] + b1[i & 127];
    agg[i] = v > 0.f ? v : expm1f(v);
}

// ---- h2 = h1act @ W2 (no bias), plus per-node attention dots for layer 2 ----
__global__ __launch_bounds__(256) void k_node2(const float* __restrict__ h1a,
                                               const float* __restrict__ W2,
                                               const float* __restrict__ ws_g,
                                               const float* __restrict__ wd_g,
                                               float* __restrict__ h2,
                                               float* __restrict__ a_s,
                                               float* __restrict__ a_d, int N) {
    __shared__ float w[128 * 18];
    __shared__ float ws[18], wd[18];
    for (int i = threadIdx.x; i < 128 * 18; i += 256) w[i] = W2[i];
    if (threadIdx.x < 18) { ws[threadIdx.x] = ws_g[threadIdx.x]; wd[threadIdx.x] = wd_g[threadIdx.x]; }
    __syncthreads();
    int n = blockIdx.x * 256 + threadIdx.x;
    if (n >= N) return;
    const float* row = h1a + (size_t)n * 128;
    float acc[18];
#pragma unroll
    for (int c = 0; c < 18; ++c) acc[c] = 0.f;
    for (int k = 0; k < 128; ++k) {
        float v = row[k];
#pragma unroll
        for (int c = 0; c < 18; ++c) acc[c] += v * w[k * 18 + c];
    }
    float s = 0.f, d = 0.f;
#pragma unroll
    for (int c = 0; c < 18; ++c) {
        h2[(size_t)n * 18 + c] = acc[c];
        s += acc[c] * ws[c];
        d += acc[c] * wd[c];
    }
    a_s[n] = s;
    a_d[n] = d;
}

// ---- edge pass 2a ----
__global__ void k_edge2_max(const int* __restrict__ ei, const float* __restrict__ a_s,
                            const float* __restrict__ a_d, float* __restrict__ e_out,
                            unsigned* __restrict__ m2, int E, int Etot) {
    int e = blockIdx.x * blockDim.x + threadIdx.x;
    if (e >= Etot) return;
    int src, dst;
    if (e < E) { src = ei[e]; dst = ei[E + e]; } else { src = dst = e - E; }
    float v = a_s[src] + a_d[dst];
    v = v > 0.f ? v : NEG_SLOPE * v;
    e_out[e] = v;
    atomicMax(&m2[dst], fenc(v));
}

// ---- edge pass 2b ----
__global__ void k_edge2_expsum(const int* __restrict__ ei, float* __restrict__ e_buf,
                               const unsigned* __restrict__ m2, float* __restrict__ den2,
                               int E, int Etot) {
    int e = blockIdx.x * blockDim.x + threadIdx.x;
    if (e >= Etot) return;
    int dst = (e < E) ? ei[E + e] : (e - E);
    float ex = expf(e_buf[e] - fdec(m2[dst]));
    e_buf[e] = ex;
    atomicAdd(&den2[dst], ex);
}

// ---- edge pass 2c: out[dst,c] += h2[src,c] * alpha ----
__global__ __launch_bounds__(256) void k_edge2_agg(const int* __restrict__ ei,
                                                   const float* __restrict__ h2,
                                                   const float* __restrict__ ex,
                                                   const float* __restrict__ den,
                                                   float* __restrict__ out,
                                                   int E, int Etot) {
    int t = blockIdx.x * 256 + threadIdx.x;
    int e = t >> 5;
    int c = t & 31;
    if (e >= Etot || c >= 18) return;
    int src, dst;
    if (e < E) { src = ei[e]; dst = ei[E + e]; } else { src = dst = e - E; }
    float alpha = ex[e] / den[dst];
    atomicAdd(&out[(size_t)dst * 18 + c], h2[(size_t)src * 18 + c] * alpha);
}

// ---- final: add b2, log_softmax over 18 classes, in place in d_out ----
__global__ void k_logsoftmax(float* __restrict__ out, const float* __restrict__ b2, int N) {
    int n = blockIdx.x * blockDim.x + threadIdx.x;
    if (n >= N) return;
    float v[18];
    float mx = -INFINITY;
#pragma unroll
    for (int c = 0; c < 18; ++c) {
        v[c] = out[(size_t)n * 18 + c] + b2[c];
        mx = fmaxf(mx, v[c]);
    }
    float s = 0.f;
#pragma unroll
    for (int c = 0; c < 18; ++c) s += expf(v[c] - mx);
    float lse = mx + logf(s);
#pragma unroll
    for (int c = 0; c < 18; ++c) out[(size_t)n * 18 + c] = v[c] - lse;
}

extern "C" void kernel_launch(void* const* d_in, const int* in_sizes, int n_in,
                              void* d_out, int out_size, void* d_ws, size_t ws_size,
                              hipStream_t stream) {
    const float* x      = (const float*)d_in[0];
    const int*   ei     = (const int*)d_in[1];
    const float* W0     = (const float*)d_in[2];
    const float* b0     = (const float*)d_in[3];
    const float* W1     = (const float*)d_in[4];
    const float* att_s1 = (const float*)d_in[5];
    const float* att_d1 = (const float*)d_in[6];
    const float* b1     = (const float*)d_in[7];
    const float* W2     = (const float*)d_in[8];
    const float* att_s2 = (const float*)d_in[9];
    const float* att_d2 = (const float*)d_in[10];
    const float* b2     = (const float*)d_in[11];

    const int N = in_sizes[0] / 128;
    const int E = in_sizes[1] / 2;
    const int Etot = E + N;

    // workspace carve-up (~160 MB total)
    char* w = (char*)d_ws;
    float* h0 = (float*)w;      w += (size_t)N * 64 * 4;
    float* h1 = (float*)w;      w += (size_t)N * 128 * 4;
    float* as1 = (float*)w;     w += (size_t)N * 2 * 4;
    float* ad1 = (float*)w;     w += (size_t)N * 2 * 4;
    unsigned* m1 = (unsigned*)w; w += (size_t)N * 2 * 4;
    float* den1 = (float*)w;    w += (size_t)N * 2 * 4;
    float* ex1 = (float*)w;     w += (size_t)Etot * 2 * 4;
    float* agg1 = (float*)w;    w += (size_t)N * 128 * 4;
    float* h2 = (float*)w;      w += (size_t)N * 18 * 4;
    float* as2 = (float*)w;     w += (size_t)N * 4;
    float* ad2 = (float*)w;     w += (size_t)N * 4;
    unsigned* m2 = (unsigned*)w; w += (size_t)N * 4;
    float* den2 = (float*)w;    w += (size_t)N * 4;
    float* ex2 = (float*)w;     w += (size_t)Etot * 4;

    float* out = (float*)d_out;

    k_init<<<(N * 128 + 255) / 256, 256, 0, stream>>>(agg1, out, m1, den1, m2, den2, N);

    k_gemm1<<<(N + 3) / 4, 256, 0, stream>>>(x, W0, b0, h0, N);
    k_gemm2<<<(N + 1) / 2, 256, 0, stream>>>(h0, W1, h1, N);
    k_att1<<<(N * 2 + 255) / 256, 256, 0, stream>>>(h1, att_s1, att_d1, as1, ad1, N);

    k_edge1_max<<<(Etot + 255) / 256, 256, 0, stream>>>(ei, as1, ad1, ex1, m1, E, Etot);
    k_edge1_expsum<<<(Etot + 255) / 256, 256, 0, stream>>>(ei, ex1, m1, den1, E, Etot);
    k_edge1_agg<<<(Etot * 128 + 255) / 256, 256, 0, stream>>>(ei, h1, ex1, den1, agg1, E, Etot);

    k_bias_elu<<<(N * 128 + 255) / 256, 256, 0, stream>>>(agg1, b1, N);

    k_node2<<<(N + 255) / 256, 256, 0, stream>>>(agg1, W2, att_s2, att_d2, h2, as2, ad2, N);

    k_edge2_max<<<(Etot + 255) / 256, 256, 0, stream>>>(ei, as2, ad2, ex2, m2, E, Etot);
    k_edge2_expsum<<<(Etot + 255) / 256, 256, 0, stream>>>(ei, ex2, m2, den2, E, Etot);
    k_edge2_agg<<<((Etot * 32) + 255) / 256, 256, 0, stream>>>(ei, h2, ex2, den2, out, E, Etot);

    k_logsoftmax<<<(N + 255) / 256, 256, 0, stream>>>(out, b2, N);
}

// Round 2
// 956.250 us; speedup vs baseline: 1.9782x; 1.9782x over previous
//
#include <hip/hip_runtime.h>
#include <math.h>

// GAT 2-layer: N=100000, E=1600000 (+N self loops), F_IN=128, HID=64, HEADS=2,
// OUT_HEADS=1, NUM_CLASS=18, NEG_SLOPE=0.2
// Round 1: CSR-by-dst build per call, then gather-based fused softmax+agg
// (one wave per node, online softmax). Eliminates the 850MB atomicAdd
// write-through that dominated round 0.

#define NEG_SLOPE 0.2f

// ---------------- wave reductions (64 lanes) ----------------
__device__ __forceinline__ float wmax(float v) {
    for (int o = 32; o; o >>= 1) v = fmaxf(v, __shfl_xor(v, o));
    return v;
}
__device__ __forceinline__ float wsum(float v) {
    for (int o = 32; o; o >>= 1) v += __shfl_xor(v, o);
    return v;
}

// ---------------- CSR build ----------------
__global__ void k_deg_init(int* __restrict__ deg, int N) {
    int i = blockIdx.x * blockDim.x + threadIdx.x;
    if (i < N) deg[i] = 1;  // self loop
}
__global__ void k_deg_edges(const int* __restrict__ ei, int* __restrict__ deg, int E) {
    int e = blockIdx.x * blockDim.x + threadIdx.x;
    if (e < E) atomicAdd(&deg[ei[E + e]], 1);
}

// block-scan: each block handles 1024 elems (256 thr x 4)
__global__ __launch_bounds__(256) void k_scan1(const int* __restrict__ deg, int* __restrict__ rs,
                                               int* __restrict__ bsum, int N) {
    __shared__ int s[256];
    int t = threadIdx.x;
    int base = blockIdx.x * 1024;
    int i0 = base + t * 4;
    int d0 = (i0 + 0 < N) ? deg[i0 + 0] : 0;
    int d1 = (i0 + 1 < N) ? deg[i0 + 1] : 0;
    int d2 = (i0 + 2 < N) ? deg[i0 + 2] : 0;
    int d3 = (i0 + 3 < N) ? deg[i0 + 3] : 0;
    int s0 = d0, s1 = s0 + d1, s2 = s1 + d2, s3 = s2 + d3;
    int tsum = s3;
    s[t] = tsum;
    __syncthreads();
    for (int off = 1; off < 256; off <<= 1) {
        int v = (t >= off) ? s[t - off] : 0;
        __syncthreads();
        s[t] += v;
        __syncthreads();
    }
    int excl = s[t] - tsum;
    if (i0 + 0 < N) rs[1 + i0 + 0] = excl + s0;
    if (i0 + 1 < N) rs[1 + i0 + 1] = excl + s1;
    if (i0 + 2 < N) rs[1 + i0 + 2] = excl + s2;
    if (i0 + 3 < N) rs[1 + i0 + 3] = excl + s3;
    if (t == 0) bsum[blockIdx.x] = s[255];
}

__global__ __launch_bounds__(256) void k_scan2(const int* __restrict__ bsum,
                                               int* __restrict__ boff, int NB) {
    __shared__ int s[256];
    int t = threadIdx.x;
    int orig = (t < NB) ? bsum[t] : 0;
    s[t] = orig;
    __syncthreads();
    for (int off = 1; off < 256; off <<= 1) {
        int v = (t >= off) ? s[t - off] : 0;
        __syncthreads();
        s[t] += v;
        __syncthreads();
    }
    if (t < NB) boff[t] = s[t] - orig;  // exclusive
}

__global__ void k_scan3(int* __restrict__ rs, const int* __restrict__ boff, int N) {
    int i = blockIdx.x * blockDim.x + threadIdx.x;
    if (i == 0) rs[0] = 0;
    if (i < N) rs[1 + i] += boff[i >> 10];
}

__global__ void k_cursor(const int* __restrict__ rs, int* __restrict__ cur, int N) {
    int i = blockIdx.x * blockDim.x + threadIdx.x;
    if (i < N) cur[i] = rs[i];
}

__global__ void k_scatter(const int* __restrict__ ei, int* __restrict__ cur,
                          int* __restrict__ csr, int E, int Etot) {
    int e = blockIdx.x * blockDim.x + threadIdx.x;
    if (e >= Etot) return;
    int src, dst;
    if (e < E) { src = ei[e]; dst = ei[E + e]; } else { src = dst = e - E; }
    int pos = atomicAdd(&cur[dst], 1);
    csr[pos] = src;
}

// ---------------- dense node kernels ----------------
// h0 = relu(x @ W0 + b0); x[N,128], W0[128,64]
__global__ __launch_bounds__(256) void k_gemm1(const float* __restrict__ x,
                                               const float* __restrict__ W0,
                                               const float* __restrict__ b0,
                                               float* __restrict__ h0, int N) {
    __shared__ float w[128 * 64];
    for (int i = threadIdx.x; i < 128 * 64; i += 256) w[i] = W0[i];
    __syncthreads();
    int m = threadIdx.x & 63;
    int n = blockIdx.x * 4 + (threadIdx.x >> 6);
    if (n >= N) return;
    const float* xr = x + (size_t)n * 128;
    float acc = 0.f;
#pragma unroll 8
    for (int k = 0; k < 128; ++k) acc += xr[k] * w[k * 64 + m];
    acc += b0[m];
    h0[(size_t)n * 64 + m] = fmaxf(acc, 0.f);
}

// h1 = h0 @ W1; h0[N,64], W1[64,128]
__global__ __launch_bounds__(256) void k_gemm2(const float* __restrict__ h0,
                                               const float* __restrict__ W1,
                                               float* __restrict__ h1, int N) {
    __shared__ float w[64 * 128];
    for (int i = threadIdx.x; i < 64 * 128; i += 256) w[i] = W1[i];
    __syncthreads();
    int m = threadIdx.x & 127;
    int n = blockIdx.x * 2 + (threadIdx.x >> 7);
    if (n >= N) return;
    const float* xr = h0 + (size_t)n * 64;
    float acc = 0.f;
#pragma unroll 8
    for (int k = 0; k < 64; ++k) acc += xr[k] * w[k * 128 + m];
    h1[(size_t)n * 128 + m] = acc;
}

// per-node attention logits, layer 1: a_s[n*2+h], a_d[n*2+h]
__global__ void k_att1(const float* __restrict__ h1, const float* __restrict__ ws_g,
                       const float* __restrict__ wd_g, float* __restrict__ a_s,
                       float* __restrict__ a_d, int N) {
    int i = blockIdx.x * blockDim.x + threadIdx.x;  // i = n*2 + h
    if (i >= N * 2) return;
    int h = i & 1, n = i >> 1;
    const float* row = h1 + (size_t)n * 128 + h * 64;
    const float* ws = ws_g + h * 64;
    const float* wd = wd_g + h * 64;
    float s = 0.f, d = 0.f;
#pragma unroll 8
    for (int c = 0; c < 64; ++c) { float v = row[c]; s += v * ws[c]; d += v * wd[c]; }
    a_s[i] = s;
    a_d[i] = d;
}

// ---- layer-1 fused: per-node online softmax + aggregation + bias + ELU ----
// one wave per node; lane covers features (2*lane, 2*lane+1); head = lane>=32
__global__ __launch_bounds__(256) void k_node_l1(const int* __restrict__ rs,
                                                 const int* __restrict__ csr,
                                                 const float* __restrict__ h1,
                                                 const float* __restrict__ as1,
                                                 const float* __restrict__ ad1,
                                                 const float* __restrict__ b1,
                                                 float* __restrict__ agg, int N) {
    int lane = threadIdx.x & 63;
    int n = (blockIdx.x * 256 + threadIdx.x) >> 6;
    if (n >= N) return;
    int row = rs[n], end = rs[n + 1];
    float2 adv = ((const float2*)ad1)[n];
    const float2* asp = (const float2*)as1;
    bool head1 = lane >= 32;
    float m0 = -INFINITY, m1 = -INFINITY, l0 = 0.f, l1 = 0.f;
    float accx = 0.f, accy = 0.f;
    for (int base = row; base < end; base += 64) {
        int idx = base + lane;
        bool act = idx < end;
        int src = act ? csr[idx] : 0;
        float2 av = asp[src];
        float e0 = av.x + adv.x, e1 = av.y + adv.y;
        e0 = e0 > 0.f ? e0 : NEG_SLOPE * e0;
        e1 = e1 > 0.f ? e1 : NEG_SLOPE * e1;
        if (!act) { e0 = -INFINITY; e1 = -INFINITY; }
        float m0n = fmaxf(m0, wmax(e0));
        float m1n = fmaxf(m1, wmax(e1));
        float r0 = __expf(m0 - m0n), r1 = __expf(m1 - m1n);
        float p0 = act ? __expf(e0 - m0n) : 0.f;
        float p1 = act ? __expf(e1 - m1n) : 0.f;
        l0 = l0 * r0 + wsum(p0);
        l1 = l1 * r1 + wsum(p1);
        float rr = head1 ? r1 : r0;
        accx *= rr; accy *= rr;
        int cnt = min(64, end - base);
#pragma unroll 4
        for (int j = 0; j < cnt; ++j) {
            int sj = __shfl(src, j);
            float a0j = __shfl(p0, j);
            float a1j = __shfl(p1, j);
            float aj = head1 ? a1j : a0j;
            float2 v = ((const float2*)(h1 + (size_t)sj * 128))[lane];
            accx += v.x * aj;
            accy += v.y * aj;
        }
        m0 = m0n; m1 = m1n;
    }
    float inv = 1.f / (head1 ? l1 : l0);
    float vx = accx * inv + b1[lane * 2];
    float vy = accy * inv + b1[lane * 2 + 1];
    vx = vx > 0.f ? vx : expm1f(vx);
    vy = vy > 0.f ? vy : expm1f(vy);
    float2 r; r.x = vx; r.y = vy;
    ((float2*)(agg + (size_t)n * 128))[lane] = r;
}

// h2 = h1act @ W2 (no bias) + per-node attention dots layer 2
__global__ __launch_bounds__(256) void k_node2(const float* __restrict__ h1a,
                                               const float* __restrict__ W2,
                                               const float* __restrict__ ws_g,
                                               const float* __restrict__ wd_g,
                                               float* __restrict__ h2,
                                               float* __restrict__ a_s,
                                               float* __restrict__ a_d, int N) {
    __shared__ float w[128 * 18];
    __shared__ float ws[18], wd[18];
    for (int i = threadIdx.x; i < 128 * 18; i += 256) w[i] = W2[i];
    if (threadIdx.x < 18) { ws[threadIdx.x] = ws_g[threadIdx.x]; wd[threadIdx.x] = wd_g[threadIdx.x]; }
    __syncthreads();
    int n = blockIdx.x * 256 + threadIdx.x;
    if (n >= N) return;
    const float* row = h1a + (size_t)n * 128;
    float acc[18];
#pragma unroll
    for (int c = 0; c < 18; ++c) acc[c] = 0.f;
    for (int k = 0; k < 128; ++k) {
        float v = row[k];
#pragma unroll
        for (int c = 0; c < 18; ++c) acc[c] += v * w[k * 18 + c];
    }
    float s = 0.f, d = 0.f;
#pragma unroll
    for (int c = 0; c < 18; ++c) {
        h2[(size_t)n * 18 + c] = acc[c];
        s += acc[c] * ws[c];
        d += acc[c] * wd[c];
    }
    a_s[n] = s;
    a_d[n] = d;
}

// ---- layer-2 fused: per-node online softmax + agg + bias + log_softmax ----
// one wave per node; lanes parallel over edges, 18-class partials per lane.
__global__ __launch_bounds__(256) void k_node_l2(const int* __restrict__ rs,
                                                 const int* __restrict__ csr,
                                                 const float* __restrict__ h2,
                                                 const float* __restrict__ as2,
                                                 const float* __restrict__ ad2,
                                                 const float* __restrict__ b2,
                                                 float* __restrict__ out, int N) {
    int lane = threadIdx.x & 63;
    int n = (blockIdx.x * 256 + threadIdx.x) >> 6;
    if (n >= N) return;
    int row = rs[n], end = rs[n + 1];
    float adn = ad2[n];
    float m = -INFINITY, l = 0.f;
    float acc[18];
#pragma unroll
    for (int c = 0; c < 18; ++c) acc[c] = 0.f;
    for (int base = row; base < end; base += 64) {
        int idx = base + lane;
        bool act = idx < end;
        int src = act ? csr[idx] : 0;
        float e = as2[src] + adn;
        e = e > 0.f ? e : NEG_SLOPE * e;
        if (!act) e = -INFINITY;
        float mn = fmaxf(m, wmax(e));
        float r = __expf(m - mn);
        float p = act ? __expf(e - mn) : 0.f;
        l = l * r + wsum(p);
#pragma unroll
        for (int c = 0; c < 18; ++c) acc[c] *= r;
        if (act) {
            const float* hp = h2 + (size_t)src * 18;
#pragma unroll
            for (int c = 0; c < 18; ++c) acc[c] += p * hp[c];
        }
        m = mn;
    }
    for (int o = 32; o; o >>= 1) {
#pragma unroll
        for (int c = 0; c < 18; ++c) acc[c] += __shfl_xor(acc[c], o);
    }
    float inv = 1.f / l;
    float v[18];
    float mx = -INFINITY;
#pragma unroll
    for (int c = 0; c < 18; ++c) { v[c] = acc[c] * inv + b2[c]; mx = fmaxf(mx, v[c]); }
    float s = 0.f;
#pragma unroll
    for (int c = 0; c < 18; ++c) s += __expf(v[c] - mx);
    float lse = mx + __logf(s);
    if (lane == 0) {
#pragma unroll
        for (int c = 0; c < 18; ++c) out[(size_t)n * 18 + c] = v[c] - lse;
    }
}

extern "C" void kernel_launch(void* const* d_in, const int* in_sizes, int n_in,
                              void* d_out, int out_size, void* d_ws, size_t ws_size,
                              hipStream_t stream) {
    const float* x      = (const float*)d_in[0];
    const int*   ei     = (const int*)d_in[1];
    const float* W0     = (const float*)d_in[2];
    const float* b0     = (const float*)d_in[3];
    const float* W1     = (const float*)d_in[4];
    const float* att_s1 = (const float*)d_in[5];
    const float* att_d1 = (const float*)d_in[6];
    const float* b1     = (const float*)d_in[7];
    const float* W2     = (const float*)d_in[8];
    const float* att_s2 = (const float*)d_in[9];
    const float* att_d2 = (const float*)d_in[10];
    const float* b2     = (const float*)d_in[11];

    const int N = in_sizes[0] / 128;
    const int E = in_sizes[1] / 2;
    const int Etot = E + N;
    const int NB = (N + 1023) / 1024;  // scan blocks (must be <= 256)

    // workspace carve-up (~145 MB)
    char* w = (char*)d_ws;
    float* h0   = (float*)w; w += (size_t)N * 64 * 4;
    float* h1   = (float*)w; w += (size_t)N * 128 * 4;
    float* agg1 = (float*)w; w += (size_t)N * 128 * 4;
    float* as1  = (float*)w; w += (size_t)N * 2 * 4;
    float* ad1  = (float*)w; w += (size_t)N * 2 * 4;
    float* h2   = (float*)w; w += (size_t)N * 18 * 4;
    float* as2  = (float*)w; w += (size_t)N * 4;
    float* ad2  = (float*)w; w += (size_t)N * 4;
    int* deg    = (int*)w;   w += (size_t)N * 4;
    int* rs     = (int*)w;   w += (size_t)(N + 1) * 4;
    int* cur    = (int*)w;   w += (size_t)N * 4;
    int* bsum   = (int*)w;   w += (size_t)256 * 4;
    int* boff   = (int*)w;   w += (size_t)256 * 4;
    int* csr    = (int*)w;   w += (size_t)Etot * 4;

    float* out = (float*)d_out;

    // ---- CSR build ----
    k_deg_init<<<(N + 255) / 256, 256, 0, stream>>>(deg, N);
    k_deg_edges<<<(E + 255) / 256, 256, 0, stream>>>(ei, deg, E);
    k_scan1<<<NB, 256, 0, stream>>>(deg, rs, bsum, N);
    k_scan2<<<1, 256, 0, stream>>>(bsum, boff, NB);
    k_scan3<<<(N + 255) / 256, 256, 0, stream>>>(rs, boff, N);
    k_cursor<<<(N + 255) / 256, 256, 0, stream>>>(rs, cur, N);
    k_scatter<<<(Etot + 255) / 256, 256, 0, stream>>>(ei, cur, csr, E, Etot);

    // ---- dense ----
    k_gemm1<<<(N + 3) / 4, 256, 0, stream>>>(x, W0, b0, h0, N);
    k_gemm2<<<(N + 1) / 2, 256, 0, stream>>>(h0, W1, h1, N);
    k_att1<<<(N * 2 + 255) / 256, 256, 0, stream>>>(h1, att_s1, att_d1, as1, ad1, N);

    // ---- layer 1 fused edge pass ----
    k_node_l1<<<(N * 64 + 255) / 256, 256, 0, stream>>>(rs, csr, h1, as1, ad1, b1, agg1, N);

    // ---- layer 2 dense + fused edge pass ----
    k_node2<<<(N + 255) / 256, 256, 0, stream>>>(agg1, W2, att_s2, att_d2, h2, as2, ad2, N);
    k_node_l2<<<(N * 64 + 255) / 256, 256, 0, stream>>>(rs, csr, h2, as2, ad2, b2, out, N);
}

// Round 3
// 825.525 us; speedup vs baseline: 2.2915x; 1.1584x over previous
//
#include <hip/hip_runtime.h>
#include <math.h>

// GAT 2-layer: N=100000, E=1600000 (+N self loops), F_IN=128, HID=64, HEADS=2,
// OUT_HEADS=1, NUM_CLASS=18, NEG_SLOPE=0.2
// Round 2: register-tiled dense GEMMs (the R1 versions were single-output
// dependent-chain latency-bound: 189us for 1.6GF). att1 fused into gemm2
// epilogue. node2 rewritten GEMM-style with LDS staging (was uncoalesced).

#define NEG_SLOPE 0.2f

// ---------------- wave reductions (64 lanes) ----------------
__device__ __forceinline__ float wmax(float v) {
    for (int o = 32; o; o >>= 1) v = fmaxf(v, __shfl_xor(v, o));
    return v;
}
__device__ __forceinline__ float wsum(float v) {
    for (int o = 32; o; o >>= 1) v += __shfl_xor(v, o);
    return v;
}

// ---------------- CSR build ----------------
__global__ void k_deg_init(int* __restrict__ deg, int N) {
    int i = blockIdx.x * blockDim.x + threadIdx.x;
    if (i < N) deg[i] = 1;  // self loop
}
__global__ void k_deg_edges(const int* __restrict__ ei, int* __restrict__ deg, int E) {
    int e = blockIdx.x * blockDim.x + threadIdx.x;
    if (e < E) atomicAdd(&deg[ei[E + e]], 1);
}

__global__ __launch_bounds__(256) void k_scan1(const int* __restrict__ deg, int* __restrict__ rs,
                                               int* __restrict__ bsum, int N) {
    __shared__ int s[256];
    int t = threadIdx.x;
    int base = blockIdx.x * 1024;
    int i0 = base + t * 4;
    int d0 = (i0 + 0 < N) ? deg[i0 + 0] : 0;
    int d1 = (i0 + 1 < N) ? deg[i0 + 1] : 0;
    int d2 = (i0 + 2 < N) ? deg[i0 + 2] : 0;
    int d3 = (i0 + 3 < N) ? deg[i0 + 3] : 0;
    int s0 = d0, s1 = s0 + d1, s2 = s1 + d2, s3 = s2 + d3;
    int tsum = s3;
    s[t] = tsum;
    __syncthreads();
    for (int off = 1; off < 256; off <<= 1) {
        int v = (t >= off) ? s[t - off] : 0;
        __syncthreads();
        s[t] += v;
        __syncthreads();
    }
    int excl = s[t] - tsum;
    if (i0 + 0 < N) rs[1 + i0 + 0] = excl + s0;
    if (i0 + 1 < N) rs[1 + i0 + 1] = excl + s1;
    if (i0 + 2 < N) rs[1 + i0 + 2] = excl + s2;
    if (i0 + 3 < N) rs[1 + i0 + 3] = excl + s3;
    if (t == 0) bsum[blockIdx.x] = s[255];
}

__global__ __launch_bounds__(256) void k_scan2(const int* __restrict__ bsum,
                                               int* __restrict__ boff, int NB) {
    __shared__ int s[256];
    int t = threadIdx.x;
    int orig = (t < NB) ? bsum[t] : 0;
    s[t] = orig;
    __syncthreads();
    for (int off = 1; off < 256; off <<= 1) {
        int v = (t >= off) ? s[t - off] : 0;
        __syncthreads();
        s[t] += v;
        __syncthreads();
    }
    if (t < NB) boff[t] = s[t] - orig;  // exclusive
}

__global__ void k_scan3(int* __restrict__ rs, const int* __restrict__ boff, int N) {
    int i = blockIdx.x * blockDim.x + threadIdx.x;
    if (i == 0) rs[0] = 0;
    if (i < N) rs[1 + i] += boff[i >> 10];
}

__global__ void k_cursor(const int* __restrict__ rs, int* __restrict__ cur, int N) {
    int i = blockIdx.x * blockDim.x + threadIdx.x;
    if (i < N) cur[i] = rs[i];
}

__global__ void k_scatter(const int* __restrict__ ei, int* __restrict__ cur,
                          int* __restrict__ csr, int E, int Etot) {
    int e = blockIdx.x * blockDim.x + threadIdx.x;
    if (e >= Etot) return;
    int src, dst;
    if (e < E) { src = ei[e]; dst = ei[E + e]; } else { src = dst = e - E; }
    int pos = atomicAdd(&cur[dst], 1);
    csr[pos] = src;
}

// ---------------- dense kernels (register-tiled) ----------------

// h0 = relu(x @ W0 + b0); x[N,128], W0[128,64]. 64 nodes/block.
// thread: colg=t&15 (4 cols), rowg=t>>4 (4 rows) -> 16 fp32 acc.
__global__ __launch_bounds__(256) void k_gemm1(const float* __restrict__ x,
                                               const float* __restrict__ W0,
                                               const float* __restrict__ b0,
                                               float* __restrict__ h0, int N) {
    __shared__ float wl[128 * 64];   // [k][c]
    __shared__ float al[64 * 132];   // [node][k] padded
    int t = threadIdx.x;
    int n0 = blockIdx.x * 64;
    const float4* wg = (const float4*)W0;
    float4* wl4 = (float4*)wl;
#pragma unroll
    for (int i = 0; i < 8; ++i) wl4[t + i * 256] = wg[t + i * 256];
#pragma unroll
    for (int i = 0; i < 8; ++i) {
        int f = t + i * 256;
        int node = f >> 5, q = f & 31;
        int ng = n0 + node; if (ng > N - 1) ng = N - 1;
        float4 v = ((const float4*)x)[(size_t)ng * 32 + q];
        *(float4*)&al[node * 132 + q * 4] = v;
    }
    __syncthreads();
    int colg = t & 15;   // cols colg*4..+3
    int rowg = t >> 4;   // rows rowg*4..+3
    float4 acc[4];
#pragma unroll
    for (int j = 0; j < 4; ++j) acc[j] = make_float4(0.f, 0.f, 0.f, 0.f);
    for (int k4 = 0; k4 < 128; k4 += 4) {
        float4 w0 = *(float4*)&wl[(k4 + 0) * 64 + colg * 4];
        float4 w1 = *(float4*)&wl[(k4 + 1) * 64 + colg * 4];
        float4 w2 = *(float4*)&wl[(k4 + 2) * 64 + colg * 4];
        float4 w3 = *(float4*)&wl[(k4 + 3) * 64 + colg * 4];
#pragma unroll
        for (int j = 0; j < 4; ++j) {
            float4 a = *(float4*)&al[(rowg * 4 + j) * 132 + k4];
            acc[j].x += a.x * w0.x + a.y * w1.x + a.z * w2.x + a.w * w3.x;
            acc[j].y += a.x * w0.y + a.y * w1.y + a.z * w2.y + a.w * w3.y;
            acc[j].z += a.x * w0.z + a.y * w1.z + a.z * w2.z + a.w * w3.z;
            acc[j].w += a.x * w0.w + a.y * w1.w + a.z * w2.w + a.w * w3.w;
        }
    }
    float4 bb = ((const float4*)b0)[colg];
#pragma unroll
    for (int j = 0; j < 4; ++j) {
        int n = n0 + rowg * 4 + j;
        if (n < N) {
            float4 r;
            r.x = fmaxf(acc[j].x + bb.x, 0.f);
            r.y = fmaxf(acc[j].y + bb.y, 0.f);
            r.z = fmaxf(acc[j].z + bb.z, 0.f);
            r.w = fmaxf(acc[j].w + bb.w, 0.f);
            ((float4*)h0)[(size_t)n * 16 + colg] = r;
        }
    }
}

// h1 = h0 @ W1 + fused att1 dots. h0[N,64], W1[64,128]. 64 nodes/block.
// thread: colg=t&31 (4 cols), rowg=t>>5 (8 rows) -> 32 fp32 acc.
__global__ __launch_bounds__(256) void k_gemm2(const float* __restrict__ h0,
                                               const float* __restrict__ W1,
                                               const float* __restrict__ as_g,
                                               const float* __restrict__ ad_g,
                                               float* __restrict__ h1,
                                               float* __restrict__ as1,
                                               float* __restrict__ ad1, int N) {
    __shared__ float wl[64 * 128];  // [k][c]
    __shared__ float al[64 * 68];   // [node][k] padded
    int t = threadIdx.x;
    int n0 = blockIdx.x * 64;
    const float4* wg = (const float4*)W1;
    float4* wl4 = (float4*)wl;
#pragma unroll
    for (int i = 0; i < 8; ++i) wl4[t + i * 256] = wg[t + i * 256];
#pragma unroll
    for (int i = 0; i < 4; ++i) {
        int f = t + i * 256;
        int node = f >> 4, q = f & 15;
        int ng = n0 + node; if (ng > N - 1) ng = N - 1;
        float4 v = ((const float4*)h0)[(size_t)ng * 16 + q];
        *(float4*)&al[node * 68 + q * 4] = v;
    }
    __syncthreads();
    int colg = t & 31;   // cols colg*4..+3 (head = colg>=16)
    int rowg = t >> 5;   // rows rowg*8..+7
    float4 acc[8];
#pragma unroll
    for (int j = 0; j < 8; ++j) acc[j] = make_float4(0.f, 0.f, 0.f, 0.f);
    for (int k4 = 0; k4 < 64; k4 += 4) {
        float4 w0 = *(float4*)&wl[(k4 + 0) * 128 + colg * 4];
        float4 w1 = *(float4*)&wl[(k4 + 1) * 128 + colg * 4];
        float4 w2 = *(float4*)&wl[(k4 + 2) * 128 + colg * 4];
        float4 w3 = *(float4*)&wl[(k4 + 3) * 128 + colg * 4];
#pragma unroll
        for (int j = 0; j < 8; ++j) {
            float4 a = *(float4*)&al[(rowg * 8 + j) * 68 + k4];
            acc[j].x += a.x * w0.x + a.y * w1.x + a.z * w2.x + a.w * w3.x;
            acc[j].y += a.x * w0.y + a.y * w1.y + a.z * w2.y + a.w * w3.y;
            acc[j].z += a.x * w0.z + a.y * w1.z + a.z * w2.z + a.w * w3.z;
            acc[j].w += a.x * w0.w + a.y * w1.w + a.z * w2.w + a.w * w3.w;
        }
    }
    // fused attention dots: att vectors are flat [128] matching col layout
    float4 asv = ((const float4*)as_g)[colg];
    float4 adv = ((const float4*)ad_g)[colg];
    float ps[8], pd[8];
#pragma unroll
    for (int j = 0; j < 8; ++j) {
        ps[j] = acc[j].x * asv.x + acc[j].y * asv.y + acc[j].z * asv.z + acc[j].w * asv.w;
        pd[j] = acc[j].x * adv.x + acc[j].y * adv.y + acc[j].z * adv.z + acc[j].w * adv.w;
    }
    // reduce within 16-lane groups (one (rowg, head) pair per group)
    for (int o = 1; o < 16; o <<= 1) {
#pragma unroll
        for (int j = 0; j < 8; ++j) {
            ps[j] += __shfl_xor(ps[j], o);
            pd[j] += __shfl_xor(pd[j], o);
        }
    }
#pragma unroll
    for (int j = 0; j < 8; ++j) {
        int n = n0 + rowg * 8 + j;
        if (n < N) ((float4*)h1)[(size_t)n * 32 + colg] = acc[j];
    }
    int lane = t & 63;
    if ((lane & 15) == 0) {
        int head = (lane >> 4) & 1;
#pragma unroll
        for (int j = 0; j < 8; ++j) {
            int n = n0 + rowg * 8 + j;
            if (n < N) {
                as1[n * 2 + head] = ps[j];
                ad1[n * 2 + head] = pd[j];
            }
        }
    }
}

// ---- layer-1 fused: per-node online softmax + aggregation + bias + ELU ----
__global__ __launch_bounds__(256) void k_node_l1(const int* __restrict__ rs,
                                                 const int* __restrict__ csr,
                                                 const float* __restrict__ h1,
                                                 const float* __restrict__ as1,
                                                 const float* __restrict__ ad1,
                                                 const float* __restrict__ b1,
                                                 float* __restrict__ agg, int N) {
    int lane = threadIdx.x & 63;
    int n = (blockIdx.x * 256 + threadIdx.x) >> 6;
    if (n >= N) return;
    int row = rs[n], end = rs[n + 1];
    float2 adv = ((const float2*)ad1)[n];
    const float2* asp = (const float2*)as1;
    bool head1 = lane >= 32;
    float m0 = -INFINITY, m1 = -INFINITY, l0 = 0.f, l1 = 0.f;
    float accx = 0.f, accy = 0.f;
    for (int base = row; base < end; base += 64) {
        int idx = base + lane;
        bool act = idx < end;
        int src = act ? csr[idx] : 0;
        float2 av = asp[src];
        float e0 = av.x + adv.x, e1 = av.y + adv.y;
        e0 = e0 > 0.f ? e0 : NEG_SLOPE * e0;
        e1 = e1 > 0.f ? e1 : NEG_SLOPE * e1;
        if (!act) { e0 = -INFINITY; e1 = -INFINITY; }
        float m0n = fmaxf(m0, wmax(e0));
        float m1n = fmaxf(m1, wmax(e1));
        float r0 = __expf(m0 - m0n), r1 = __expf(m1 - m1n);
        float p0 = act ? __expf(e0 - m0n) : 0.f;
        float p1 = act ? __expf(e1 - m1n) : 0.f;
        l0 = l0 * r0 + wsum(p0);
        l1 = l1 * r1 + wsum(p1);
        float rr = head1 ? r1 : r0;
        accx *= rr; accy *= rr;
        int cnt = min(64, end - base);
#pragma unroll 4
        for (int j = 0; j < cnt; ++j) {
            int sj = __shfl(src, j);
            float a0j = __shfl(p0, j);
            float a1j = __shfl(p1, j);
            float aj = head1 ? a1j : a0j;
            float2 v = ((const float2*)(h1 + (size_t)sj * 128))[lane];
            accx += v.x * aj;
            accy += v.y * aj;
        }
        m0 = m0n; m1 = m1n;
    }
    float inv = 1.f / (head1 ? l1 : l0);
    float vx = accx * inv + b1[lane * 2];
    float vy = accy * inv + b1[lane * 2 + 1];
    vx = vx > 0.f ? vx : expm1f(vx);
    vy = vy > 0.f ? vy : expm1f(vy);
    float2 r; r.x = vx; r.y = vy;
    ((float2*)(agg + (size_t)n * 128))[lane] = r;
}

// h2 = h1act @ W2 + att2 dots. 64 nodes/block, 4 threads/node x 5 cols.
__global__ __launch_bounds__(256) void k_node2(const float* __restrict__ h1a,
                                               const float* __restrict__ W2,
                                               const float* __restrict__ as_g,
                                               const float* __restrict__ ad_g,
                                               float* __restrict__ h2,
                                               float* __restrict__ a_s,
                                               float* __restrict__ a_d, int N) {
    __shared__ float al[64 * 132];   // [node][k] padded
    __shared__ float w2t[20 * 132];  // [c][k] padded, cols 18,19 zero
    int t = threadIdx.x;
    int n0 = blockIdx.x * 64;
#pragma unroll
    for (int i = 0; i < 8; ++i) {
        int f = t + i * 256;
        int node = f >> 5, q = f & 31;
        int ng = n0 + node; if (ng > N - 1) ng = N - 1;
        float4 v = ((const float4*)h1a)[(size_t)ng * 32 + q];
        *(float4*)&al[node * 132 + q * 4] = v;
    }
    for (int i = t; i < 2560; i += 256) {
        int c = i >> 7, k = i & 127;
        w2t[c * 132 + k] = (c < 18) ? W2[k * 18 + c] : 0.f;
    }
    __syncthreads();
    int node = t >> 2;
    int cq = t & 3;
    int c0 = cq * 5;  // cols c0..c0+4 (cq==3: cols 15..19, 18/19 dead)
    int n = n0 + node;
    float acc[5] = {0.f, 0.f, 0.f, 0.f, 0.f};
    for (int k4 = 0; k4 < 128; k4 += 4) {
        float4 a = *(float4*)&al[node * 132 + k4];
#pragma unroll
        for (int i = 0; i < 5; ++i) {
            float4 w = *(float4*)&w2t[(c0 + i) * 132 + k4];
            acc[i] += a.x * w.x + a.y * w.y + a.z * w.z + a.w * w.w;
        }
    }
    float ps = 0.f, pd = 0.f;
#pragma unroll
    for (int i = 0; i < 5; ++i) {
        int c = c0 + i;
        float asv = (c < 18) ? as_g[c] : 0.f;
        float adv = (c < 18) ? ad_g[c] : 0.f;
        ps += acc[i] * asv;
        pd += acc[i] * adv;
    }
    ps += __shfl_xor(ps, 1); ps += __shfl_xor(ps, 2);
    pd += __shfl_xor(pd, 1); pd += __shfl_xor(pd, 2);
    if (n < N) {
#pragma unroll
        for (int i = 0; i < 5; ++i) {
            int c = c0 + i;
            if (c < 18) h2[(size_t)n * 18 + c] = acc[i];
        }
        if (cq == 0) { a_s[n] = ps; a_d[n] = pd; }
    }
}

// ---- layer-2 fused: per-node online softmax + agg + bias + log_softmax ----
__global__ __launch_bounds__(256) void k_node_l2(const int* __restrict__ rs,
                                                 const int* __restrict__ csr,
                                                 const float* __restrict__ h2,
                                                 const float* __restrict__ as2,
                                                 const float* __restrict__ ad2,
                                                 const float* __restrict__ b2,
                                                 float* __restrict__ out, int N) {
    int lane = threadIdx.x & 63;
    int n = (blockIdx.x * 256 + threadIdx.x) >> 6;
    if (n >= N) return;
    int row = rs[n], end = rs[n + 1];
    float adn = ad2[n];
    float m = -INFINITY, l = 0.f;
    float acc[18];
#pragma unroll
    for (int c = 0; c < 18; ++c) acc[c] = 0.f;
    for (int base = row; base < end; base += 64) {
        int idx = base + lane;
        bool act = idx < end;
        int src = act ? csr[idx] : 0;
        float e = as2[src] + adn;
        e = e > 0.f ? e : NEG_SLOPE * e;
        if (!act) e = -INFINITY;
        float mn = fmaxf(m, wmax(e));
        float r = __expf(m - mn);
        float p = act ? __expf(e - mn) : 0.f;
        l = l * r + wsum(p);
#pragma unroll
        for (int c = 0; c < 18; ++c) acc[c] *= r;
        if (act) {
            const float* hp = h2 + (size_t)src * 18;
#pragma unroll
            for (int c = 0; c < 18; ++c) acc[c] += p * hp[c];
        }
        m = mn;
    }
    for (int o = 32; o; o >>= 1) {
#pragma unroll
        for (int c = 0; c < 18; ++c) acc[c] += __shfl_xor(acc[c], o);
    }
    float inv = 1.f / l;
    float v[18];
    float mx = -INFINITY;
#pragma unroll
    for (int c = 0; c < 18; ++c) { v[c] = acc[c] * inv + b2[c]; mx = fmaxf(mx, v[c]); }
    float s = 0.f;
#pragma unroll
    for (int c = 0; c < 18; ++c) s += __expf(v[c] - mx);
    float lse = mx + __logf(s);
    if (lane == 0) {
#pragma unroll
        for (int c = 0; c < 18; ++c) out[(size_t)n * 18 + c] = v[c] - lse;
    }
}

extern "C" void kernel_launch(void* const* d_in, const int* in_sizes, int n_in,
                              void* d_out, int out_size, void* d_ws, size_t ws_size,
                              hipStream_t stream) {
    const float* x      = (const float*)d_in[0];
    const int*   ei     = (const int*)d_in[1];
    const float* W0     = (const float*)d_in[2];
    const float* b0     = (const float*)d_in[3];
    const float* W1     = (const float*)d_in[4];
    const float* att_s1 = (const float*)d_in[5];
    const float* att_d1 = (const float*)d_in[6];
    const float* b1     = (const float*)d_in[7];
    const float* W2     = (const float*)d_in[8];
    const float* att_s2 = (const float*)d_in[9];
    const float* att_d2 = (const float*)d_in[10];
    const float* b2     = (const float*)d_in[11];

    const int N = in_sizes[0] / 128;
    const int E = in_sizes[1] / 2;
    const int Etot = E + N;
    const int NB = (N + 1023) / 1024;  // scan blocks (<= 256)
    const int NBLK = (N + 63) / 64;    // dense tiles

    // workspace carve-up (~145 MB)
    char* w = (char*)d_ws;
    float* h0   = (float*)w; w += (size_t)N * 64 * 4;
    float* h1   = (float*)w; w += (size_t)N * 128 * 4;
    float* agg1 = (float*)w; w += (size_t)N * 128 * 4;
    float* as1  = (float*)w; w += (size_t)N * 2 * 4;
    float* ad1  = (float*)w; w += (size_t)N * 2 * 4;
    float* h2   = (float*)w; w += (size_t)N * 18 * 4;
    float* as2  = (float*)w; w += (size_t)N * 4;
    float* ad2  = (float*)w; w += (size_t)N * 4;
    int* deg    = (int*)w;   w += (size_t)N * 4;
    int* rs     = (int*)w;   w += (size_t)(N + 1) * 4;
    int* cur    = (int*)w;   w += (size_t)N * 4;
    int* bsum   = (int*)w;   w += (size_t)256 * 4;
    int* boff   = (int*)w;   w += (size_t)256 * 4;
    int* csr    = (int*)w;   w += (size_t)Etot * 4;

    float* out = (float*)d_out;

    // ---- CSR build ----
    k_deg_init<<<(N + 255) / 256, 256, 0, stream>>>(deg, N);
    k_deg_edges<<<(E + 255) / 256, 256, 0, stream>>>(ei, deg, E);
    k_scan1<<<NB, 256, 0, stream>>>(deg, rs, bsum, N);
    k_scan2<<<1, 256, 0, stream>>>(bsum, boff, NB);
    k_scan3<<<(N + 255) / 256, 256, 0, stream>>>(rs, boff, N);
    k_cursor<<<(N + 255) / 256, 256, 0, stream>>>(rs, cur, N);
    k_scatter<<<(Etot + 255) / 256, 256, 0, stream>>>(ei, cur, csr, E, Etot);

    // ---- dense ----
    k_gemm1<<<NBLK, 256, 0, stream>>>(x, W0, b0, h0, N);
    k_gemm2<<<NBLK, 256, 0, stream>>>(h0, W1, att_s1, att_d1, h1, as1, ad1, N);

    // ---- layer 1 fused edge pass ----
    k_node_l1<<<(N * 64 + 255) / 256, 256, 0, stream>>>(rs, csr, h1, as1, ad1, b1, agg1, N);

    // ---- layer 2 dense + fused edge pass ----
    k_node2<<<NBLK, 256, 0, stream>>>(agg1, W2, att_s2, att_d2, h2, as2, ad2, N);
    k_node_l2<<<(N * 64 + 255) / 256, 256, 0, stream>>>(rs, csr, h2, as2, ad2, b2, out, N);
}

// Round 4
// 667.011 us; speedup vs baseline: 2.8360x; 1.2376x over previous
//
#include <hip/hip_runtime.h>
#include <math.h>

// GAT 2-layer: N=100000, E=1600000 (+N self loops), F_IN=128, HID=64, HEADS=2,
// OUT_HEADS=1, NUM_CLASS=18, NEG_SLOPE=0.2
// Round 3: k_node2 was spilling (VGPR=256, 445MB scratch writes, VALUBusy 6%).
// Fix: __launch_bounds__(256,4) caps VGPR at 128; #pragma unroll 2 stops the
// full 32-iter unroll that caused the pressure. No other changes.

#define NEG_SLOPE 0.2f

// ---------------- wave reductions (64 lanes) ----------------
__device__ __forceinline__ float wmax(float v) {
    for (int o = 32; o; o >>= 1) v = fmaxf(v, __shfl_xor(v, o));
    return v;
}
__device__ __forceinline__ float wsum(float v) {
    for (int o = 32; o; o >>= 1) v += __shfl_xor(v, o);
    return v;
}

// ---------------- CSR build ----------------
__global__ void k_deg_init(int* __restrict__ deg, int N) {
    int i = blockIdx.x * blockDim.x + threadIdx.x;
    if (i < N) deg[i] = 1;  // self loop
}
__global__ void k_deg_edges(const int* __restrict__ ei, int* __restrict__ deg, int E) {
    int e = blockIdx.x * blockDim.x + threadIdx.x;
    if (e < E) atomicAdd(&deg[ei[E + e]], 1);
}

__global__ __launch_bounds__(256) void k_scan1(const int* __restrict__ deg, int* __restrict__ rs,
                                               int* __restrict__ bsum, int N) {
    __shared__ int s[256];
    int t = threadIdx.x;
    int base = blockIdx.x * 1024;
    int i0 = base + t * 4;
    int d0 = (i0 + 0 < N) ? deg[i0 + 0] : 0;
    int d1 = (i0 + 1 < N) ? deg[i0 + 1] : 0;
    int d2 = (i0 + 2 < N) ? deg[i0 + 2] : 0;
    int d3 = (i0 + 3 < N) ? deg[i0 + 3] : 0;
    int s0 = d0, s1 = s0 + d1, s2 = s1 + d2, s3 = s2 + d3;
    int tsum = s3;
    s[t] = tsum;
    __syncthreads();
    for (int off = 1; off < 256; off <<= 1) {
        int v = (t >= off) ? s[t - off] : 0;
        __syncthreads();
        s[t] += v;
        __syncthreads();
    }
    int excl = s[t] - tsum;
    if (i0 + 0 < N) rs[1 + i0 + 0] = excl + s0;
    if (i0 + 1 < N) rs[1 + i0 + 1] = excl + s1;
    if (i0 + 2 < N) rs[1 + i0 + 2] = excl + s2;
    if (i0 + 3 < N) rs[1 + i0 + 3] = excl + s3;
    if (t == 0) bsum[blockIdx.x] = s[255];
}

__global__ __launch_bounds__(256) void k_scan2(const int* __restrict__ bsum,
                                               int* __restrict__ boff, int NB) {
    __shared__ int s[256];
    int t = threadIdx.x;
    int orig = (t < NB) ? bsum[t] : 0;
    s[t] = orig;
    __syncthreads();
    for (int off = 1; off < 256; off <<= 1) {
        int v = (t >= off) ? s[t - off] : 0;
        __syncthreads();
        s[t] += v;
        __syncthreads();
    }
    if (t < NB) boff[t] = s[t] - orig;  // exclusive
}

__global__ void k_scan3(int* __restrict__ rs, const int* __restrict__ boff, int N) {
    int i = blockIdx.x * blockDim.x + threadIdx.x;
    if (i == 0) rs[0] = 0;
    if (i < N) rs[1 + i] += boff[i >> 10];
}

__global__ void k_cursor(const int* __restrict__ rs, int* __restrict__ cur, int N) {
    int i = blockIdx.x * blockDim.x + threadIdx.x;
    if (i < N) cur[i] = rs[i];
}

__global__ void k_scatter(const int* __restrict__ ei, int* __restrict__ cur,
                          int* __restrict__ csr, int E, int Etot) {
    int e = blockIdx.x * blockDim.x + threadIdx.x;
    if (e >= Etot) return;
    int src, dst;
    if (e < E) { src = ei[e]; dst = ei[E + e]; } else { src = dst = e - E; }
    int pos = atomicAdd(&cur[dst], 1);
    csr[pos] = src;
}

// ---------------- dense kernels (register-tiled) ----------------

// h0 = relu(x @ W0 + b0); x[N,128], W0[128,64]. 64 nodes/block.
__global__ __launch_bounds__(256) void k_gemm1(const float* __restrict__ x,
                                               const float* __restrict__ W0,
                                               const float* __restrict__ b0,
                                               float* __restrict__ h0, int N) {
    __shared__ float wl[128 * 64];   // [k][c]
    __shared__ float al[64 * 132];   // [node][k] padded
    int t = threadIdx.x;
    int n0 = blockIdx.x * 64;
    const float4* wg = (const float4*)W0;
    float4* wl4 = (float4*)wl;
#pragma unroll
    for (int i = 0; i < 8; ++i) wl4[t + i * 256] = wg[t + i * 256];
#pragma unroll
    for (int i = 0; i < 8; ++i) {
        int f = t + i * 256;
        int node = f >> 5, q = f & 31;
        int ng = n0 + node; if (ng > N - 1) ng = N - 1;
        float4 v = ((const float4*)x)[(size_t)ng * 32 + q];
        *(float4*)&al[node * 132 + q * 4] = v;
    }
    __syncthreads();
    int colg = t & 15;   // cols colg*4..+3
    int rowg = t >> 4;   // rows rowg*4..+3
    float4 acc[4];
#pragma unroll
    for (int j = 0; j < 4; ++j) acc[j] = make_float4(0.f, 0.f, 0.f, 0.f);
    for (int k4 = 0; k4 < 128; k4 += 4) {
        float4 w0 = *(float4*)&wl[(k4 + 0) * 64 + colg * 4];
        float4 w1 = *(float4*)&wl[(k4 + 1) * 64 + colg * 4];
        float4 w2 = *(float4*)&wl[(k4 + 2) * 64 + colg * 4];
        float4 w3 = *(float4*)&wl[(k4 + 3) * 64 + colg * 4];
#pragma unroll
        for (int j = 0; j < 4; ++j) {
            float4 a = *(float4*)&al[(rowg * 4 + j) * 132 + k4];
            acc[j].x += a.x * w0.x + a.y * w1.x + a.z * w2.x + a.w * w3.x;
            acc[j].y += a.x * w0.y + a.y * w1.y + a.z * w2.y + a.w * w3.y;
            acc[j].z += a.x * w0.z + a.y * w1.z + a.z * w2.z + a.w * w3.z;
            acc[j].w += a.x * w0.w + a.y * w1.w + a.z * w2.w + a.w * w3.w;
        }
    }
    float4 bb = ((const float4*)b0)[colg];
#pragma unroll
    for (int j = 0; j < 4; ++j) {
        int n = n0 + rowg * 4 + j;
        if (n < N) {
            float4 r;
            r.x = fmaxf(acc[j].x + bb.x, 0.f);
            r.y = fmaxf(acc[j].y + bb.y, 0.f);
            r.z = fmaxf(acc[j].z + bb.z, 0.f);
            r.w = fmaxf(acc[j].w + bb.w, 0.f);
            ((float4*)h0)[(size_t)n * 16 + colg] = r;
        }
    }
}

// h1 = h0 @ W1 + fused att1 dots. h0[N,64], W1[64,128]. 64 nodes/block.
__global__ __launch_bounds__(256) void k_gemm2(const float* __restrict__ h0,
                                               const float* __restrict__ W1,
                                               const float* __restrict__ as_g,
                                               const float* __restrict__ ad_g,
                                               float* __restrict__ h1,
                                               float* __restrict__ as1,
                                               float* __restrict__ ad1, int N) {
    __shared__ float wl[64 * 128];  // [k][c]
    __shared__ float al[64 * 68];   // [node][k] padded
    int t = threadIdx.x;
    int n0 = blockIdx.x * 64;
    const float4* wg = (const float4*)W1;
    float4* wl4 = (float4*)wl;
#pragma unroll
    for (int i = 0; i < 8; ++i) wl4[t + i * 256] = wg[t + i * 256];
#pragma unroll
    for (int i = 0; i < 4; ++i) {
        int f = t + i * 256;
        int node = f >> 4, q = f & 15;
        int ng = n0 + node; if (ng > N - 1) ng = N - 1;
        float4 v = ((const float4*)h0)[(size_t)ng * 16 + q];
        *(float4*)&al[node * 68 + q * 4] = v;
    }
    __syncthreads();
    int colg = t & 31;   // cols colg*4..+3 (head = colg>=16)
    int rowg = t >> 5;   // rows rowg*8..+7
    float4 acc[8];
#pragma unroll
    for (int j = 0; j < 8; ++j) acc[j] = make_float4(0.f, 0.f, 0.f, 0.f);
    for (int k4 = 0; k4 < 64; k4 += 4) {
        float4 w0 = *(float4*)&wl[(k4 + 0) * 128 + colg * 4];
        float4 w1 = *(float4*)&wl[(k4 + 1) * 128 + colg * 4];
        float4 w2 = *(float4*)&wl[(k4 + 2) * 128 + colg * 4];
        float4 w3 = *(float4*)&wl[(k4 + 3) * 128 + colg * 4];
#pragma unroll
        for (int j = 0; j < 8; ++j) {
            float4 a = *(float4*)&al[(rowg * 8 + j) * 68 + k4];
            acc[j].x += a.x * w0.x + a.y * w1.x + a.z * w2.x + a.w * w3.x;
            acc[j].y += a.x * w0.y + a.y * w1.y + a.z * w2.y + a.w * w3.y;
            acc[j].z += a.x * w0.z + a.y * w1.z + a.z * w2.z + a.w * w3.z;
            acc[j].w += a.x * w0.w + a.y * w1.w + a.z * w2.w + a.w * w3.w;
        }
    }
    float4 asv = ((const float4*)as_g)[colg];
    float4 adv = ((const float4*)ad_g)[colg];
    float ps[8], pd[8];
#pragma unroll
    for (int j = 0; j < 8; ++j) {
        ps[j] = acc[j].x * asv.x + acc[j].y * asv.y + acc[j].z * asv.z + acc[j].w * asv.w;
        pd[j] = acc[j].x * adv.x + acc[j].y * adv.y + acc[j].z * adv.z + acc[j].w * adv.w;
    }
    for (int o = 1; o < 16; o <<= 1) {
#pragma unroll
        for (int j = 0; j < 8; ++j) {
            ps[j] += __shfl_xor(ps[j], o);
            pd[j] += __shfl_xor(pd[j], o);
        }
    }
#pragma unroll
    for (int j = 0; j < 8; ++j) {
        int n = n0 + rowg * 8 + j;
        if (n < N) ((float4*)h1)[(size_t)n * 32 + colg] = acc[j];
    }
    int lane = t & 63;
    if ((lane & 15) == 0) {
        int head = (lane >> 4) & 1;
#pragma unroll
        for (int j = 0; j < 8; ++j) {
            int n = n0 + rowg * 8 + j;
            if (n < N) {
                as1[n * 2 + head] = ps[j];
                ad1[n * 2 + head] = pd[j];
            }
        }
    }
}

// ---- layer-1 fused: per-node online softmax + aggregation + bias + ELU ----
__global__ __launch_bounds__(256) void k_node_l1(const int* __restrict__ rs,
                                                 const int* __restrict__ csr,
                                                 const float* __restrict__ h1,
                                                 const float* __restrict__ as1,
                                                 const float* __restrict__ ad1,
                                                 const float* __restrict__ b1,
                                                 float* __restrict__ agg, int N) {
    int lane = threadIdx.x & 63;
    int n = (blockIdx.x * 256 + threadIdx.x) >> 6;
    if (n >= N) return;
    int row = rs[n], end = rs[n + 1];
    float2 adv = ((const float2*)ad1)[n];
    const float2* asp = (const float2*)as1;
    bool head1 = lane >= 32;
    float m0 = -INFINITY, m1 = -INFINITY, l0 = 0.f, l1 = 0.f;
    float accx = 0.f, accy = 0.f;
    for (int base = row; base < end; base += 64) {
        int idx = base + lane;
        bool act = idx < end;
        int src = act ? csr[idx] : 0;
        float2 av = asp[src];
        float e0 = av.x + adv.x, e1 = av.y + adv.y;
        e0 = e0 > 0.f ? e0 : NEG_SLOPE * e0;
        e1 = e1 > 0.f ? e1 : NEG_SLOPE * e1;
        if (!act) { e0 = -INFINITY; e1 = -INFINITY; }
        float m0n = fmaxf(m0, wmax(e0));
        float m1n = fmaxf(m1, wmax(e1));
        float r0 = __expf(m0 - m0n), r1 = __expf(m1 - m1n);
        float p0 = act ? __expf(e0 - m0n) : 0.f;
        float p1 = act ? __expf(e1 - m1n) : 0.f;
        l0 = l0 * r0 + wsum(p0);
        l1 = l1 * r1 + wsum(p1);
        float rr = head1 ? r1 : r0;
        accx *= rr; accy *= rr;
        int cnt = min(64, end - base);
#pragma unroll 4
        for (int j = 0; j < cnt; ++j) {
            int sj = __shfl(src, j);
            float a0j = __shfl(p0, j);
            float a1j = __shfl(p1, j);
            float aj = head1 ? a1j : a0j;
            float2 v = ((const float2*)(h1 + (size_t)sj * 128))[lane];
            accx += v.x * aj;
            accy += v.y * aj;
        }
        m0 = m0n; m1 = m1n;
    }
    float inv = 1.f / (head1 ? l1 : l0);
    float vx = accx * inv + b1[lane * 2];
    float vy = accy * inv + b1[lane * 2 + 1];
    vx = vx > 0.f ? vx : expm1f(vx);
    vy = vy > 0.f ? vy : expm1f(vy);
    float2 r; r.x = vx; r.y = vy;
    ((float2*)(agg + (size_t)n * 128))[lane] = r;
}

// h2 = h1act @ W2 + att2 dots. 64 nodes/block, 4 threads/node x 5 cols.
// __launch_bounds__(256,4): cap VGPR<=128 (R2 hit the 256 cap and spilled
// ~1KB/thread to scratch -> 445MB writes, 210us). unroll 2 keeps pressure low.
__global__ __launch_bounds__(256, 4) void k_node2(const float* __restrict__ h1a,
                                                  const float* __restrict__ W2,
                                                  const float* __restrict__ as_g,
                                                  const float* __restrict__ ad_g,
                                                  float* __restrict__ h2,
                                                  float* __restrict__ a_s,
                                                  float* __restrict__ a_d, int N) {
    __shared__ float al[64 * 132];   // [node][k] padded
    __shared__ float w2t[20 * 132];  // [c][k] padded, cols 18,19 zero
    int t = threadIdx.x;
    int n0 = blockIdx.x * 64;
#pragma unroll
    for (int i = 0; i < 8; ++i) {
        int f = t + i * 256;
        int node = f >> 5, q = f & 31;
        int ng = n0 + node; if (ng > N - 1) ng = N - 1;
        float4 v = ((const float4*)h1a)[(size_t)ng * 32 + q];
        *(float4*)&al[node * 132 + q * 4] = v;
    }
    for (int i = t; i < 2560; i += 256) {
        int c = i >> 7, k = i & 127;
        w2t[c * 132 + k] = (c < 18) ? W2[k * 18 + c] : 0.f;
    }
    __syncthreads();
    int node = t >> 2;
    int cq = t & 3;
    int c0 = cq * 5;  // cols c0..c0+4 (cq==3: cols 15..19, 18/19 dead)
    int n = n0 + node;
    float acc[5] = {0.f, 0.f, 0.f, 0.f, 0.f};
#pragma unroll 2
    for (int k4 = 0; k4 < 128; k4 += 4) {
        float4 a = *(float4*)&al[node * 132 + k4];
#pragma unroll
        for (int i = 0; i < 5; ++i) {
            float4 w = *(float4*)&w2t[(c0 + i) * 132 + k4];
            acc[i] += a.x * w.x + a.y * w.y + a.z * w.z + a.w * w.w;
        }
    }
    float ps = 0.f, pd = 0.f;
#pragma unroll
    for (int i = 0; i < 5; ++i) {
        int c = c0 + i;
        float asv = (c < 18) ? as_g[c] : 0.f;
        float adv = (c < 18) ? ad_g[c] : 0.f;
        ps += acc[i] * asv;
        pd += acc[i] * adv;
    }
    ps += __shfl_xor(ps, 1); ps += __shfl_xor(ps, 2);
    pd += __shfl_xor(pd, 1); pd += __shfl_xor(pd, 2);
    if (n < N) {
#pragma unroll
        for (int i = 0; i < 5; ++i) {
            int c = c0 + i;
            if (c < 18) h2[(size_t)n * 18 + c] = acc[i];
        }
        if (cq == 0) { a_s[n] = ps; a_d[n] = pd; }
    }
}

// ---- layer-2 fused: per-node online softmax + agg + bias + log_softmax ----
__global__ __launch_bounds__(256) void k_node_l2(const int* __restrict__ rs,
                                                 const int* __restrict__ csr,
                                                 const float* __restrict__ h2,
                                                 const float* __restrict__ as2,
                                                 const float* __restrict__ ad2,
                                                 const float* __restrict__ b2,
                                                 float* __restrict__ out, int N) {
    int lane = threadIdx.x & 63;
    int n = (blockIdx.x * 256 + threadIdx.x) >> 6;
    if (n >= N) return;
    int row = rs[n], end = rs[n + 1];
    float adn = ad2[n];
    float m = -INFINITY, l = 0.f;
    float acc[18];
#pragma unroll
    for (int c = 0; c < 18; ++c) acc[c] = 0.f;
    for (int base = row; base < end; base += 64) {
        int idx = base + lane;
        bool act = idx < end;
        int src = act ? csr[idx] : 0;
        float e = as2[src] + adn;
        e = e > 0.f ? e : NEG_SLOPE * e;
        if (!act) e = -INFINITY;
        float mn = fmaxf(m, wmax(e));
        float r = __expf(m - mn);
        float p = act ? __expf(e - mn) : 0.f;
        l = l * r + wsum(p);
#pragma unroll
        for (int c = 0; c < 18; ++c) acc[c] *= r;
        if (act) {
            const float* hp = h2 + (size_t)src * 18;
#pragma unroll
            for (int c = 0; c < 18; ++c) acc[c] += p * hp[c];
        }
        m = mn;
    }
    for (int o = 32; o; o >>= 1) {
#pragma unroll
        for (int c = 0; c < 18; ++c) acc[c] += __shfl_xor(acc[c], o);
    }
    float inv = 1.f / l;
    float v[18];
    float mx = -INFINITY;
#pragma unroll
    for (int c = 0; c < 18; ++c) { v[c] = acc[c] * inv + b2[c]; mx = fmaxf(mx, v[c]); }
    float s = 0.f;
#pragma unroll
    for (int c = 0; c < 18; ++c) s += __expf(v[c] - mx);
    float lse = mx + __logf(s);
    if (lane == 0) {
#pragma unroll
        for (int c = 0; c < 18; ++c) out[(size_t)n * 18 + c] = v[c] - lse;
    }
}

extern "C" void kernel_launch(void* const* d_in, const int* in_sizes, int n_in,
                              void* d_out, int out_size, void* d_ws, size_t ws_size,
                              hipStream_t stream) {
    const float* x      = (const float*)d_in[0];
    const int*   ei     = (const int*)d_in[1];
    const float* W0     = (const float*)d_in[2];
    const float* b0     = (const float*)d_in[3];
    const float* W1     = (const float*)d_in[4];
    const float* att_s1 = (const float*)d_in[5];
    const float* att_d1 = (const float*)d_in[6];
    const float* b1     = (const float*)d_in[7];
    const float* W2     = (const float*)d_in[8];
    const float* att_s2 = (const float*)d_in[9];
    const float* att_d2 = (const float*)d_in[10];
    const float* b2     = (const float*)d_in[11];

    const int N = in_sizes[0] / 128;
    const int E = in_sizes[1] / 2;
    const int Etot = E + N;
    const int NB = (N + 1023) / 1024;  // scan blocks (<= 256)
    const int NBLK = (N + 63) / 64;    // dense tiles

    // workspace carve-up (~145 MB)
    char* w = (char*)d_ws;
    float* h0   = (float*)w; w += (size_t)N * 64 * 4;
    float* h1   = (float*)w; w += (size_t)N * 128 * 4;
    float* agg1 = (float*)w; w += (size_t)N * 128 * 4;
    float* as1  = (float*)w; w += (size_t)N * 2 * 4;
    float* ad1  = (float*)w; w += (size_t)N * 2 * 4;
    float* h2   = (float*)w; w += (size_t)N * 18 * 4;
    float* as2  = (float*)w; w += (size_t)N * 4;
    float* ad2  = (float*)w; w += (size_t)N * 4;
    int* deg    = (int*)w;   w += (size_t)N * 4;
    int* rs     = (int*)w;   w += (size_t)(N + 1) * 4;
    int* cur    = (int*)w;   w += (size_t)N * 4;
    int* bsum   = (int*)w;   w += (size_t)256 * 4;
    int* boff   = (int*)w;   w += (size_t)256 * 4;
    int* csr    = (int*)w;   w += (size_t)Etot * 4;

    float* out = (float*)d_out;

    // ---- CSR build ----
    k_deg_init<<<(N + 255) / 256, 256, 0, stream>>>(deg, N);
    k_deg_edges<<<(E + 255) / 256, 256, 0, stream>>>(ei, deg, E);
    k_scan1<<<NB, 256, 0, stream>>>(deg, rs, bsum, N);
    k_scan2<<<1, 256, 0, stream>>>(bsum, boff, NB);
    k_scan3<<<(N + 255) / 256, 256, 0, stream>>>(rs, boff, N);
    k_cursor<<<(N + 255) / 256, 256, 0, stream>>>(rs, cur, N);
    k_scatter<<<(Etot + 255) / 256, 256, 0, stream>>>(ei, cur, csr, E, Etot);

    // ---- dense ----
    k_gemm1<<<NBLK, 256, 0, stream>>>(x, W0, b0, h0, N);
    k_gemm2<<<NBLK, 256, 0, stream>>>(h0, W1, att_s1, att_d1, h1, as1, ad1, N);

    // ---- layer 1 fused edge pass ----
    k_node_l1<<<(N * 64 + 255) / 256, 256, 0, stream>>>(rs, csr, h1, as1, ad1, b1, agg1, N);

    // ---- layer 2 dense + fused edge pass ----
    k_node2<<<NBLK, 256, 0, stream>>>(agg1, W2, att_s2, att_d2, h2, as2, ad2, N);
    k_node_l2<<<(N * 64 + 255) / 256, 256, 0, stream>>>(rs, csr, h2, as2, ad2, b2, out, N);
}

// Round 6
// 553.293 us; speedup vs baseline: 3.4189x; 1.2055x over previous
//
#include <hip/hip_runtime.h>
#include <math.h>

// GAT 2-layer: N=100000, E=1600000 (+N self loops), F_IN=128, HID=64, HEADS=2,
// OUT_HEADS=1, NUM_CLASS=18, NEG_SLOPE=0.2
// Round 5: R4 design with the h1b write-stride bug fixed (uint2 row stride is
// 32, not 16 — half the bf16 rows were poison). No other changes.
//  - h1/h2 stored bf16 (RNE): halves random-gather HBM traffic.
//  - scatter: atomic-free + XCD-slice-filtered for full-line write-backs.

#define NEG_SLOPE 0.2f

typedef unsigned short ushort_t;

// ---------------- wave reductions (64 lanes) ----------------
__device__ __forceinline__ float wmax(float v) {
    for (int o = 32; o; o >>= 1) v = fmaxf(v, __shfl_xor(v, o));
    return v;
}
__device__ __forceinline__ float wsum(float v) {
    for (int o = 32; o; o >>= 1) v += __shfl_xor(v, o);
    return v;
}

// ---------------- bf16 helpers (RNE) ----------------
__device__ __forceinline__ unsigned bfpack(float a, float b) {
    unsigned ua = __float_as_uint(a);
    unsigned ub = __float_as_uint(b);
    ua = (ua + 0x7fffu + ((ua >> 16) & 1u)) >> 16;
    ub = (ub + 0x7fffu + ((ub >> 16) & 1u)) & 0xffff0000u;
    return ua | ub;
}
__device__ __forceinline__ ushort_t bf16of(float a) {
    unsigned ua = __float_as_uint(a);
    return (ushort_t)((ua + 0x7fffu + ((ua >> 16) & 1u)) >> 16);
}
__device__ __forceinline__ float bflo(unsigned u) { return __uint_as_float(u << 16); }
__device__ __forceinline__ float bfhi(unsigned u) { return __uint_as_float(u & 0xffff0000u); }

// ---------------- CSR build ----------------
__global__ void k_deg_init(int* __restrict__ deg, int N) {
    int i = blockIdx.x * blockDim.x + threadIdx.x;
    if (i < N) deg[i] = 1;  // slot 0 reserved for self loop
}
// histogram + per-edge within-dst offset (removes the atomic from scatter)
__global__ void k_deg_edges(const int* __restrict__ ei, int* __restrict__ deg,
                            int* __restrict__ eofs, int E) {
    int e = blockIdx.x * blockDim.x + threadIdx.x;
    if (e < E) eofs[e] = atomicAdd(&deg[ei[E + e]], 1);
}

__global__ __launch_bounds__(256) void k_scan1(const int* __restrict__ deg, int* __restrict__ rs,
                                               int* __restrict__ bsum, int N) {
    __shared__ int s[256];
    int t = threadIdx.x;
    int base = blockIdx.x * 1024;
    int i0 = base + t * 4;
    int d0 = (i0 + 0 < N) ? deg[i0 + 0] : 0;
    int d1 = (i0 + 1 < N) ? deg[i0 + 1] : 0;
    int d2 = (i0 + 2 < N) ? deg[i0 + 2] : 0;
    int d3 = (i0 + 3 < N) ? deg[i0 + 3] : 0;
    int s0 = d0, s1 = s0 + d1, s2 = s1 + d2, s3 = s2 + d3;
    int tsum = s3;
    s[t] = tsum;
    __syncthreads();
    for (int off = 1; off < 256; off <<= 1) {
        int v = (t >= off) ? s[t - off] : 0;
        __syncthreads();
        s[t] += v;
        __syncthreads();
    }
    int excl = s[t] - tsum;
    if (i0 + 0 < N) rs[1 + i0 + 0] = excl + s0;
    if (i0 + 1 < N) rs[1 + i0 + 1] = excl + s1;
    if (i0 + 2 < N) rs[1 + i0 + 2] = excl + s2;
    if (i0 + 3 < N) rs[1 + i0 + 3] = excl + s3;
    if (t == 0) bsum[blockIdx.x] = s[255];
}

__global__ __launch_bounds__(256) void k_scan2(const int* __restrict__ bsum,
                                               int* __restrict__ boff, int NB) {
    __shared__ int s[256];
    int t = threadIdx.x;
    int orig = (t < NB) ? bsum[t] : 0;
    s[t] = orig;
    __syncthreads();
    for (int off = 1; off < 256; off <<= 1) {
        int v = (t >= off) ? s[t - off] : 0;
        __syncthreads();
        s[t] += v;
        __syncthreads();
    }
    if (t < NB) boff[t] = s[t] - orig;  // exclusive
}

__global__ void k_scan3(int* __restrict__ rs, const int* __restrict__ boff, int N) {
    int i = blockIdx.x * blockDim.x + threadIdx.x;
    if (i == 0) rs[0] = 0;
    if (i < N) rs[1 + i] += boff[i >> 10];
}

// slice-filtered, atomic-free scatter. cohort c = blockIdx&7 (XCD heuristic);
// slice(dst) = dst>>13; cohort writes only its slices -> csr lines stay in
// one XCD L2 and write back as full lines.
__global__ __launch_bounds__(256) void k_scatter(const int* __restrict__ ei,
                                                 const int* __restrict__ eofs,
                                                 const int* __restrict__ rs,
                                                 int* __restrict__ csr,
                                                 int E, int Etot, int cohortBlocks) {
    int c = blockIdx.x & 7;
    int pb = blockIdx.x >> 3;
    int tid = pb * 256 + threadIdx.x;
    int stride = cohortBlocks * 256;
    for (int e = tid; e < Etot; e += stride) {
        int dst = (e < E) ? ei[E + e] : (e - E);
        if (((dst >> 13) & 7) != c) continue;
        int src, ofs;
        if (e < E) { src = ei[e]; ofs = eofs[e]; } else { src = dst; ofs = 0; }
        csr[rs[dst] + ofs] = src;
    }
}

// ---------------- dense kernels (register-tiled) ----------------

// h0 = relu(x @ W0 + b0); x[N,128], W0[128,64]. 64 nodes/block.
__global__ __launch_bounds__(256) void k_gemm1(const float* __restrict__ x,
                                               const float* __restrict__ W0,
                                               const float* __restrict__ b0,
                                               float* __restrict__ h0, int N) {
    __shared__ float wl[128 * 64];   // [k][c]
    __shared__ float al[64 * 132];   // [node][k] padded
    int t = threadIdx.x;
    int n0 = blockIdx.x * 64;
    const float4* wg = (const float4*)W0;
    float4* wl4 = (float4*)wl;
#pragma unroll
    for (int i = 0; i < 8; ++i) wl4[t + i * 256] = wg[t + i * 256];
#pragma unroll
    for (int i = 0; i < 8; ++i) {
        int f = t + i * 256;
        int node = f >> 5, q = f & 31;
        int ng = n0 + node; if (ng > N - 1) ng = N - 1;
        float4 v = ((const float4*)x)[(size_t)ng * 32 + q];
        *(float4*)&al[node * 132 + q * 4] = v;
    }
    __syncthreads();
    int colg = t & 15;   // cols colg*4..+3
    int rowg = t >> 4;   // rows rowg*4..+3
    float4 acc[4];
#pragma unroll
    for (int j = 0; j < 4; ++j) acc[j] = make_float4(0.f, 0.f, 0.f, 0.f);
    for (int k4 = 0; k4 < 128; k4 += 4) {
        float4 w0 = *(float4*)&wl[(k4 + 0) * 64 + colg * 4];
        float4 w1 = *(float4*)&wl[(k4 + 1) * 64 + colg * 4];
        float4 w2 = *(float4*)&wl[(k4 + 2) * 64 + colg * 4];
        float4 w3 = *(float4*)&wl[(k4 + 3) * 64 + colg * 4];
#pragma unroll
        for (int j = 0; j < 4; ++j) {
            float4 a = *(float4*)&al[(rowg * 4 + j) * 132 + k4];
            acc[j].x += a.x * w0.x + a.y * w1.x + a.z * w2.x + a.w * w3.x;
            acc[j].y += a.x * w0.y + a.y * w1.y + a.z * w2.y + a.w * w3.y;
            acc[j].z += a.x * w0.z + a.y * w1.z + a.z * w2.z + a.w * w3.z;
            acc[j].w += a.x * w0.w + a.y * w1.w + a.z * w2.w + a.w * w3.w;
        }
    }
    float4 bb = ((const float4*)b0)[colg];
#pragma unroll
    for (int j = 0; j < 4; ++j) {
        int n = n0 + rowg * 4 + j;
        if (n < N) {
            float4 r;
            r.x = fmaxf(acc[j].x + bb.x, 0.f);
            r.y = fmaxf(acc[j].y + bb.y, 0.f);
            r.z = fmaxf(acc[j].z + bb.z, 0.f);
            r.w = fmaxf(acc[j].w + bb.w, 0.f);
            ((float4*)h0)[(size_t)n * 16 + colg] = r;
        }
    }
}

// h1 = h0 @ W1 (stored bf16) + fused att1 dots. h0[N,64], W1[64,128].
__global__ __launch_bounds__(256) void k_gemm2(const float* __restrict__ h0,
                                               const float* __restrict__ W1,
                                               const float* __restrict__ as_g,
                                               const float* __restrict__ ad_g,
                                               ushort_t* __restrict__ h1b,
                                               float* __restrict__ as1,
                                               float* __restrict__ ad1, int N) {
    __shared__ float wl[64 * 128];  // [k][c]
    __shared__ float al[64 * 68];   // [node][k] padded
    int t = threadIdx.x;
    int n0 = blockIdx.x * 64;
    const float4* wg = (const float4*)W1;
    float4* wl4 = (float4*)wl;
#pragma unroll
    for (int i = 0; i < 8; ++i) wl4[t + i * 256] = wg[t + i * 256];
#pragma unroll
    for (int i = 0; i < 4; ++i) {
        int f = t + i * 256;
        int node = f >> 4, q = f & 15;
        int ng = n0 + node; if (ng > N - 1) ng = N - 1;
        float4 v = ((const float4*)h0)[(size_t)ng * 16 + q];
        *(float4*)&al[node * 68 + q * 4] = v;
    }
    __syncthreads();
    int colg = t & 31;   // cols colg*4..+3 (head = colg>=16)
    int rowg = t >> 5;   // rows rowg*8..+7
    float4 acc[8];
#pragma unroll
    for (int j = 0; j < 8; ++j) acc[j] = make_float4(0.f, 0.f, 0.f, 0.f);
    for (int k4 = 0; k4 < 64; k4 += 4) {
        float4 w0 = *(float4*)&wl[(k4 + 0) * 128 + colg * 4];
        float4 w1 = *(float4*)&wl[(k4 + 1) * 128 + colg * 4];
        float4 w2 = *(float4*)&wl[(k4 + 2) * 128 + colg * 4];
        float4 w3 = *(float4*)&wl[(k4 + 3) * 128 + colg * 4];
#pragma unroll
        for (int j = 0; j < 8; ++j) {
            float4 a = *(float4*)&al[(rowg * 8 + j) * 68 + k4];
            acc[j].x += a.x * w0.x + a.y * w1.x + a.z * w2.x + a.w * w3.x;
            acc[j].y += a.x * w0.y + a.y * w1.y + a.z * w2.y + a.w * w3.y;
            acc[j].z += a.x * w0.z + a.y * w1.z + a.z * w2.z + a.w * w3.z;
            acc[j].w += a.x * w0.w + a.y * w1.w + a.z * w2.w + a.w * w3.w;
        }
    }
    float4 asv = ((const float4*)as_g)[colg];
    float4 adv = ((const float4*)ad_g)[colg];
    float ps[8], pd[8];
#pragma unroll
    for (int j = 0; j < 8; ++j) {
        ps[j] = acc[j].x * asv.x + acc[j].y * asv.y + acc[j].z * asv.z + acc[j].w * asv.w;
        pd[j] = acc[j].x * adv.x + acc[j].y * adv.y + acc[j].z * adv.z + acc[j].w * adv.w;
    }
    for (int o = 1; o < 16; o <<= 1) {
#pragma unroll
        for (int j = 0; j < 8; ++j) {
            ps[j] += __shfl_xor(ps[j], o);
            pd[j] += __shfl_xor(pd[j], o);
        }
    }
#pragma unroll
    for (int j = 0; j < 8; ++j) {
        int n = n0 + rowg * 8 + j;
        if (n < N) {
            uint2 pr;
            pr.x = bfpack(acc[j].x, acc[j].y);
            pr.y = bfpack(acc[j].z, acc[j].w);
            // row = 128 bf16 = 32 uint2 (R4 bug: stride 16 corrupted rows)
            ((uint2*)h1b)[(size_t)n * 32 + colg] = pr;
        }
    }
    int lane = t & 63;
    if ((lane & 15) == 0) {
        int head = (lane >> 4) & 1;
#pragma unroll
        for (int j = 0; j < 8; ++j) {
            int n = n0 + rowg * 8 + j;
            if (n < N) {
                as1[n * 2 + head] = ps[j];
                ad1[n * 2 + head] = pd[j];
            }
        }
    }
}

// ---- layer-1 fused: per-node online softmax + aggregation + bias + ELU ----
// h1 payload gathered as bf16 (halves the dominant HBM fetch).
__global__ __launch_bounds__(256) void k_node_l1(const int* __restrict__ rs,
                                                 const int* __restrict__ csr,
                                                 const ushort_t* __restrict__ h1b,
                                                 const float* __restrict__ as1,
                                                 const float* __restrict__ ad1,
                                                 const float* __restrict__ b1,
                                                 float* __restrict__ agg, int N) {
    int lane = threadIdx.x & 63;
    int n = (blockIdx.x * 256 + threadIdx.x) >> 6;
    if (n >= N) return;
    int row = rs[n], end = rs[n + 1];
    float2 adv = ((const float2*)ad1)[n];
    const float2* asp = (const float2*)as1;
    const unsigned* h1u = (const unsigned*)h1b;
    bool head1 = lane >= 32;
    float m0 = -INFINITY, m1 = -INFINITY, l0 = 0.f, l1 = 0.f;
    float accx = 0.f, accy = 0.f;
    for (int base = row; base < end; base += 64) {
        int idx = base + lane;
        bool act = idx < end;
        int src = act ? csr[idx] : 0;
        float2 av = asp[src];
        float e0 = av.x + adv.x, e1 = av.y + adv.y;
        e0 = e0 > 0.f ? e0 : NEG_SLOPE * e0;
        e1 = e1 > 0.f ? e1 : NEG_SLOPE * e1;
        if (!act) { e0 = -INFINITY; e1 = -INFINITY; }
        float m0n = fmaxf(m0, wmax(e0));
        float m1n = fmaxf(m1, wmax(e1));
        float r0 = __expf(m0 - m0n), r1 = __expf(m1 - m1n);
        float p0 = act ? __expf(e0 - m0n) : 0.f;
        float p1 = act ? __expf(e1 - m1n) : 0.f;
        l0 = l0 * r0 + wsum(p0);
        l1 = l1 * r1 + wsum(p1);
        float rr = head1 ? r1 : r0;
        accx *= rr; accy *= rr;
        int cnt = min(64, end - base);
#pragma unroll 4
        for (int j = 0; j < cnt; ++j) {
            int sj = __shfl(src, j);
            float a0j = __shfl(p0, j);
            float a1j = __shfl(p1, j);
            float aj = head1 ? a1j : a0j;
            unsigned u = h1u[(size_t)sj * 64 + lane];
            accx += bflo(u) * aj;
            accy += bfhi(u) * aj;
        }
        m0 = m0n; m1 = m1n;
    }
    float inv = 1.f / (head1 ? l1 : l0);
    float vx = accx * inv + b1[lane * 2];
    float vy = accy * inv + b1[lane * 2 + 1];
    vx = vx > 0.f ? vx : expm1f(vx);
    vy = vy > 0.f ? vy : expm1f(vy);
    float2 r; r.x = vx; r.y = vy;
    ((float2*)(agg + (size_t)n * 128))[lane] = r;
}

// h2 = h1act @ W2 (stored bf16, stride 24) + att2 dots. 64 nodes/block.
__global__ __launch_bounds__(256, 4) void k_node2(const float* __restrict__ h1a,
                                                  const float* __restrict__ W2,
                                                  const float* __restrict__ as_g,
                                                  const float* __restrict__ ad_g,
                                                  ushort_t* __restrict__ h2b,
                                                  float* __restrict__ a_s,
                                                  float* __restrict__ a_d, int N) {
    __shared__ float al[64 * 132];   // [node][k] padded
    __shared__ float w2t[20 * 132];  // [c][k] padded, cols 18,19 zero
    int t = threadIdx.x;
    int n0 = blockIdx.x * 64;
#pragma unroll
    for (int i = 0; i < 8; ++i) {
        int f = t + i * 256;
        int node = f >> 5, q = f & 31;
        int ng = n0 + node; if (ng > N - 1) ng = N - 1;
        float4 v = ((const float4*)h1a)[(size_t)ng * 32 + q];
        *(float4*)&al[node * 132 + q * 4] = v;
    }
    for (int i = t; i < 2560; i += 256) {
        int c = i >> 7, k = i & 127;
        w2t[c * 132 + k] = (c < 18) ? W2[k * 18 + c] : 0.f;
    }
    __syncthreads();
    int node = t >> 2;
    int cq = t & 3;
    int c0 = cq * 5;  // cols c0..c0+4 (cq==3: cols 15..19, 18/19 dead)
    int n = n0 + node;
    float acc[5] = {0.f, 0.f, 0.f, 0.f, 0.f};
#pragma unroll 2
    for (int k4 = 0; k4 < 128; k4 += 4) {
        float4 a = *(float4*)&al[node * 132 + k4];
#pragma unroll
        for (int i = 0; i < 5; ++i) {
            float4 w = *(float4*)&w2t[(c0 + i) * 132 + k4];
            acc[i] += a.x * w.x + a.y * w.y + a.z * w.z + a.w * w.w;
        }
    }
    float ps = 0.f, pd = 0.f;
#pragma unroll
    for (int i = 0; i < 5; ++i) {
        int c = c0 + i;
        float asv = (c < 18) ? as_g[c] : 0.f;
        float adv = (c < 18) ? ad_g[c] : 0.f;
        ps += acc[i] * asv;
        pd += acc[i] * adv;
    }
    ps += __shfl_xor(ps, 1); ps += __shfl_xor(ps, 2);
    pd += __shfl_xor(pd, 1); pd += __shfl_xor(pd, 2);
    if (n < N) {
#pragma unroll
        for (int i = 0; i < 5; ++i) {
            int c = c0 + i;
            if (c < 18) h2b[(size_t)n * 24 + c] = bf16of(acc[i]);
        }
        if (cq == 0) { a_s[n] = ps; a_d[n] = pd; }
    }
}

// ---- layer-2 fused: per-node online softmax + agg + bias + log_softmax ----
// h2 gathered as bf16 (stride 24 ushorts = 12 uints).
__global__ __launch_bounds__(256) void k_node_l2(const int* __restrict__ rs,
                                                 const int* __restrict__ csr,
                                                 const ushort_t* __restrict__ h2b,
                                                 const float* __restrict__ as2,
                                                 const float* __restrict__ ad2,
                                                 const float* __restrict__ b2,
                                                 float* __restrict__ out, int N) {
    int lane = threadIdx.x & 63;
    int n = (blockIdx.x * 256 + threadIdx.x) >> 6;
    if (n >= N) return;
    int row = rs[n], end = rs[n + 1];
    float adn = ad2[n];
    const unsigned* h2u = (const unsigned*)h2b;
    float m = -INFINITY, l = 0.f;
    float acc[18];
#pragma unroll
    for (int c = 0; c < 18; ++c) acc[c] = 0.f;
    for (int base = row; base < end; base += 64) {
        int idx = base + lane;
        bool act = idx < end;
        int src = act ? csr[idx] : 0;
        float e = as2[src] + adn;
        e = e > 0.f ? e : NEG_SLOPE * e;
        if (!act) e = -INFINITY;
        float mn = fmaxf(m, wmax(e));
        float r = __expf(m - mn);
        float p = act ? __expf(e - mn) : 0.f;
        l = l * r + wsum(p);
#pragma unroll
        for (int c = 0; c < 18; ++c) acc[c] *= r;
        if (act) {
            const unsigned* hp = h2u + (size_t)src * 12;
#pragma unroll
            for (int k = 0; k < 9; ++k) {
                unsigned u = hp[k];
                acc[2 * k] += p * bflo(u);
                acc[2 * k + 1] += p * bfhi(u);
            }
        }
        m = mn;
    }
    for (int o = 32; o; o >>= 1) {
#pragma unroll
        for (int c = 0; c < 18; ++c) acc[c] += __shfl_xor(acc[c], o);
    }
    float inv = 1.f / l;
    float v[18];
    float mx = -INFINITY;
#pragma unroll
    for (int c = 0; c < 18; ++c) { v[c] = acc[c] * inv + b2[c]; mx = fmaxf(mx, v[c]); }
    float s = 0.f;
#pragma unroll
    for (int c = 0; c < 18; ++c) s += __expf(v[c] - mx);
    float lse = mx + __logf(s);
    if (lane == 0) {
#pragma unroll
        for (int c = 0; c < 18; ++c) out[(size_t)n * 18 + c] = v[c] - lse;
    }
}

extern "C" void kernel_launch(void* const* d_in, const int* in_sizes, int n_in,
                              void* d_out, int out_size, void* d_ws, size_t ws_size,
                              hipStream_t stream) {
    const float* x      = (const float*)d_in[0];
    const int*   ei     = (const int*)d_in[1];
    const float* W0     = (const float*)d_in[2];
    const float* b0     = (const float*)d_in[3];
    const float* W1     = (const float*)d_in[4];
    const float* att_s1 = (const float*)d_in[5];
    const float* att_d1 = (const float*)d_in[6];
    const float* b1     = (const float*)d_in[7];
    const float* W2     = (const float*)d_in[8];
    const float* att_s2 = (const float*)d_in[9];
    const float* att_d2 = (const float*)d_in[10];
    const float* b2     = (const float*)d_in[11];

    const int N = in_sizes[0] / 128;
    const int E = in_sizes[1] / 2;
    const int Etot = E + N;
    const int NB = (N + 1023) / 1024;  // scan blocks (<= 256)
    const int NBLK = (N + 63) / 64;    // dense tiles

    // workspace carve-up (~125 MB)
    char* w = (char*)d_ws;
    float* h0      = (float*)w;    w += (size_t)N * 64 * 4;
    ushort_t* h1b  = (ushort_t*)w; w += (size_t)N * 128 * 2;
    float* agg1    = (float*)w;    w += (size_t)N * 128 * 4;
    float* as1     = (float*)w;    w += (size_t)N * 2 * 4;
    float* ad1     = (float*)w;    w += (size_t)N * 2 * 4;
    ushort_t* h2b  = (ushort_t*)w; w += (size_t)N * 24 * 2;
    float* as2     = (float*)w;    w += (size_t)N * 4;
    float* ad2     = (float*)w;    w += (size_t)N * 4;
    int* deg       = (int*)w;      w += (size_t)N * 4;
    int* rs        = (int*)w;      w += (size_t)(N + 1) * 4;
    int* bsum      = (int*)w;      w += (size_t)256 * 4;
    int* boff      = (int*)w;      w += (size_t)256 * 4;
    int* eofs      = (int*)w;      w += (size_t)E * 4;
    int* csr       = (int*)w;      w += (size_t)Etot * 4;

    float* out = (float*)d_out;

    // ---- CSR build ----
    k_deg_init<<<(N + 255) / 256, 256, 0, stream>>>(deg, N);
    k_deg_edges<<<(E + 255) / 256, 256, 0, stream>>>(ei, deg, eofs, E);
    k_scan1<<<NB, 256, 0, stream>>>(deg, rs, bsum, N);
    k_scan2<<<1, 256, 0, stream>>>(bsum, boff, NB);
    k_scan3<<<(N + 255) / 256, 256, 0, stream>>>(rs, boff, N);
    const int cohortBlocks = 128;
    k_scatter<<<8 * cohortBlocks, 256, 0, stream>>>(ei, eofs, rs, csr, E, Etot, cohortBlocks);

    // ---- dense ----
    k_gemm1<<<NBLK, 256, 0, stream>>>(x, W0, b0, h0, N);
    k_gemm2<<<NBLK, 256, 0, stream>>>(h0, W1, att_s1, att_d1, h1b, as1, ad1, N);

    // ---- layer 1 fused edge pass ----
    k_node_l1<<<(N * 64 + 255) / 256, 256, 0, stream>>>(rs, csr, h1b, as1, ad1, b1, agg1, N);

    // ---- layer 2 dense + fused edge pass ----
    k_node2<<<NBLK, 256, 0, stream>>>(agg1, W2, att_s2, att_d2, h2b, as2, ad2, N);
    k_node_l2<<<(N * 64 + 255) / 256, 256, 0, stream>>>(rs, csr, h2b, as2, ad2, b2, out, N);
}

// Round 8
// 523.970 us; speedup vs baseline: 3.6103x; 1.0560x over previous
//
#include <hip/hip_runtime.h>
#include <math.h>

// GAT 2-layer: N=100000, E=1600000 (+N self loops), F_IN=128, HID=64, HEADS=2,
// OUT_HEADS=1, NUM_CLASS=18, NEG_SLOPE=0.2
// Round 7: R6's channel-parallel k_node_l2 with the group-sum fixed: both
// shfl reads must see the PRE-mutation acc (R6 chained += double-counted a
// shifted lane -> absmax 0.625). Everything else identical to passing R5.

#define NEG_SLOPE 0.2f

typedef unsigned short ushort_t;

// ---------------- wave reductions (64 lanes) ----------------
__device__ __forceinline__ float wmax(float v) {
    for (int o = 32; o; o >>= 1) v = fmaxf(v, __shfl_xor(v, o));
    return v;
}
__device__ __forceinline__ float wsum(float v) {
    for (int o = 32; o; o >>= 1) v += __shfl_xor(v, o);
    return v;
}

// ---------------- bf16 helpers (RNE) ----------------
__device__ __forceinline__ unsigned bfpack(float a, float b) {
    unsigned ua = __float_as_uint(a);
    unsigned ub = __float_as_uint(b);
    ua = (ua + 0x7fffu + ((ua >> 16) & 1u)) >> 16;
    ub = (ub + 0x7fffu + ((ub >> 16) & 1u)) & 0xffff0000u;
    return ua | ub;
}
__device__ __forceinline__ ushort_t bf16of(float a) {
    unsigned ua = __float_as_uint(a);
    return (ushort_t)((ua + 0x7fffu + ((ua >> 16) & 1u)) >> 16);
}
__device__ __forceinline__ float bflo(unsigned u) { return __uint_as_float(u << 16); }
__device__ __forceinline__ float bfhi(unsigned u) { return __uint_as_float(u & 0xffff0000u); }
__device__ __forceinline__ float bfval(ushort_t u) { return __uint_as_float(((unsigned)u) << 16); }

// ---------------- CSR build ----------------
__global__ void k_deg_init(int* __restrict__ deg, int N) {
    int i = blockIdx.x * blockDim.x + threadIdx.x;
    if (i < N) deg[i] = 1;  // slot 0 reserved for self loop
}
__global__ void k_deg_edges(const int* __restrict__ ei, int* __restrict__ deg,
                            int* __restrict__ eofs, int E) {
    int e = blockIdx.x * blockDim.x + threadIdx.x;
    if (e < E) eofs[e] = atomicAdd(&deg[ei[E + e]], 1);
}

__global__ __launch_bounds__(256) void k_scan1(const int* __restrict__ deg, int* __restrict__ rs,
                                               int* __restrict__ bsum, int N) {
    __shared__ int s[256];
    int t = threadIdx.x;
    int base = blockIdx.x * 1024;
    int i0 = base + t * 4;
    int d0 = (i0 + 0 < N) ? deg[i0 + 0] : 0;
    int d1 = (i0 + 1 < N) ? deg[i0 + 1] : 0;
    int d2 = (i0 + 2 < N) ? deg[i0 + 2] : 0;
    int d3 = (i0 + 3 < N) ? deg[i0 + 3] : 0;
    int s0 = d0, s1 = s0 + d1, s2 = s1 + d2, s3 = s2 + d3;
    int tsum = s3;
    s[t] = tsum;
    __syncthreads();
    for (int off = 1; off < 256; off <<= 1) {
        int v = (t >= off) ? s[t - off] : 0;
        __syncthreads();
        s[t] += v;
        __syncthreads();
    }
    int excl = s[t] - tsum;
    if (i0 + 0 < N) rs[1 + i0 + 0] = excl + s0;
    if (i0 + 1 < N) rs[1 + i0 + 1] = excl + s1;
    if (i0 + 2 < N) rs[1 + i0 + 2] = excl + s2;
    if (i0 + 3 < N) rs[1 + i0 + 3] = excl + s3;
    if (t == 0) bsum[blockIdx.x] = s[255];
}

__global__ __launch_bounds__(256) void k_scan2(const int* __restrict__ bsum,
                                               int* __restrict__ boff, int NB) {
    __shared__ int s[256];
    int t = threadIdx.x;
    int orig = (t < NB) ? bsum[t] : 0;
    s[t] = orig;
    __syncthreads();
    for (int off = 1; off < 256; off <<= 1) {
        int v = (t >= off) ? s[t - off] : 0;
        __syncthreads();
        s[t] += v;
        __syncthreads();
    }
    if (t < NB) boff[t] = s[t] - orig;  // exclusive
}

__global__ void k_scan3(int* __restrict__ rs, const int* __restrict__ boff, int N) {
    int i = blockIdx.x * blockDim.x + threadIdx.x;
    if (i == 0) rs[0] = 0;
    if (i < N) rs[1 + i] += boff[i >> 10];
}

// slice-filtered, atomic-free scatter (csr lines stay in one XCD L2).
__global__ __launch_bounds__(256) void k_scatter(const int* __restrict__ ei,
                                                 const int* __restrict__ eofs,
                                                 const int* __restrict__ rs,
                                                 int* __restrict__ csr,
                                                 int E, int Etot, int cohortBlocks) {
    int c = blockIdx.x & 7;
    int pb = blockIdx.x >> 3;
    int tid = pb * 256 + threadIdx.x;
    int stride = cohortBlocks * 256;
    for (int e = tid; e < Etot; e += stride) {
        int dst = (e < E) ? ei[E + e] : (e - E);
        if (((dst >> 13) & 7) != c) continue;
        int src, ofs;
        if (e < E) { src = ei[e]; ofs = eofs[e]; } else { src = dst; ofs = 0; }
        csr[rs[dst] + ofs] = src;
    }
}

// ---------------- dense kernels (register-tiled) ----------------

// h0 = relu(x @ W0 + b0); x[N,128], W0[128,64]. 64 nodes/block.
__global__ __launch_bounds__(256) void k_gemm1(const float* __restrict__ x,
                                               const float* __restrict__ W0,
                                               const float* __restrict__ b0,
                                               float* __restrict__ h0, int N) {
    __shared__ float wl[128 * 64];   // [k][c]
    __shared__ float al[64 * 132];   // [node][k] padded
    int t = threadIdx.x;
    int n0 = blockIdx.x * 64;
    const float4* wg = (const float4*)W0;
    float4* wl4 = (float4*)wl;
#pragma unroll
    for (int i = 0; i < 8; ++i) wl4[t + i * 256] = wg[t + i * 256];
#pragma unroll
    for (int i = 0; i < 8; ++i) {
        int f = t + i * 256;
        int node = f >> 5, q = f & 31;
        int ng = n0 + node; if (ng > N - 1) ng = N - 1;
        float4 v = ((const float4*)x)[(size_t)ng * 32 + q];
        *(float4*)&al[node * 132 + q * 4] = v;
    }
    __syncthreads();
    int colg = t & 15;   // cols colg*4..+3
    int rowg = t >> 4;   // rows rowg*4..+3
    float4 acc[4];
#pragma unroll
    for (int j = 0; j < 4; ++j) acc[j] = make_float4(0.f, 0.f, 0.f, 0.f);
    for (int k4 = 0; k4 < 128; k4 += 4) {
        float4 w0 = *(float4*)&wl[(k4 + 0) * 64 + colg * 4];
        float4 w1 = *(float4*)&wl[(k4 + 1) * 64 + colg * 4];
        float4 w2 = *(float4*)&wl[(k4 + 2) * 64 + colg * 4];
        float4 w3 = *(float4*)&wl[(k4 + 3) * 64 + colg * 4];
#pragma unroll
        for (int j = 0; j < 4; ++j) {
            float4 a = *(float4*)&al[(rowg * 4 + j) * 132 + k4];
            acc[j].x += a.x * w0.x + a.y * w1.x + a.z * w2.x + a.w * w3.x;
            acc[j].y += a.x * w0.y + a.y * w1.y + a.z * w2.y + a.w * w3.y;
            acc[j].z += a.x * w0.z + a.y * w1.z + a.z * w2.z + a.w * w3.z;
            acc[j].w += a.x * w0.w + a.y * w1.w + a.z * w2.w + a.w * w3.w;
        }
    }
    float4 bb = ((const float4*)b0)[colg];
#pragma unroll
    for (int j = 0; j < 4; ++j) {
        int n = n0 + rowg * 4 + j;
        if (n < N) {
            float4 r;
            r.x = fmaxf(acc[j].x + bb.x, 0.f);
            r.y = fmaxf(acc[j].y + bb.y, 0.f);
            r.z = fmaxf(acc[j].z + bb.z, 0.f);
            r.w = fmaxf(acc[j].w + bb.w, 0.f);
            ((float4*)h0)[(size_t)n * 16 + colg] = r;
        }
    }
}

// h1 = h0 @ W1 (stored bf16) + fused att1 dots. h0[N,64], W1[64,128].
__global__ __launch_bounds__(256) void k_gemm2(const float* __restrict__ h0,
                                               const float* __restrict__ W1,
                                               const float* __restrict__ as_g,
                                               const float* __restrict__ ad_g,
                                               ushort_t* __restrict__ h1b,
                                               float* __restrict__ as1,
                                               float* __restrict__ ad1, int N) {
    __shared__ float wl[64 * 128];  // [k][c]
    __shared__ float al[64 * 68];   // [node][k] padded
    int t = threadIdx.x;
    int n0 = blockIdx.x * 64;
    const float4* wg = (const float4*)W1;
    float4* wl4 = (float4*)wl;
#pragma unroll
    for (int i = 0; i < 8; ++i) wl4[t + i * 256] = wg[t + i * 256];
#pragma unroll
    for (int i = 0; i < 4; ++i) {
        int f = t + i * 256;
        int node = f >> 4, q = f & 15;
        int ng = n0 + node; if (ng > N - 1) ng = N - 1;
        float4 v = ((const float4*)h0)[(size_t)ng * 16 + q];
        *(float4*)&al[node * 68 + q * 4] = v;
    }
    __syncthreads();
    int colg = t & 31;   // cols colg*4..+3 (head = colg>=16)
    int rowg = t >> 5;   // rows rowg*8..+7
    float4 acc[8];
#pragma unroll
    for (int j = 0; j < 8; ++j) acc[j] = make_float4(0.f, 0.f, 0.f, 0.f);
    for (int k4 = 0; k4 < 64; k4 += 4) {
        float4 w0 = *(float4*)&wl[(k4 + 0) * 128 + colg * 4];
        float4 w1 = *(float4*)&wl[(k4 + 1) * 128 + colg * 4];
        float4 w2 = *(float4*)&wl[(k4 + 2) * 128 + colg * 4];
        float4 w3 = *(float4*)&wl[(k4 + 3) * 128 + colg * 4];
#pragma unroll
        for (int j = 0; j < 8; ++j) {
            float4 a = *(float4*)&al[(rowg * 8 + j) * 68 + k4];
            acc[j].x += a.x * w0.x + a.y * w1.x + a.z * w2.x + a.w * w3.x;
            acc[j].y += a.x * w0.y + a.y * w1.y + a.z * w2.y + a.w * w3.y;
            acc[j].z += a.x * w0.z + a.y * w1.z + a.z * w2.z + a.w * w3.z;
            acc[j].w += a.x * w0.w + a.y * w1.w + a.z * w2.w + a.w * w3.w;
        }
    }
    float4 asv = ((const float4*)as_g)[colg];
    float4 adv = ((const float4*)ad_g)[colg];
    float ps[8], pd[8];
#pragma unroll
    for (int j = 0; j < 8; ++j) {
        ps[j] = acc[j].x * asv.x + acc[j].y * asv.y + acc[j].z * asv.z + acc[j].w * asv.w;
        pd[j] = acc[j].x * adv.x + acc[j].y * adv.y + acc[j].z * adv.z + acc[j].w * adv.w;
    }
    for (int o = 1; o < 16; o <<= 1) {
#pragma unroll
        for (int j = 0; j < 8; ++j) {
            ps[j] += __shfl_xor(ps[j], o);
            pd[j] += __shfl_xor(pd[j], o);
        }
    }
#pragma unroll
    for (int j = 0; j < 8; ++j) {
        int n = n0 + rowg * 8 + j;
        if (n < N) {
            uint2 pr;
            pr.x = bfpack(acc[j].x, acc[j].y);
            pr.y = bfpack(acc[j].z, acc[j].w);
            ((uint2*)h1b)[(size_t)n * 32 + colg] = pr;  // 32 uint2 per row
        }
    }
    int lane = t & 63;
    if ((lane & 15) == 0) {
        int head = (lane >> 4) & 1;
#pragma unroll
        for (int j = 0; j < 8; ++j) {
            int n = n0 + rowg * 8 + j;
            if (n < N) {
                as1[n * 2 + head] = ps[j];
                ad1[n * 2 + head] = pd[j];
            }
        }
    }
}

// ---- layer-1 fused: per-node online softmax + aggregation + bias + ELU ----
__global__ __launch_bounds__(256) void k_node_l1(const int* __restrict__ rs,
                                                 const int* __restrict__ csr,
                                                 const ushort_t* __restrict__ h1b,
                                                 const float* __restrict__ as1,
                                                 const float* __restrict__ ad1,
                                                 const float* __restrict__ b1,
                                                 float* __restrict__ agg, int N) {
    int lane = threadIdx.x & 63;
    int n = (blockIdx.x * 256 + threadIdx.x) >> 6;
    if (n >= N) return;
    int row = rs[n], end = rs[n + 1];
    float2 adv = ((const float2*)ad1)[n];
    const float2* asp = (const float2*)as1;
    const unsigned* h1u = (const unsigned*)h1b;
    bool head1 = lane >= 32;
    float m0 = -INFINITY, m1 = -INFINITY, l0 = 0.f, l1 = 0.f;
    float accx = 0.f, accy = 0.f;
    for (int base = row; base < end; base += 64) {
        int idx = base + lane;
        bool act = idx < end;
        int src = act ? csr[idx] : 0;
        float2 av = asp[src];
        float e0 = av.x + adv.x, e1 = av.y + adv.y;
        e0 = e0 > 0.f ? e0 : NEG_SLOPE * e0;
        e1 = e1 > 0.f ? e1 : NEG_SLOPE * e1;
        if (!act) { e0 = -INFINITY; e1 = -INFINITY; }
        float m0n = fmaxf(m0, wmax(e0));
        float m1n = fmaxf(m1, wmax(e1));
        float r0 = __expf(m0 - m0n), r1 = __expf(m1 - m1n);
        float p0 = act ? __expf(e0 - m0n) : 0.f;
        float p1 = act ? __expf(e1 - m1n) : 0.f;
        l0 = l0 * r0 + wsum(p0);
        l1 = l1 * r1 + wsum(p1);
        float rr = head1 ? r1 : r0;
        accx *= rr; accy *= rr;
        int cnt = min(64, end - base);
#pragma unroll 4
        for (int j = 0; j < cnt; ++j) {
            int sj = __shfl(src, j);
            float a0j = __shfl(p0, j);
            float a1j = __shfl(p1, j);
            float aj = head1 ? a1j : a0j;
            unsigned u = h1u[(size_t)sj * 64 + lane];
            accx += bflo(u) * aj;
            accy += bfhi(u) * aj;
        }
        m0 = m0n; m1 = m1n;
    }
    float inv = 1.f / (head1 ? l1 : l0);
    float vx = accx * inv + b1[lane * 2];
    float vy = accy * inv + b1[lane * 2 + 1];
    vx = vx > 0.f ? vx : expm1f(vx);
    vy = vy > 0.f ? vy : expm1f(vy);
    float2 r; r.x = vx; r.y = vy;
    ((float2*)(agg + (size_t)n * 128))[lane] = r;
}

// h2 = h1act @ W2 (stored bf16, stride 24) + att2 dots. 64 nodes/block.
__global__ __launch_bounds__(256, 4) void k_node2(const float* __restrict__ h1a,
                                                  const float* __restrict__ W2,
                                                  const float* __restrict__ as_g,
                                                  const float* __restrict__ ad_g,
                                                  ushort_t* __restrict__ h2b,
                                                  float* __restrict__ a_s,
                                                  float* __restrict__ a_d, int N) {
    __shared__ float al[64 * 132];   // [node][k] padded
    __shared__ float w2t[20 * 132];  // [c][k] padded, cols 18,19 zero
    int t = threadIdx.x;
    int n0 = blockIdx.x * 64;
#pragma unroll
    for (int i = 0; i < 8; ++i) {
        int f = t + i * 256;
        int node = f >> 5, q = f & 31;
        int ng = n0 + node; if (ng > N - 1) ng = N - 1;
        float4 v = ((const float4*)h1a)[(size_t)ng * 32 + q];
        *(float4*)&al[node * 132 + q * 4] = v;
    }
    for (int i = t; i < 2560; i += 256) {
        int c = i >> 7, k = i & 127;
        w2t[c * 132 + k] = (c < 18) ? W2[k * 18 + c] : 0.f;
    }
    __syncthreads();
    int node = t >> 2;
    int cq = t & 3;
    int c0 = cq * 5;  // cols c0..c0+4 (cq==3: cols 15..19, 18/19 dead)
    int n = n0 + node;
    float acc[5] = {0.f, 0.f, 0.f, 0.f, 0.f};
#pragma unroll 2
    for (int k4 = 0; k4 < 128; k4 += 4) {
        float4 a = *(float4*)&al[node * 132 + k4];
#pragma unroll
        for (int i = 0; i < 5; ++i) {
            float4 w = *(float4*)&w2t[(c0 + i) * 132 + k4];
            acc[i] += a.x * w.x + a.y * w.y + a.z * w.z + a.w * w.w;
        }
    }
    float ps = 0.f, pd = 0.f;
#pragma unroll
    for (int i = 0; i < 5; ++i) {
        int c = c0 + i;
        float asv = (c < 18) ? as_g[c] : 0.f;
        float adv = (c < 18) ? ad_g[c] : 0.f;
        ps += acc[i] * asv;
        pd += acc[i] * adv;
    }
    ps += __shfl_xor(ps, 1); ps += __shfl_xor(ps, 2);
    pd += __shfl_xor(pd, 1); pd += __shfl_xor(pd, 2);
    if (n < N) {
#pragma unroll
        for (int i = 0; i < 5; ++i) {
            int c = c0 + i;
            if (c < 18) h2b[(size_t)n * 24 + c] = bf16of(acc[i]);
        }
        if (cq == 0) { a_s[n] = ps; a_d[n] = pd; }
    }
}

// ---- layer-2 fused, v2: phase A (m,l) + channel-parallel phase B ----
__global__ __launch_bounds__(256) void k_node_l2(const int* __restrict__ rs,
                                                 const int* __restrict__ csr,
                                                 const ushort_t* __restrict__ h2b,
                                                 const float* __restrict__ as2,
                                                 const float* __restrict__ ad2,
                                                 const float* __restrict__ b2,
                                                 float* __restrict__ out, int N) {
    int lane = threadIdx.x & 63;
    int n = (blockIdx.x * 256 + threadIdx.x) >> 6;
    if (n >= N) return;
    int row = rs[n], end = rs[n + 1];
    float adn = ad2[n];
    // ---- phase A: online (m, l), edge-parallel ----
    float m = -INFINITY, l = 0.f;
    for (int base = row; base < end; base += 64) {
        int idx = base + lane;
        bool act = idx < end;
        int src = act ? csr[idx] : 0;
        float e = as2[src] + adn;
        e = e > 0.f ? e : NEG_SLOPE * e;
        if (!act) e = -INFINITY;
        float mn = fmaxf(m, wmax(e));
        float p = act ? __expf(e - mn) : 0.f;
        l = l * __expf(m - mn) + wsum(p);
        m = mn;
    }
    float invl = 1.f / l;
    // ---- phase B: 3 edge-groups x 21 lanes (c<18 live) ----
    int g = lane / 21;            // 0..3 (lane 63 -> g=3, result discarded)
    int c = lane - g * 21;        // 0..20
    int cc = c < 18 ? c : 17;     // clamp for safe loads
    float acc = 0.f;
    for (int pos = row + g; pos < end; pos += 3) {
        int src = csr[pos];       // 3 distinct addrs per wave
        float e = as2[src] + adn;
        e = e > 0.f ? e : NEG_SLOPE * e;
        float alpha = __expf(e - m) * invl;
        acc += alpha * bfval(h2b[(size_t)src * 24 + cc]);
    }
    // group-sum into lanes 0..17: BOTH shfls must read pre-mutation acc
    // (R6 bug: chained += made the 2nd shfl read an already-summed value)
    float t1 = __shfl(acc, (lane + 21) & 63);
    float t2 = __shfl(acc, (lane + 42) & 63);
    acc += t1 + t2;
    float bb = (lane < 18) ? b2[lane] : 0.f;
    float v = acc + bb;
    // ---- lane-parallel log-softmax over lanes 0..17 (32-lane xor net) ----
    float tmx = (lane < 18) ? v : -INFINITY;
    for (int o = 16; o; o >>= 1) tmx = fmaxf(tmx, __shfl_xor(tmx, o));
    float s = (lane < 18) ? __expf(v - tmx) : 0.f;
    for (int o = 16; o; o >>= 1) s += __shfl_xor(s, o);
    float lse = tmx + __logf(s);
    if (lane < 18) out[(size_t)n * 18 + lane] = v - lse;
}

extern "C" void kernel_launch(void* const* d_in, const int* in_sizes, int n_in,
                              void* d_out, int out_size, void* d_ws, size_t ws_size,
                              hipStream_t stream) {
    const float* x      = (const float*)d_in[0];
    const int*   ei     = (const int*)d_in[1];
    const float* W0     = (const float*)d_in[2];
    const float* b0     = (const float*)d_in[3];
    const float* W1     = (const float*)d_in[4];
    const float* att_s1 = (const float*)d_in[5];
    const float* att_d1 = (const float*)d_in[6];
    const float* b1     = (const float*)d_in[7];
    const float* W2     = (const float*)d_in[8];
    const float* att_s2 = (const float*)d_in[9];
    const float* att_d2 = (const float*)d_in[10];
    const float* b2     = (const float*)d_in[11];

    const int N = in_sizes[0] / 128;
    const int E = in_sizes[1] / 2;
    const int Etot = E + N;
    const int NB = (N + 1023) / 1024;  // scan blocks (<= 256)
    const int NBLK = (N + 63) / 64;    // dense tiles

    // workspace carve-up (~125 MB)
    char* w = (char*)d_ws;
    float* h0      = (float*)w;    w += (size_t)N * 64 * 4;
    ushort_t* h1b  = (ushort_t*)w; w += (size_t)N * 128 * 2;
    float* agg1    = (float*)w;    w += (size_t)N * 128 * 4;
    float* as1     = (float*)w;    w += (size_t)N * 2 * 4;
    float* ad1     = (float*)w;    w += (size_t)N * 2 * 4;
    ushort_t* h2b  = (ushort_t*)w; w += (size_t)N * 24 * 2;
    float* as2     = (float*)w;    w += (size_t)N * 4;
    float* ad2     = (float*)w;    w += (size_t)N * 4;
    int* deg       = (int*)w;      w += (size_t)N * 4;
    int* rs        = (int*)w;      w += (size_t)(N + 1) * 4;
    int* bsum      = (int*)w;      w += (size_t)256 * 4;
    int* boff      = (int*)w;      w += (size_t)256 * 4;
    int* eofs      = (int*)w;      w += (size_t)E * 4;
    int* csr       = (int*)w;      w += (size_t)Etot * 4;

    float* out = (float*)d_out;

    // ---- CSR build ----
    k_deg_init<<<(N + 255) / 256, 256, 0, stream>>>(deg, N);
    k_deg_edges<<<(E + 255) / 256, 256, 0, stream>>>(ei, deg, eofs, E);
    k_scan1<<<NB, 256, 0, stream>>>(deg, rs, bsum, N);
    k_scan2<<<1, 256, 0, stream>>>(bsum, boff, NB);
    k_scan3<<<(N + 255) / 256, 256, 0, stream>>>(rs, boff, N);
    const int cohortBlocks = 128;
    k_scatter<<<8 * cohortBlocks, 256, 0, stream>>>(ei, eofs, rs, csr, E, Etot, cohortBlocks);

    // ---- dense ----
    k_gemm1<<<NBLK, 256, 0, stream>>>(x, W0, b0, h0, N);
    k_gemm2<<<NBLK, 256, 0, stream>>>(h0, W1, att_s1, att_d1, h1b, as1, ad1, N);

    // ---- layer 1 fused edge pass ----
    k_node_l1<<<(N * 64 + 255) / 256, 256, 0, stream>>>(rs, csr, h1b, as1, ad1, b1, agg1, N);

    // ---- layer 2 dense + fused edge pass ----
    k_node2<<<NBLK, 256, 0, stream>>>(agg1, W2, att_s2, att_d2, h2b, as2, ad2, N);
    k_node_l2<<<(N * 64 + 255) / 256, 256, 0, stream>>>(rs, csr, h2b, as2, ad2, b2, out, N);
}

// Round 9
// 478.219 us; speedup vs baseline: 3.9557x; 1.0957x over previous
//
#include <hip/hip_runtime.h>
#include <math.h>

// GAT 2-layer: N=100000, E=1600000 (+N self loops), F_IN=128, HID=64, HEADS=2,
// OUT_HEADS=1, NUM_CLASS=18, NEG_SLOPE=0.2
// Round 8: k_node_l1 two-pass restructure (was 130us, inst/latency-bound,
// 3 shfls per edge in the hot loop). Pass 1: final (m,l) edge-parallel.
// Pass 2: alpha computed once per edge, (src,alpha) stashed in per-wave LDS,
// feature loop = ds_read_b64 + load + 2 FMA. No online rescaling, no shfls.

#define NEG_SLOPE 0.2f

typedef unsigned short ushort_t;

// ---------------- wave reductions (64 lanes) ----------------
__device__ __forceinline__ float wmax(float v) {
    for (int o = 32; o; o >>= 1) v = fmaxf(v, __shfl_xor(v, o));
    return v;
}
__device__ __forceinline__ float wsum(float v) {
    for (int o = 32; o; o >>= 1) v += __shfl_xor(v, o);
    return v;
}

// ---------------- bf16 helpers (RNE) ----------------
__device__ __forceinline__ unsigned bfpack(float a, float b) {
    unsigned ua = __float_as_uint(a);
    unsigned ub = __float_as_uint(b);
    ua = (ua + 0x7fffu + ((ua >> 16) & 1u)) >> 16;
    ub = (ub + 0x7fffu + ((ub >> 16) & 1u)) & 0xffff0000u;
    return ua | ub;
}
__device__ __forceinline__ ushort_t bf16of(float a) {
    unsigned ua = __float_as_uint(a);
    return (ushort_t)((ua + 0x7fffu + ((ua >> 16) & 1u)) >> 16);
}
__device__ __forceinline__ float bflo(unsigned u) { return __uint_as_float(u << 16); }
__device__ __forceinline__ float bfhi(unsigned u) { return __uint_as_float(u & 0xffff0000u); }
__device__ __forceinline__ float bfval(ushort_t u) { return __uint_as_float(((unsigned)u) << 16); }

// ---------------- CSR build ----------------
__global__ void k_deg_init(int* __restrict__ deg, int N) {
    int i = blockIdx.x * blockDim.x + threadIdx.x;
    if (i < N) deg[i] = 1;  // slot 0 reserved for self loop
}
__global__ void k_deg_edges(const int* __restrict__ ei, int* __restrict__ deg,
                            int* __restrict__ eofs, int E) {
    int e = blockIdx.x * blockDim.x + threadIdx.x;
    if (e < E) eofs[e] = atomicAdd(&deg[ei[E + e]], 1);
}

__global__ __launch_bounds__(256) void k_scan1(const int* __restrict__ deg, int* __restrict__ rs,
                                               int* __restrict__ bsum, int N) {
    __shared__ int s[256];
    int t = threadIdx.x;
    int base = blockIdx.x * 1024;
    int i0 = base + t * 4;
    int d0 = (i0 + 0 < N) ? deg[i0 + 0] : 0;
    int d1 = (i0 + 1 < N) ? deg[i0 + 1] : 0;
    int d2 = (i0 + 2 < N) ? deg[i0 + 2] : 0;
    int d3 = (i0 + 3 < N) ? deg[i0 + 3] : 0;
    int s0 = d0, s1 = s0 + d1, s2 = s1 + d2, s3 = s2 + d3;
    int tsum = s3;
    s[t] = tsum;
    __syncthreads();
    for (int off = 1; off < 256; off <<= 1) {
        int v = (t >= off) ? s[t - off] : 0;
        __syncthreads();
        s[t] += v;
        __syncthreads();
    }
    int excl = s[t] - tsum;
    if (i0 + 0 < N) rs[1 + i0 + 0] = excl + s0;
    if (i0 + 1 < N) rs[1 + i0 + 1] = excl + s1;
    if (i0 + 2 < N) rs[1 + i0 + 2] = excl + s2;
    if (i0 + 3 < N) rs[1 + i0 + 3] = excl + s3;
    if (t == 0) bsum[blockIdx.x] = s[255];
}

__global__ __launch_bounds__(256) void k_scan2(const int* __restrict__ bsum,
                                               int* __restrict__ boff, int NB) {
    __shared__ int s[256];
    int t = threadIdx.x;
    int orig = (t < NB) ? bsum[t] : 0;
    s[t] = orig;
    __syncthreads();
    for (int off = 1; off < 256; off <<= 1) {
        int v = (t >= off) ? s[t - off] : 0;
        __syncthreads();
        s[t] += v;
        __syncthreads();
    }
    if (t < NB) boff[t] = s[t] - orig;  // exclusive
}

__global__ void k_scan3(int* __restrict__ rs, const int* __restrict__ boff, int N) {
    int i = blockIdx.x * blockDim.x + threadIdx.x;
    if (i == 0) rs[0] = 0;
    if (i < N) rs[1 + i] += boff[i >> 10];
}

// slice-filtered, atomic-free scatter (csr lines stay in one XCD L2).
__global__ __launch_bounds__(256) void k_scatter(const int* __restrict__ ei,
                                                 const int* __restrict__ eofs,
                                                 const int* __restrict__ rs,
                                                 int* __restrict__ csr,
                                                 int E, int Etot, int cohortBlocks) {
    int c = blockIdx.x & 7;
    int pb = blockIdx.x >> 3;
    int tid = pb * 256 + threadIdx.x;
    int stride = cohortBlocks * 256;
    for (int e = tid; e < Etot; e += stride) {
        int dst = (e < E) ? ei[E + e] : (e - E);
        if (((dst >> 13) & 7) != c) continue;
        int src, ofs;
        if (e < E) { src = ei[e]; ofs = eofs[e]; } else { src = dst; ofs = 0; }
        csr[rs[dst] + ofs] = src;
    }
}

// ---------------- dense kernels (register-tiled) ----------------

// h0 = relu(x @ W0 + b0); x[N,128], W0[128,64]. 64 nodes/block.
__global__ __launch_bounds__(256) void k_gemm1(const float* __restrict__ x,
                                               const float* __restrict__ W0,
                                               const float* __restrict__ b0,
                                               float* __restrict__ h0, int N) {
    __shared__ float wl[128 * 64];   // [k][c]
    __shared__ float al[64 * 132];   // [node][k] padded
    int t = threadIdx.x;
    int n0 = blockIdx.x * 64;
    const float4* wg = (const float4*)W0;
    float4* wl4 = (float4*)wl;
#pragma unroll
    for (int i = 0; i < 8; ++i) wl4[t + i * 256] = wg[t + i * 256];
#pragma unroll
    for (int i = 0; i < 8; ++i) {
        int f = t + i * 256;
        int node = f >> 5, q = f & 31;
        int ng = n0 + node; if (ng > N - 1) ng = N - 1;
        float4 v = ((const float4*)x)[(size_t)ng * 32 + q];
        *(float4*)&al[node * 132 + q * 4] = v;
    }
    __syncthreads();
    int colg = t & 15;   // cols colg*4..+3
    int rowg = t >> 4;   // rows rowg*4..+3
    float4 acc[4];
#pragma unroll
    for (int j = 0; j < 4; ++j) acc[j] = make_float4(0.f, 0.f, 0.f, 0.f);
    for (int k4 = 0; k4 < 128; k4 += 4) {
        float4 w0 = *(float4*)&wl[(k4 + 0) * 64 + colg * 4];
        float4 w1 = *(float4*)&wl[(k4 + 1) * 64 + colg * 4];
        float4 w2 = *(float4*)&wl[(k4 + 2) * 64 + colg * 4];
        float4 w3 = *(float4*)&wl[(k4 + 3) * 64 + colg * 4];
#pragma unroll
        for (int j = 0; j < 4; ++j) {
            float4 a = *(float4*)&al[(rowg * 4 + j) * 132 + k4];
            acc[j].x += a.x * w0.x + a.y * w1.x + a.z * w2.x + a.w * w3.x;
            acc[j].y += a.x * w0.y + a.y * w1.y + a.z * w2.y + a.w * w3.y;
            acc[j].z += a.x * w0.z + a.y * w1.z + a.z * w2.z + a.w * w3.z;
            acc[j].w += a.x * w0.w + a.y * w1.w + a.z * w2.w + a.w * w3.w;
        }
    }
    float4 bb = ((const float4*)b0)[colg];
#pragma unroll
    for (int j = 0; j < 4; ++j) {
        int n = n0 + rowg * 4 + j;
        if (n < N) {
            float4 r;
            r.x = fmaxf(acc[j].x + bb.x, 0.f);
            r.y = fmaxf(acc[j].y + bb.y, 0.f);
            r.z = fmaxf(acc[j].z + bb.z, 0.f);
            r.w = fmaxf(acc[j].w + bb.w, 0.f);
            ((float4*)h0)[(size_t)n * 16 + colg] = r;
        }
    }
}

// h1 = h0 @ W1 (stored bf16) + fused att1 dots. h0[N,64], W1[64,128].
__global__ __launch_bounds__(256) void k_gemm2(const float* __restrict__ h0,
                                               const float* __restrict__ W1,
                                               const float* __restrict__ as_g,
                                               const float* __restrict__ ad_g,
                                               ushort_t* __restrict__ h1b,
                                               float* __restrict__ as1,
                                               float* __restrict__ ad1, int N) {
    __shared__ float wl[64 * 128];  // [k][c]
    __shared__ float al[64 * 68];   // [node][k] padded
    int t = threadIdx.x;
    int n0 = blockIdx.x * 64;
    const float4* wg = (const float4*)W1;
    float4* wl4 = (float4*)wl;
#pragma unroll
    for (int i = 0; i < 8; ++i) wl4[t + i * 256] = wg[t + i * 256];
#pragma unroll
    for (int i = 0; i < 4; ++i) {
        int f = t + i * 256;
        int node = f >> 4, q = f & 15;
        int ng = n0 + node; if (ng > N - 1) ng = N - 1;
        float4 v = ((const float4*)h0)[(size_t)ng * 16 + q];
        *(float4*)&al[node * 68 + q * 4] = v;
    }
    __syncthreads();
    int colg = t & 31;   // cols colg*4..+3 (head = colg>=16)
    int rowg = t >> 5;   // rows rowg*8..+7
    float4 acc[8];
#pragma unroll
    for (int j = 0; j < 8; ++j) acc[j] = make_float4(0.f, 0.f, 0.f, 0.f);
    for (int k4 = 0; k4 < 64; k4 += 4) {
        float4 w0 = *(float4*)&wl[(k4 + 0) * 128 + colg * 4];
        float4 w1 = *(float4*)&wl[(k4 + 1) * 128 + colg * 4];
        float4 w2 = *(float4*)&wl[(k4 + 2) * 128 + colg * 4];
        float4 w3 = *(float4*)&wl[(k4 + 3) * 128 + colg * 4];
#pragma unroll
        for (int j = 0; j < 8; ++j) {
            float4 a = *(float4*)&al[(rowg * 8 + j) * 68 + k4];
            acc[j].x += a.x * w0.x + a.y * w1.x + a.z * w2.x + a.w * w3.x;
            acc[j].y += a.x * w0.y + a.y * w1.y + a.z * w2.y + a.w * w3.y;
            acc[j].z += a.x * w0.z + a.y * w1.z + a.z * w2.z + a.w * w3.z;
            acc[j].w += a.x * w0.w + a.y * w1.w + a.z * w2.w + a.w * w3.w;
        }
    }
    float4 asv = ((const float4*)as_g)[colg];
    float4 adv = ((const float4*)ad_g)[colg];
    float ps[8], pd[8];
#pragma unroll
    for (int j = 0; j < 8; ++j) {
        ps[j] = acc[j].x * asv.x + acc[j].y * asv.y + acc[j].z * asv.z + acc[j].w * asv.w;
        pd[j] = acc[j].x * adv.x + acc[j].y * adv.y + acc[j].z * adv.z + acc[j].w * adv.w;
    }
    for (int o = 1; o < 16; o <<= 1) {
#pragma unroll
        for (int j = 0; j < 8; ++j) {
            ps[j] += __shfl_xor(ps[j], o);
            pd[j] += __shfl_xor(pd[j], o);
        }
    }
#pragma unroll
    for (int j = 0; j < 8; ++j) {
        int n = n0 + rowg * 8 + j;
        if (n < N) {
            uint2 pr;
            pr.x = bfpack(acc[j].x, acc[j].y);
            pr.y = bfpack(acc[j].z, acc[j].w);
            ((uint2*)h1b)[(size_t)n * 32 + colg] = pr;  // 32 uint2 per row
        }
    }
    int lane = t & 63;
    if ((lane & 15) == 0) {
        int head = (lane >> 4) & 1;
#pragma unroll
        for (int j = 0; j < 8; ++j) {
            int n = n0 + rowg * 8 + j;
            if (n < N) {
                as1[n * 2 + head] = ps[j];
                ad1[n * 2 + head] = pd[j];
            }
        }
    }
}

// ---- layer-1 fused, v2: two-pass, LDS alpha stash, shfl-free hot loop ----
__global__ __launch_bounds__(256) void k_node_l1(const int* __restrict__ rs,
                                                 const int* __restrict__ csr,
                                                 const ushort_t* __restrict__ h1b,
                                                 const float* __restrict__ as1,
                                                 const float* __restrict__ ad1,
                                                 const float* __restrict__ b1,
                                                 float* __restrict__ agg, int N) {
    __shared__ float2 stash[4][128];  // per wave: [head][64 edges] (src bits, alpha)
    int wid = threadIdx.x >> 6;
    int lane = threadIdx.x & 63;
    int n = (blockIdx.x * 256 + threadIdx.x) >> 6;
    if (n >= N) return;
    int row = rs[n], end = rs[n + 1];
    float2 adv = ((const float2*)ad1)[n];
    const float2* asp = (const float2*)as1;
    const unsigned* h1u = (const unsigned*)h1b;
    // ---- pass 1: final (m0,m1,l0,l1), edge-parallel, no payload ----
    float m0 = -INFINITY, m1 = -INFINITY, l0 = 0.f, l1 = 0.f;
    for (int base = row; base < end; base += 64) {
        int idx = base + lane;
        bool act = idx < end;
        int src = act ? csr[idx] : 0;
        float2 av = asp[src];
        float e0 = av.x + adv.x, e1 = av.y + adv.y;
        e0 = e0 > 0.f ? e0 : NEG_SLOPE * e0;
        e1 = e1 > 0.f ? e1 : NEG_SLOPE * e1;
        if (!act) { e0 = -INFINITY; e1 = -INFINITY; }
        float m0n = fmaxf(m0, wmax(e0));
        float m1n = fmaxf(m1, wmax(e1));
        float p0 = act ? __expf(e0 - m0n) : 0.f;
        float p1 = act ? __expf(e1 - m1n) : 0.f;
        l0 = l0 * __expf(m0 - m0n) + wsum(p0);
        l1 = l1 * __expf(m1 - m1n) + wsum(p1);
        m0 = m0n; m1 = m1n;
    }
    float inv0 = 1.f / l0, inv1 = 1.f / l1;
    // ---- pass 2: per chunk, stash (src, alpha) to LDS; shfl-free j-loop ----
    bool head1 = lane >= 32;
    float accx = 0.f, accy = 0.f;
    const float2* sp = &stash[wid][head1 ? 64 : 0];
    for (int base = row; base < end; base += 64) {
        int idx = base + lane;
        bool act = idx < end;
        int src = act ? csr[idx] : 0;
        float2 av = asp[src];
        float e0 = av.x + adv.x, e1 = av.y + adv.y;
        e0 = e0 > 0.f ? e0 : NEG_SLOPE * e0;
        e1 = e1 > 0.f ? e1 : NEG_SLOPE * e1;
        float a0 = act ? __expf(e0 - m0) * inv0 : 0.f;
        float a1 = act ? __expf(e1 - m1) * inv1 : 0.f;
        stash[wid][lane] = make_float2(__int_as_float(src), a0);
        stash[wid][64 + lane] = make_float2(__int_as_float(src), a1);
        // same-wave LDS write->read: in-order DS ops, no barrier needed
        int cnt = min(64, end - base);
#pragma unroll 4
        for (int j = 0; j < cnt; ++j) {
            float2 sa = sp[j];
            int sj = __float_as_int(sa.x);
            float aj = sa.y;
            unsigned u = h1u[(size_t)sj * 64 + lane];
            accx += bflo(u) * aj;
            accy += bfhi(u) * aj;
        }
    }
    float vx = accx + b1[lane * 2];
    float vy = accy + b1[lane * 2 + 1];
    vx = vx > 0.f ? vx : expm1f(vx);
    vy = vy > 0.f ? vy : expm1f(vy);
    float2 r; r.x = vx; r.y = vy;
    ((float2*)(agg + (size_t)n * 128))[lane] = r;
}

// h2 = h1act @ W2 (stored bf16, stride 24) + att2 dots. 64 nodes/block.
__global__ __launch_bounds__(256, 4) void k_node2(const float* __restrict__ h1a,
                                                  const float* __restrict__ W2,
                                                  const float* __restrict__ as_g,
                                                  const float* __restrict__ ad_g,
                                                  ushort_t* __restrict__ h2b,
                                                  float* __restrict__ a_s,
                                                  float* __restrict__ a_d, int N) {
    __shared__ float al[64 * 132];   // [node][k] padded
    __shared__ float w2t[20 * 132];  // [c][k] padded, cols 18,19 zero
    int t = threadIdx.x;
    int n0 = blockIdx.x * 64;
#pragma unroll
    for (int i = 0; i < 8; ++i) {
        int f = t + i * 256;
        int node = f >> 5, q = f & 31;
        int ng = n0 + node; if (ng > N - 1) ng = N - 1;
        float4 v = ((const float4*)h1a)[(size_t)ng * 32 + q];
        *(float4*)&al[node * 132 + q * 4] = v;
    }
    for (int i = t; i < 2560; i += 256) {
        int c = i >> 7, k = i & 127;
        w2t[c * 132 + k] = (c < 18) ? W2[k * 18 + c] : 0.f;
    }
    __syncthreads();
    int node = t >> 2;
    int cq = t & 3;
    int c0 = cq * 5;  // cols c0..c0+4 (cq==3: cols 15..19, 18/19 dead)
    int n = n0 + node;
    float acc[5] = {0.f, 0.f, 0.f, 0.f, 0.f};
#pragma unroll 2
    for (int k4 = 0; k4 < 128; k4 += 4) {
        float4 a = *(float4*)&al[node * 132 + k4];
#pragma unroll
        for (int i = 0; i < 5; ++i) {
            float4 w = *(float4*)&w2t[(c0 + i) * 132 + k4];
            acc[i] += a.x * w.x + a.y * w.y + a.z * w.z + a.w * w.w;
        }
    }
    float ps = 0.f, pd = 0.f;
#pragma unroll
    for (int i = 0; i < 5; ++i) {
        int c = c0 + i;
        float asv = (c < 18) ? as_g[c] : 0.f;
        float adv = (c < 18) ? ad_g[c] : 0.f;
        ps += acc[i] * asv;
        pd += acc[i] * adv;
    }
    ps += __shfl_xor(ps, 1); ps += __shfl_xor(ps, 2);
    pd += __shfl_xor(pd, 1); pd += __shfl_xor(pd, 2);
    if (n < N) {
#pragma unroll
        for (int i = 0; i < 5; ++i) {
            int c = c0 + i;
            if (c < 18) h2b[(size_t)n * 24 + c] = bf16of(acc[i]);
        }
        if (cq == 0) { a_s[n] = ps; a_d[n] = pd; }
    }
}

// ---- layer-2 fused: phase A (m,l) + channel-parallel phase B ----
__global__ __launch_bounds__(256) void k_node_l2(const int* __restrict__ rs,
                                                 const int* __restrict__ csr,
                                                 const ushort_t* __restrict__ h2b,
                                                 const float* __restrict__ as2,
                                                 const float* __restrict__ ad2,
                                                 const float* __restrict__ b2,
                                                 float* __restrict__ out, int N) {
    int lane = threadIdx.x & 63;
    int n = (blockIdx.x * 256 + threadIdx.x) >> 6;
    if (n >= N) return;
    int row = rs[n], end = rs[n + 1];
    float adn = ad2[n];
    // ---- phase A: online (m, l), edge-parallel ----
    float m = -INFINITY, l = 0.f;
    for (int base = row; base < end; base += 64) {
        int idx = base + lane;
        bool act = idx < end;
        int src = act ? csr[idx] : 0;
        float e = as2[src] + adn;
        e = e > 0.f ? e : NEG_SLOPE * e;
        if (!act) e = -INFINITY;
        float mn = fmaxf(m, wmax(e));
        float p = act ? __expf(e - mn) : 0.f;
        l = l * __expf(m - mn) + wsum(p);
        m = mn;
    }
    float invl = 1.f / l;
    // ---- phase B: 3 edge-groups x 21 lanes (c<18 live) ----
    int g = lane / 21;            // 0..3 (lane 63 -> g=3, result discarded)
    int c = lane - g * 21;        // 0..20
    int cc = c < 18 ? c : 17;     // clamp for safe loads
    float acc = 0.f;
    for (int pos = row + g; pos < end; pos += 3) {
        int src = csr[pos];       // 3 distinct addrs per wave
        float e = as2[src] + adn;
        e = e > 0.f ? e : NEG_SLOPE * e;
        float alpha = __expf(e - m) * invl;
        acc += alpha * bfval(h2b[(size_t)src * 24 + cc]);
    }
    // group-sum into lanes 0..17: both shfls read pre-mutation acc
    float t1 = __shfl(acc, (lane + 21) & 63);
    float t2 = __shfl(acc, (lane + 42) & 63);
    acc += t1 + t2;
    float bb = (lane < 18) ? b2[lane] : 0.f;
    float v = acc + bb;
    // ---- lane-parallel log-softmax over lanes 0..17 (32-lane xor net) ----
    float tmx = (lane < 18) ? v : -INFINITY;
    for (int o = 16; o; o >>= 1) tmx = fmaxf(tmx, __shfl_xor(tmx, o));
    float s = (lane < 18) ? __expf(v - tmx) : 0.f;
    for (int o = 16; o; o >>= 1) s += __shfl_xor(s, o);
    float lse = tmx + __logf(s);
    if (lane < 18) out[(size_t)n * 18 + lane] = v - lse;
}

extern "C" void kernel_launch(void* const* d_in, const int* in_sizes, int n_in,
                              void* d_out, int out_size, void* d_ws, size_t ws_size,
                              hipStream_t stream) {
    const float* x      = (const float*)d_in[0];
    const int*   ei     = (const int*)d_in[1];
    const float* W0     = (const float*)d_in[2];
    const float* b0     = (const float*)d_in[3];
    const float* W1     = (const float*)d_in[4];
    const float* att_s1 = (const float*)d_in[5];
    const float* att_d1 = (const float*)d_in[6];
    const float* b1     = (const float*)d_in[7];
    const float* W2     = (const float*)d_in[8];
    const float* att_s2 = (const float*)d_in[9];
    const float* att_d2 = (const float*)d_in[10];
    const float* b2     = (const float*)d_in[11];

    const int N = in_sizes[0] / 128;
    const int E = in_sizes[1] / 2;
    const int Etot = E + N;
    const int NB = (N + 1023) / 1024;  // scan blocks (<= 256)
    const int NBLK = (N + 63) / 64;    // dense tiles

    // workspace carve-up (~125 MB)
    char* w = (char*)d_ws;
    float* h0      = (float*)w;    w += (size_t)N * 64 * 4;
    ushort_t* h1b  = (ushort_t*)w; w += (size_t)N * 128 * 2;
    float* agg1    = (float*)w;    w += (size_t)N * 128 * 4;
    float* as1     = (float*)w;    w += (size_t)N * 2 * 4;
    float* ad1     = (float*)w;    w += (size_t)N * 2 * 4;
    ushort_t* h2b  = (ushort_t*)w; w += (size_t)N * 24 * 2;
    float* as2     = (float*)w;    w += (size_t)N * 4;
    float* ad2     = (float*)w;    w += (size_t)N * 4;
    int* deg       = (int*)w;      w += (size_t)N * 4;
    int* rs        = (int*)w;      w += (size_t)(N + 1) * 4;
    int* bsum      = (int*)w;      w += (size_t)256 * 4;
    int* boff      = (int*)w;      w += (size_t)256 * 4;
    int* eofs      = (int*)w;      w += (size_t)E * 4;
    int* csr       = (int*)w;      w += (size_t)Etot * 4;

    float* out = (float*)d_out;

    // ---- CSR build ----
    k_deg_init<<<(N + 255) / 256, 256, 0, stream>>>(deg, N);
    k_deg_edges<<<(E + 255) / 256, 256, 0, stream>>>(ei, deg, eofs, E);
    k_scan1<<<NB, 256, 0, stream>>>(deg, rs, bsum, N);
    k_scan2<<<1, 256, 0, stream>>>(bsum, boff, NB);
    k_scan3<<<(N + 255) / 256, 256, 0, stream>>>(rs, boff, N);
    const int cohortBlocks = 128;
    k_scatter<<<8 * cohortBlocks, 256, 0, stream>>>(ei, eofs, rs, csr, E, Etot, cohortBlocks);

    // ---- dense ----
    k_gemm1<<<NBLK, 256, 0, stream>>>(x, W0, b0, h0, N);
    k_gemm2<<<NBLK, 256, 0, stream>>>(h0, W1, att_s1, att_d1, h1b, as1, ad1, N);

    // ---- layer 1 fused edge pass ----
    k_node_l1<<<(N * 64 + 255) / 256, 256, 0, stream>>>(rs, csr, h1b, as1, ad1, b1, agg1, N);

    // ---- layer 2 dense + fused edge pass ----
    k_node2<<<NBLK, 256, 0, stream>>>(agg1, W2, att_s2, att_d2, h2b, as2, ad2, N);
    k_node_l2<<<(N * 64 + 255) / 256, 256, 0, stream>>>(rs, csr, h2b, as2, ad2, b2, out, N);
}

// Round 10
// 451.160 us; speedup vs baseline: 4.1929x; 1.0600x over previous
//
#include <hip/hip_runtime.h>
#include <math.h>

// GAT 2-layer: N=100000, E=1600000 (+N self loops), F_IN=128, HID=64, HEADS=2,
// OUT_HEADS=1, NUM_CLASS=18, NEG_SLOPE=0.2
// Round 9: both edge kernels were latency-bound on redundant dependent global
// loads (csr->as re-gathered in the payload phase). Phase/pass 1 now stashes
// (src, e) in per-wave LDS (128-entry, overflow falls back to global);
// payload phases read the stash. Shortens the per-iteration dependency chain.

#define NEG_SLOPE 0.2f
#define STASH_CAP 128

typedef unsigned short ushort_t;

// ---------------- wave reductions (64 lanes) ----------------
__device__ __forceinline__ float wmax(float v) {
    for (int o = 32; o; o >>= 1) v = fmaxf(v, __shfl_xor(v, o));
    return v;
}
__device__ __forceinline__ float wsum(float v) {
    for (int o = 32; o; o >>= 1) v += __shfl_xor(v, o);
    return v;
}

// ---------------- bf16 helpers (RNE) ----------------
__device__ __forceinline__ unsigned bfpack(float a, float b) {
    unsigned ua = __float_as_uint(a);
    unsigned ub = __float_as_uint(b);
    ua = (ua + 0x7fffu + ((ua >> 16) & 1u)) >> 16;
    ub = (ub + 0x7fffu + ((ub >> 16) & 1u)) & 0xffff0000u;
    return ua | ub;
}
__device__ __forceinline__ ushort_t bf16of(float a) {
    unsigned ua = __float_as_uint(a);
    return (ushort_t)((ua + 0x7fffu + ((ua >> 16) & 1u)) >> 16);
}
__device__ __forceinline__ float bflo(unsigned u) { return __uint_as_float(u << 16); }
__device__ __forceinline__ float bfhi(unsigned u) { return __uint_as_float(u & 0xffff0000u); }
__device__ __forceinline__ float bfval(ushort_t u) { return __uint_as_float(((unsigned)u) << 16); }

// ---------------- CSR build ----------------
__global__ void k_deg_init(int* __restrict__ deg, int N) {
    int i = blockIdx.x * blockDim.x + threadIdx.x;
    if (i < N) deg[i] = 1;  // slot 0 reserved for self loop
}
__global__ void k_deg_edges(const int* __restrict__ ei, int* __restrict__ deg,
                            int* __restrict__ eofs, int E) {
    int e = blockIdx.x * blockDim.x + threadIdx.x;
    if (e < E) eofs[e] = atomicAdd(&deg[ei[E + e]], 1);
}

__global__ __launch_bounds__(256) void k_scan1(const int* __restrict__ deg, int* __restrict__ rs,
                                               int* __restrict__ bsum, int N) {
    __shared__ int s[256];
    int t = threadIdx.x;
    int base = blockIdx.x * 1024;
    int i0 = base + t * 4;
    int d0 = (i0 + 0 < N) ? deg[i0 + 0] : 0;
    int d1 = (i0 + 1 < N) ? deg[i0 + 1] : 0;
    int d2 = (i0 + 2 < N) ? deg[i0 + 2] : 0;
    int d3 = (i0 + 3 < N) ? deg[i0 + 3] : 0;
    int s0 = d0, s1 = s0 + d1, s2 = s1 + d2, s3 = s2 + d3;
    int tsum = s3;
    s[t] = tsum;
    __syncthreads();
    for (int off = 1; off < 256; off <<= 1) {
        int v = (t >= off) ? s[t - off] : 0;
        __syncthreads();
        s[t] += v;
        __syncthreads();
    }
    int excl = s[t] - tsum;
    if (i0 + 0 < N) rs[1 + i0 + 0] = excl + s0;
    if (i0 + 1 < N) rs[1 + i0 + 1] = excl + s1;
    if (i0 + 2 < N) rs[1 + i0 + 2] = excl + s2;
    if (i0 + 3 < N) rs[1 + i0 + 3] = excl + s3;
    if (t == 0) bsum[blockIdx.x] = s[255];
}

__global__ __launch_bounds__(256) void k_scan2(const int* __restrict__ bsum,
                                               int* __restrict__ boff, int NB) {
    __shared__ int s[256];
    int t = threadIdx.x;
    int orig = (t < NB) ? bsum[t] : 0;
    s[t] = orig;
    __syncthreads();
    for (int off = 1; off < 256; off <<= 1) {
        int v = (t >= off) ? s[t - off] : 0;
        __syncthreads();
        s[t] += v;
        __syncthreads();
    }
    if (t < NB) boff[t] = s[t] - orig;  // exclusive
}

__global__ void k_scan3(int* __restrict__ rs, const int* __restrict__ boff, int N) {
    int i = blockIdx.x * blockDim.x + threadIdx.x;
    if (i == 0) rs[0] = 0;
    if (i < N) rs[1 + i] += boff[i >> 10];
}

// slice-filtered, atomic-free scatter (csr lines stay in one XCD L2).
__global__ __launch_bounds__(256) void k_scatter(const int* __restrict__ ei,
                                                 const int* __restrict__ eofs,
                                                 const int* __restrict__ rs,
                                                 int* __restrict__ csr,
                                                 int E, int Etot, int cohortBlocks) {
    int c = blockIdx.x & 7;
    int pb = blockIdx.x >> 3;
    int tid = pb * 256 + threadIdx.x;
    int stride = cohortBlocks * 256;
    for (int e = tid; e < Etot; e += stride) {
        int dst = (e < E) ? ei[E + e] : (e - E);
        if (((dst >> 13) & 7) != c) continue;
        int src, ofs;
        if (e < E) { src = ei[e]; ofs = eofs[e]; } else { src = dst; ofs = 0; }
        csr[rs[dst] + ofs] = src;
    }
}

// ---------------- dense kernels (register-tiled) ----------------

// h0 = relu(x @ W0 + b0); x[N,128], W0[128,64]. 64 nodes/block.
__global__ __launch_bounds__(256) void k_gemm1(const float* __restrict__ x,
                                               const float* __restrict__ W0,
                                               const float* __restrict__ b0,
                                               float* __restrict__ h0, int N) {
    __shared__ float wl[128 * 64];   // [k][c]
    __shared__ float al[64 * 132];   // [node][k] padded
    int t = threadIdx.x;
    int n0 = blockIdx.x * 64;
    const float4* wg = (const float4*)W0;
    float4* wl4 = (float4*)wl;
#pragma unroll
    for (int i = 0; i < 8; ++i) wl4[t + i * 256] = wg[t + i * 256];
#pragma unroll
    for (int i = 0; i < 8; ++i) {
        int f = t + i * 256;
        int node = f >> 5, q = f & 31;
        int ng = n0 + node; if (ng > N - 1) ng = N - 1;
        float4 v = ((const float4*)x)[(size_t)ng * 32 + q];
        *(float4*)&al[node * 132 + q * 4] = v;
    }
    __syncthreads();
    int colg = t & 15;   // cols colg*4..+3
    int rowg = t >> 4;   // rows rowg*4..+3
    float4 acc[4];
#pragma unroll
    for (int j = 0; j < 4; ++j) acc[j] = make_float4(0.f, 0.f, 0.f, 0.f);
    for (int k4 = 0; k4 < 128; k4 += 4) {
        float4 w0 = *(float4*)&wl[(k4 + 0) * 64 + colg * 4];
        float4 w1 = *(float4*)&wl[(k4 + 1) * 64 + colg * 4];
        float4 w2 = *(float4*)&wl[(k4 + 2) * 64 + colg * 4];
        float4 w3 = *(float4*)&wl[(k4 + 3) * 64 + colg * 4];
#pragma unroll
        for (int j = 0; j < 4; ++j) {
            float4 a = *(float4*)&al[(rowg * 4 + j) * 132 + k4];
            acc[j].x += a.x * w0.x + a.y * w1.x + a.z * w2.x + a.w * w3.x;
            acc[j].y += a.x * w0.y + a.y * w1.y + a.z * w2.y + a.w * w3.y;
            acc[j].z += a.x * w0.z + a.y * w1.z + a.z * w2.z + a.w * w3.z;
            acc[j].w += a.x * w0.w + a.y * w1.w + a.z * w2.w + a.w * w3.w;
        }
    }
    float4 bb = ((const float4*)b0)[colg];
#pragma unroll
    for (int j = 0; j < 4; ++j) {
        int n = n0 + rowg * 4 + j;
        if (n < N) {
            float4 r;
            r.x = fmaxf(acc[j].x + bb.x, 0.f);
            r.y = fmaxf(acc[j].y + bb.y, 0.f);
            r.z = fmaxf(acc[j].z + bb.z, 0.f);
            r.w = fmaxf(acc[j].w + bb.w, 0.f);
            ((float4*)h0)[(size_t)n * 16 + colg] = r;
        }
    }
}

// h1 = h0 @ W1 (stored bf16) + fused att1 dots. h0[N,64], W1[64,128].
__global__ __launch_bounds__(256) void k_gemm2(const float* __restrict__ h0,
                                               const float* __restrict__ W1,
                                               const float* __restrict__ as_g,
                                               const float* __restrict__ ad_g,
                                               ushort_t* __restrict__ h1b,
                                               float* __restrict__ as1,
                                               float* __restrict__ ad1, int N) {
    __shared__ float wl[64 * 128];  // [k][c]
    __shared__ float al[64 * 68];   // [node][k] padded
    int t = threadIdx.x;
    int n0 = blockIdx.x * 64;
    const float4* wg = (const float4*)W1;
    float4* wl4 = (float4*)wl;
#pragma unroll
    for (int i = 0; i < 8; ++i) wl4[t + i * 256] = wg[t + i * 256];
#pragma unroll
    for (int i = 0; i < 4; ++i) {
        int f = t + i * 256;
        int node = f >> 4, q = f & 15;
        int ng = n0 + node; if (ng > N - 1) ng = N - 1;
        float4 v = ((const float4*)h0)[(size_t)ng * 16 + q];
        *(float4*)&al[node * 68 + q * 4] = v;
    }
    __syncthreads();
    int colg = t & 31;   // cols colg*4..+3 (head = colg>=16)
    int rowg = t >> 5;   // rows rowg*8..+7
    float4 acc[8];
#pragma unroll
    for (int j = 0; j < 8; ++j) acc[j] = make_float4(0.f, 0.f, 0.f, 0.f);
    for (int k4 = 0; k4 < 64; k4 += 4) {
        float4 w0 = *(float4*)&wl[(k4 + 0) * 128 + colg * 4];
        float4 w1 = *(float4*)&wl[(k4 + 1) * 128 + colg * 4];
        float4 w2 = *(float4*)&wl[(k4 + 2) * 128 + colg * 4];
        float4 w3 = *(float4*)&wl[(k4 + 3) * 128 + colg * 4];
#pragma unroll
        for (int j = 0; j < 8; ++j) {
            float4 a = *(float4*)&al[(rowg * 8 + j) * 68 + k4];
            acc[j].x += a.x * w0.x + a.y * w1.x + a.z * w2.x + a.w * w3.x;
            acc[j].y += a.x * w0.y + a.y * w1.y + a.z * w2.y + a.w * w3.y;
            acc[j].z += a.x * w0.z + a.y * w1.z + a.z * w2.z + a.w * w3.z;
            acc[j].w += a.x * w0.w + a.y * w1.w + a.z * w2.w + a.w * w3.w;
        }
    }
    float4 asv = ((const float4*)as_g)[colg];
    float4 adv = ((const float4*)ad_g)[colg];
    float ps[8], pd[8];
#pragma unroll
    for (int j = 0; j < 8; ++j) {
        ps[j] = acc[j].x * asv.x + acc[j].y * asv.y + acc[j].z * asv.z + acc[j].w * asv.w;
        pd[j] = acc[j].x * adv.x + acc[j].y * adv.y + acc[j].z * adv.z + acc[j].w * adv.w;
    }
    for (int o = 1; o < 16; o <<= 1) {
#pragma unroll
        for (int j = 0; j < 8; ++j) {
            ps[j] += __shfl_xor(ps[j], o);
            pd[j] += __shfl_xor(pd[j], o);
        }
    }
#pragma unroll
    for (int j = 0; j < 8; ++j) {
        int n = n0 + rowg * 8 + j;
        if (n < N) {
            uint2 pr;
            pr.x = bfpack(acc[j].x, acc[j].y);
            pr.y = bfpack(acc[j].z, acc[j].w);
            ((uint2*)h1b)[(size_t)n * 32 + colg] = pr;  // 32 uint2 per row
        }
    }
    int lane = t & 63;
    if ((lane & 15) == 0) {
        int head = (lane >> 4) & 1;
#pragma unroll
        for (int j = 0; j < 8; ++j) {
            int n = n0 + rowg * 8 + j;
            if (n < N) {
                as1[n * 2 + head] = ps[j];
                ad1[n * 2 + head] = pd[j];
            }
        }
    }
}

// ---- layer-1 fused, v3: pass-1 stashes (src,e0,e1); pass 2 LDS-only ----
__global__ __launch_bounds__(256) void k_node_l1(const int* __restrict__ rs,
                                                 const int* __restrict__ csr,
                                                 const ushort_t* __restrict__ h1b,
                                                 const float* __restrict__ as1,
                                                 const float* __restrict__ ad1,
                                                 const float* __restrict__ b1,
                                                 float* __restrict__ agg, int N) {
    __shared__ float4 stashE[4][STASH_CAP];  // (src bits, e0, e1, -)
    __shared__ float2 stashA[4][128];        // [head][64] (src bits, alpha)
    int wid = threadIdx.x >> 6;
    int lane = threadIdx.x & 63;
    int n = (blockIdx.x * 256 + threadIdx.x) >> 6;
    if (n >= N) return;
    int row = rs[n], end = rs[n + 1];
    float2 adv = ((const float2*)ad1)[n];
    const float2* asp = (const float2*)as1;
    const unsigned* h1u = (const unsigned*)h1b;
    // ---- pass 1: final (m0,m1,l0,l1), edge-parallel; stash (src,e0,e1) ----
    float m0 = -INFINITY, m1 = -INFINITY, l0 = 0.f, l1 = 0.f;
    for (int base = row; base < end; base += 64) {
        int idx = base + lane;
        bool act = idx < end;
        int src = act ? csr[idx] : 0;
        float2 av = asp[src];
        float e0 = av.x + adv.x, e1 = av.y + adv.y;
        e0 = e0 > 0.f ? e0 : NEG_SLOPE * e0;
        e1 = e1 > 0.f ? e1 : NEG_SLOPE * e1;
        int sidx = idx - row;
        if (act && sidx < STASH_CAP)
            stashE[wid][sidx] = make_float4(__int_as_float(src), e0, e1, 0.f);
        if (!act) { e0 = -INFINITY; e1 = -INFINITY; }
        float m0n = fmaxf(m0, wmax(e0));
        float m1n = fmaxf(m1, wmax(e1));
        float p0 = act ? __expf(e0 - m0n) : 0.f;
        float p1 = act ? __expf(e1 - m1n) : 0.f;
        l0 = l0 * __expf(m0 - m0n) + wsum(p0);
        l1 = l1 * __expf(m1 - m1n) + wsum(p1);
        m0 = m0n; m1 = m1n;
    }
    float inv0 = 1.f / l0, inv1 = 1.f / l1;
    // ---- pass 2: per chunk, alpha from stashed e (global only on overflow) ----
    bool head1 = lane >= 32;
    float accx = 0.f, accy = 0.f;
    const float2* sp = &stashA[wid][head1 ? 64 : 0];
    for (int base = row; base < end; base += 64) {
        int idx = base + lane;
        bool act = idx < end;
        int sidx = idx - row;
        int src; float e0, e1;
        if (sidx < STASH_CAP) {
            float4 se = stashE[wid][sidx];  // garbage for !act lanes; guarded below
            src = __float_as_int(se.x);
            e0 = se.y; e1 = se.z;
        } else {
            src = act ? csr[idx] : 0;
            float2 av = asp[src];
            e0 = av.x + adv.x; e1 = av.y + adv.y;
            e0 = e0 > 0.f ? e0 : NEG_SLOPE * e0;
            e1 = e1 > 0.f ? e1 : NEG_SLOPE * e1;
        }
        float a0 = act ? __expf(e0 - m0) * inv0 : 0.f;
        float a1 = act ? __expf(e1 - m1) * inv1 : 0.f;
        stashA[wid][lane] = make_float2(__int_as_float(src), a0);
        stashA[wid][64 + lane] = make_float2(__int_as_float(src), a1);
        // same-wave LDS write->read: in-order DS ops, no barrier needed
        int cnt = min(64, end - base);
#pragma unroll 4
        for (int j = 0; j < cnt; ++j) {
            float2 sa = sp[j];
            int sj = __float_as_int(sa.x);
            float aj = sa.y;
            unsigned u = h1u[(size_t)sj * 64 + lane];
            accx += bflo(u) * aj;
            accy += bfhi(u) * aj;
        }
    }
    float vx = accx + b1[lane * 2];
    float vy = accy + b1[lane * 2 + 1];
    vx = vx > 0.f ? vx : expm1f(vx);
    vy = vy > 0.f ? vy : expm1f(vy);
    float2 r; r.x = vx; r.y = vy;
    ((float2*)(agg + (size_t)n * 128))[lane] = r;
}

// h2 = h1act @ W2 (stored bf16, stride 24) + att2 dots. 64 nodes/block.
__global__ __launch_bounds__(256, 4) void k_node2(const float* __restrict__ h1a,
                                                  const float* __restrict__ W2,
                                                  const float* __restrict__ as_g,
                                                  const float* __restrict__ ad_g,
                                                  ushort_t* __restrict__ h2b,
                                                  float* __restrict__ a_s,
                                                  float* __restrict__ a_d, int N) {
    __shared__ float al[64 * 132];   // [node][k] padded
    __shared__ float w2t[20 * 132];  // [c][k] padded, cols 18,19 zero
    int t = threadIdx.x;
    int n0 = blockIdx.x * 64;
#pragma unroll
    for (int i = 0; i < 8; ++i) {
        int f = t + i * 256;
        int node = f >> 5, q = f & 31;
        int ng = n0 + node; if (ng > N - 1) ng = N - 1;
        float4 v = ((const float4*)h1a)[(size_t)ng * 32 + q];
        *(float4*)&al[node * 132 + q * 4] = v;
    }
    for (int i = t; i < 2560; i += 256) {
        int c = i >> 7, k = i & 127;
        w2t[c * 132 + k] = (c < 18) ? W2[k * 18 + c] : 0.f;
    }
    __syncthreads();
    int node = t >> 2;
    int cq = t & 3;
    int c0 = cq * 5;  // cols c0..c0+4 (cq==3: cols 15..19, 18/19 dead)
    int n = n0 + node;
    float acc[5] = {0.f, 0.f, 0.f, 0.f, 0.f};
#pragma unroll 2
    for (int k4 = 0; k4 < 128; k4 += 4) {
        float4 a = *(float4*)&al[node * 132 + k4];
#pragma unroll
        for (int i = 0; i < 5; ++i) {
            float4 w = *(float4*)&w2t[(c0 + i) * 132 + k4];
            acc[i] += a.x * w.x + a.y * w.y + a.z * w.z + a.w * w.w;
        }
    }
    float ps = 0.f, pd = 0.f;
#pragma unroll
    for (int i = 0; i < 5; ++i) {
        int c = c0 + i;
        float asv = (c < 18) ? as_g[c] : 0.f;
        float adv = (c < 18) ? ad_g[c] : 0.f;
        ps += acc[i] * asv;
        pd += acc[i] * adv;
    }
    ps += __shfl_xor(ps, 1); ps += __shfl_xor(ps, 2);
    pd += __shfl_xor(pd, 1); pd += __shfl_xor(pd, 2);
    if (n < N) {
#pragma unroll
        for (int i = 0; i < 5; ++i) {
            int c = c0 + i;
            if (c < 18) h2b[(size_t)n * 24 + c] = bf16of(acc[i]);
        }
        if (cq == 0) { a_s[n] = ps; a_d[n] = pd; }
    }
}

// ---- layer-2 fused, v3: phase A stashes (src,e); phase B LDS-only ----
__global__ __launch_bounds__(256) void k_node_l2(const int* __restrict__ rs,
                                                 const int* __restrict__ csr,
                                                 const ushort_t* __restrict__ h2b,
                                                 const float* __restrict__ as2,
                                                 const float* __restrict__ ad2,
                                                 const float* __restrict__ b2,
                                                 float* __restrict__ out, int N) {
    __shared__ float2 stash[4][STASH_CAP];  // (src bits, e)
    int wid = threadIdx.x >> 6;
    int lane = threadIdx.x & 63;
    int n = (blockIdx.x * 256 + threadIdx.x) >> 6;
    if (n >= N) return;
    int row = rs[n], end = rs[n + 1];
    float adn = ad2[n];
    // ---- phase A: online (m, l), edge-parallel; stash (src, e) ----
    float m = -INFINITY, l = 0.f;
    for (int base = row; base < end; base += 64) {
        int idx = base + lane;
        bool act = idx < end;
        int src = act ? csr[idx] : 0;
        float e = as2[src] + adn;
        e = e > 0.f ? e : NEG_SLOPE * e;
        int sidx = idx - row;
        if (act && sidx < STASH_CAP)
            stash[wid][sidx] = make_float2(__int_as_float(src), e);
        if (!act) e = -INFINITY;
        float mn = fmaxf(m, wmax(e));
        float p = act ? __expf(e - mn) : 0.f;
        l = l * __expf(m - mn) + wsum(p);
        m = mn;
    }
    float invl = 1.f / l;
    // ---- phase B: 3 edge-groups x 21 lanes, stash-fed ----
    int g = lane / 21;            // 0..3 (lane 63 -> g=3, acc discarded)
    int c = lane - g * 21;        // 0..20
    int cc = c < 18 ? c : 17;     // clamp for safe loads
    float acc = 0.f;
    int deg = end - row;
    int lim = deg < STASH_CAP ? deg : STASH_CAP;
    for (int o = g; o < lim; o += 3) {
        float2 se = stash[wid][o];   // broadcast within group, conflict-free
        int src = __float_as_int(se.x);
        float alpha = __expf(se.y - m) * invl;
        acc += alpha * bfval(h2b[(size_t)src * 24 + cc]);
    }
    // overflow fallback (deg > STASH_CAP: effectively never, kept for correctness)
    for (int pos = row + STASH_CAP + g; pos < end; pos += 3) {
        int src = csr[pos];
        float e = as2[src] + adn;
        e = e > 0.f ? e : NEG_SLOPE * e;
        float alpha = __expf(e - m) * invl;
        acc += alpha * bfval(h2b[(size_t)src * 24 + cc]);
    }
    // group-sum into lanes 0..17: both shfls read pre-mutation acc
    float t1 = __shfl(acc, (lane + 21) & 63);
    float t2 = __shfl(acc, (lane + 42) & 63);
    acc += t1 + t2;
    float bb = (lane < 18) ? b2[lane] : 0.f;
    float v = acc + bb;
    // ---- lane-parallel log-softmax over lanes 0..17 (32-lane xor net) ----
    float tmx = (lane < 18) ? v : -INFINITY;
    for (int o = 16; o; o >>= 1) tmx = fmaxf(tmx, __shfl_xor(tmx, o));
    float s = (lane < 18) ? __expf(v - tmx) : 0.f;
    for (int o = 16; o; o >>= 1) s += __shfl_xor(s, o);
    float lse = tmx + __logf(s);
    if (lane < 18) out[(size_t)n * 18 + lane] = v - lse;
}

extern "C" void kernel_launch(void* const* d_in, const int* in_sizes, int n_in,
                              void* d_out, int out_size, void* d_ws, size_t ws_size,
                              hipStream_t stream) {
    const float* x      = (const float*)d_in[0];
    const int*   ei     = (const int*)d_in[1];
    const float* W0     = (const float*)d_in[2];
    const float* b0     = (const float*)d_in[3];
    const float* W1     = (const float*)d_in[4];
    const float* att_s1 = (const float*)d_in[5];
    const float* att_d1 = (const float*)d_in[6];
    const float* b1     = (const float*)d_in[7];
    const float* W2     = (const float*)d_in[8];
    const float* att_s2 = (const float*)d_in[9];
    const float* att_d2 = (const float*)d_in[10];
    const float* b2     = (const float*)d_in[11];

    const int N = in_sizes[0] / 128;
    const int E = in_sizes[1] / 2;
    const int Etot = E + N;
    const int NB = (N + 1023) / 1024;  // scan blocks (<= 256)
    const int NBLK = (N + 63) / 64;    // dense tiles

    // workspace carve-up (~125 MB)
    char* w = (char*)d_ws;
    float* h0      = (float*)w;    w += (size_t)N * 64 * 4;
    ushort_t* h1b  = (ushort_t*)w; w += (size_t)N * 128 * 2;
    float* agg1    = (float*)w;    w += (size_t)N * 128 * 4;
    float* as1     = (float*)w;    w += (size_t)N * 2 * 4;
    float* ad1     = (float*)w;    w += (size_t)N * 2 * 4;
    ushort_t* h2b  = (ushort_t*)w; w += (size_t)N * 24 * 2;
    float* as2     = (float*)w;    w += (size_t)N * 4;
    float* ad2     = (float*)w;    w += (size_t)N * 4;
    int* deg       = (int*)w;      w += (size_t)N * 4;
    int* rs        = (int*)w;      w += (size_t)(N + 1) * 4;
    int* bsum      = (int*)w;      w += (size_t)256 * 4;
    int* boff      = (int*)w;      w += (size_t)256 * 4;
    int* eofs      = (int*)w;      w += (size_t)E * 4;
    int* csr       = (int*)w;      w += (size_t)Etot * 4;

    float* out = (float*)d_out;

    // ---- CSR build ----
    k_deg_init<<<(N + 255) / 256, 256, 0, stream>>>(deg, N);
    k_deg_edges<<<(E + 255) / 256, 256, 0, stream>>>(ei, deg, eofs, E);
    k_scan1<<<NB, 256, 0, stream>>>(deg, rs, bsum, N);
    k_scan2<<<1, 256, 0, stream>>>(bsum, boff, NB);
    k_scan3<<<(N + 255) / 256, 256, 0, stream>>>(rs, boff, N);
    const int cohortBlocks = 128;
    k_scatter<<<8 * cohortBlocks, 256, 0, stream>>>(ei, eofs, rs, csr, E, Etot, cohortBlocks);

    // ---- dense ----
    k_gemm1<<<NBLK, 256, 0, stream>>>(x, W0, b0, h0, N);
    k_gemm2<<<NBLK, 256, 0, stream>>>(h0, W1, att_s1, att_d1, h1b, as1, ad1, N);

    // ---- layer 1 fused edge pass ----
    k_node_l1<<<(N * 64 + 255) / 256, 256, 0, stream>>>(rs, csr, h1b, as1, ad1, b1, agg1, N);

    // ---- layer 2 dense + fused edge pass ----
    k_node2<<<NBLK, 256, 0, stream>>>(agg1, W2, att_s2, att_d2, h2b, as2, ad2, N);
    k_node_l2<<<(N * 64 + 255) / 256, 256, 0, stream>>>(rs, csr, h2b, as2, ad2, b2, out, N);
}

// Round 11
// 449.348 us; speedup vs baseline: 4.2098x; 1.0040x over previous
//
#include <hip/hip_runtime.h>
#include <math.h>

// GAT 2-layer: N=100000, E=1600000 (+N self loops), F_IN=128, HID=64, HEADS=2,
// OUT_HEADS=1, NUM_CLASS=18, NEG_SLOPE=0.2
// Round 10: (1) h0 and agg1 stored bf16 (were fp32: 150MB of streaming
// traffic across gemm1/gemm2/node_l1/node2). (2) libm expm1f -> __expf-1 and
// fdiv -> v_rcp in the edge-kernel epilogues (expm1f is a ~25-inst ocml call,
// 2x per node in the 75%-VALU-busy k_node_l1).

#define NEG_SLOPE 0.2f
#define STASH_CAP 128

typedef unsigned short ushort_t;

// ---------------- wave reductions (64 lanes) ----------------
__device__ __forceinline__ float wmax(float v) {
    for (int o = 32; o; o >>= 1) v = fmaxf(v, __shfl_xor(v, o));
    return v;
}
__device__ __forceinline__ float wsum(float v) {
    for (int o = 32; o; o >>= 1) v += __shfl_xor(v, o);
    return v;
}

// ---------------- bf16 helpers (RNE) ----------------
__device__ __forceinline__ unsigned bfpack(float a, float b) {
    unsigned ua = __float_as_uint(a);
    unsigned ub = __float_as_uint(b);
    ua = (ua + 0x7fffu + ((ua >> 16) & 1u)) >> 16;
    ub = (ub + 0x7fffu + ((ub >> 16) & 1u)) & 0xffff0000u;
    return ua | ub;
}
__device__ __forceinline__ ushort_t bf16of(float a) {
    unsigned ua = __float_as_uint(a);
    return (ushort_t)((ua + 0x7fffu + ((ua >> 16) & 1u)) >> 16);
}
__device__ __forceinline__ float bflo(unsigned u) { return __uint_as_float(u << 16); }
__device__ __forceinline__ float bfhi(unsigned u) { return __uint_as_float(u & 0xffff0000u); }
__device__ __forceinline__ float bfval(ushort_t u) { return __uint_as_float(((unsigned)u) << 16); }

// ---------------- CSR build ----------------
__global__ void k_deg_init(int* __restrict__ deg, int N) {
    int i = blockIdx.x * blockDim.x + threadIdx.x;
    if (i < N) deg[i] = 1;  // slot 0 reserved for self loop
}
__global__ void k_deg_edges(const int* __restrict__ ei, int* __restrict__ deg,
                            int* __restrict__ eofs, int E) {
    int e = blockIdx.x * blockDim.x + threadIdx.x;
    if (e < E) eofs[e] = atomicAdd(&deg[ei[E + e]], 1);
}

__global__ __launch_bounds__(256) void k_scan1(const int* __restrict__ deg, int* __restrict__ rs,
                                               int* __restrict__ bsum, int N) {
    __shared__ int s[256];
    int t = threadIdx.x;
    int base = blockIdx.x * 1024;
    int i0 = base + t * 4;
    int d0 = (i0 + 0 < N) ? deg[i0 + 0] : 0;
    int d1 = (i0 + 1 < N) ? deg[i0 + 1] : 0;
    int d2 = (i0 + 2 < N) ? deg[i0 + 2] : 0;
    int d3 = (i0 + 3 < N) ? deg[i0 + 3] : 0;
    int s0 = d0, s1 = s0 + d1, s2 = s1 + d2, s3 = s2 + d3;
    int tsum = s3;
    s[t] = tsum;
    __syncthreads();
    for (int off = 1; off < 256; off <<= 1) {
        int v = (t >= off) ? s[t - off] : 0;
        __syncthreads();
        s[t] += v;
        __syncthreads();
    }
    int excl = s[t] - tsum;
    if (i0 + 0 < N) rs[1 + i0 + 0] = excl + s0;
    if (i0 + 1 < N) rs[1 + i0 + 1] = excl + s1;
    if (i0 + 2 < N) rs[1 + i0 + 2] = excl + s2;
    if (i0 + 3 < N) rs[1 + i0 + 3] = excl + s3;
    if (t == 0) bsum[blockIdx.x] = s[255];
}

__global__ __launch_bounds__(256) void k_scan2(const int* __restrict__ bsum,
                                               int* __restrict__ boff, int NB) {
    __shared__ int s[256];
    int t = threadIdx.x;
    int orig = (t < NB) ? bsum[t] : 0;
    s[t] = orig;
    __syncthreads();
    for (int off = 1; off < 256; off <<= 1) {
        int v = (t >= off) ? s[t - off] : 0;
        __syncthreads();
        s[t] += v;
        __syncthreads();
    }
    if (t < NB) boff[t] = s[t] - orig;  // exclusive
}

__global__ void k_scan3(int* __restrict__ rs, const int* __restrict__ boff, int N) {
    int i = blockIdx.x * blockDim.x + threadIdx.x;
    if (i == 0) rs[0] = 0;
    if (i < N) rs[1 + i] += boff[i >> 10];
}

// slice-filtered, atomic-free scatter (csr lines stay in one XCD L2).
__global__ __launch_bounds__(256) void k_scatter(const int* __restrict__ ei,
                                                 const int* __restrict__ eofs,
                                                 const int* __restrict__ rs,
                                                 int* __restrict__ csr,
                                                 int E, int Etot, int cohortBlocks) {
    int c = blockIdx.x & 7;
    int pb = blockIdx.x >> 3;
    int tid = pb * 256 + threadIdx.x;
    int stride = cohortBlocks * 256;
    for (int e = tid; e < Etot; e += stride) {
        int dst = (e < E) ? ei[E + e] : (e - E);
        if (((dst >> 13) & 7) != c) continue;
        int src, ofs;
        if (e < E) { src = ei[e]; ofs = eofs[e]; } else { src = dst; ofs = 0; }
        csr[rs[dst] + ofs] = src;
    }
}

// ---------------- dense kernels (register-tiled) ----------------

// h0 = relu(x @ W0 + b0), stored bf16; x[N,128], W0[128,64]. 64 nodes/block.
__global__ __launch_bounds__(256) void k_gemm1(const float* __restrict__ x,
                                               const float* __restrict__ W0,
                                               const float* __restrict__ b0,
                                               unsigned* __restrict__ h0b, int N) {
    __shared__ float wl[128 * 64];   // [k][c]
    __shared__ float al[64 * 132];   // [node][k] padded
    int t = threadIdx.x;
    int n0 = blockIdx.x * 64;
    const float4* wg = (const float4*)W0;
    float4* wl4 = (float4*)wl;
#pragma unroll
    for (int i = 0; i < 8; ++i) wl4[t + i * 256] = wg[t + i * 256];
#pragma unroll
    for (int i = 0; i < 8; ++i) {
        int f = t + i * 256;
        int node = f >> 5, q = f & 31;
        int ng = n0 + node; if (ng > N - 1) ng = N - 1;
        float4 v = ((const float4*)x)[(size_t)ng * 32 + q];
        *(float4*)&al[node * 132 + q * 4] = v;
    }
    __syncthreads();
    int colg = t & 15;   // cols colg*4..+3
    int rowg = t >> 4;   // rows rowg*4..+3
    float4 acc[4];
#pragma unroll
    for (int j = 0; j < 4; ++j) acc[j] = make_float4(0.f, 0.f, 0.f, 0.f);
    for (int k4 = 0; k4 < 128; k4 += 4) {
        float4 w0 = *(float4*)&wl[(k4 + 0) * 64 + colg * 4];
        float4 w1 = *(float4*)&wl[(k4 + 1) * 64 + colg * 4];
        float4 w2 = *(float4*)&wl[(k4 + 2) * 64 + colg * 4];
        float4 w3 = *(float4*)&wl[(k4 + 3) * 64 + colg * 4];
#pragma unroll
        for (int j = 0; j < 4; ++j) {
            float4 a = *(float4*)&al[(rowg * 4 + j) * 132 + k4];
            acc[j].x += a.x * w0.x + a.y * w1.x + a.z * w2.x + a.w * w3.x;
            acc[j].y += a.x * w0.y + a.y * w1.y + a.z * w2.y + a.w * w3.y;
            acc[j].z += a.x * w0.z + a.y * w1.z + a.z * w2.z + a.w * w3.z;
            acc[j].w += a.x * w0.w + a.y * w1.w + a.z * w2.w + a.w * w3.w;
        }
    }
    float4 bb = ((const float4*)b0)[colg];
#pragma unroll
    for (int j = 0; j < 4; ++j) {
        int n = n0 + rowg * 4 + j;
        if (n < N) {
            float rx = fmaxf(acc[j].x + bb.x, 0.f);
            float ry = fmaxf(acc[j].y + bb.y, 0.f);
            float rz = fmaxf(acc[j].z + bb.z, 0.f);
            float rw = fmaxf(acc[j].w + bb.w, 0.f);
            uint2 pr; pr.x = bfpack(rx, ry); pr.y = bfpack(rz, rw);
            ((uint2*)h0b)[(size_t)n * 16 + colg] = pr;  // 64 bf16 = 16 uint2/row
        }
    }
}

// h1 = h0 @ W1 (stored bf16) + fused att1 dots. h0b[N,64] bf16, W1[64,128].
__global__ __launch_bounds__(256) void k_gemm2(const unsigned* __restrict__ h0b,
                                               const float* __restrict__ W1,
                                               const float* __restrict__ as_g,
                                               const float* __restrict__ ad_g,
                                               ushort_t* __restrict__ h1b,
                                               float* __restrict__ as1,
                                               float* __restrict__ ad1, int N) {
    __shared__ float wl[64 * 128];  // [k][c]
    __shared__ float al[64 * 68];   // [node][k] padded
    int t = threadIdx.x;
    int n0 = blockIdx.x * 64;
    const float4* wg = (const float4*)W1;
    float4* wl4 = (float4*)wl;
#pragma unroll
    for (int i = 0; i < 8; ++i) wl4[t + i * 256] = wg[t + i * 256];
#pragma unroll
    for (int i = 0; i < 2; ++i) {
        int f = t + i * 256;          // 0..511
        int node = f >> 3, q = f & 7; // row = 32 uints = 8 uint4
        int ng = n0 + node; if (ng > N - 1) ng = N - 1;
        uint4 u = ((const uint4*)h0b)[(size_t)ng * 8 + q];
        float* dst = &al[node * 68 + q * 8];
        dst[0] = bflo(u.x); dst[1] = bfhi(u.x);
        dst[2] = bflo(u.y); dst[3] = bfhi(u.y);
        dst[4] = bflo(u.z); dst[5] = bfhi(u.z);
        dst[6] = bflo(u.w); dst[7] = bfhi(u.w);
    }
    __syncthreads();
    int colg = t & 31;   // cols colg*4..+3 (head = colg>=16)
    int rowg = t >> 5;   // rows rowg*8..+7
    float4 acc[8];
#pragma unroll
    for (int j = 0; j < 8; ++j) acc[j] = make_float4(0.f, 0.f, 0.f, 0.f);
    for (int k4 = 0; k4 < 64; k4 += 4) {
        float4 w0 = *(float4*)&wl[(k4 + 0) * 128 + colg * 4];
        float4 w1 = *(float4*)&wl[(k4 + 1) * 128 + colg * 4];
        float4 w2 = *(float4*)&wl[(k4 + 2) * 128 + colg * 4];
        float4 w3 = *(float4*)&wl[(k4 + 3) * 128 + colg * 4];
#pragma unroll
        for (int j = 0; j < 8; ++j) {
            float4 a = *(float4*)&al[(rowg * 8 + j) * 68 + k4];
            acc[j].x += a.x * w0.x + a.y * w1.x + a.z * w2.x + a.w * w3.x;
            acc[j].y += a.x * w0.y + a.y * w1.y + a.z * w2.y + a.w * w3.y;
            acc[j].z += a.x * w0.z + a.y * w1.z + a.z * w2.z + a.w * w3.z;
            acc[j].w += a.x * w0.w + a.y * w1.w + a.z * w2.w + a.w * w3.w;
        }
    }
    float4 asv = ((const float4*)as_g)[colg];
    float4 adv = ((const float4*)ad_g)[colg];
    float ps[8], pd[8];
#pragma unroll
    for (int j = 0; j < 8; ++j) {
        ps[j] = acc[j].x * asv.x + acc[j].y * asv.y + acc[j].z * asv.z + acc[j].w * asv.w;
        pd[j] = acc[j].x * adv.x + acc[j].y * adv.y + acc[j].z * adv.z + acc[j].w * adv.w;
    }
    for (int o = 1; o < 16; o <<= 1) {
#pragma unroll
        for (int j = 0; j < 8; ++j) {
            ps[j] += __shfl_xor(ps[j], o);
            pd[j] += __shfl_xor(pd[j], o);
        }
    }
#pragma unroll
    for (int j = 0; j < 8; ++j) {
        int n = n0 + rowg * 8 + j;
        if (n < N) {
            uint2 pr;
            pr.x = bfpack(acc[j].x, acc[j].y);
            pr.y = bfpack(acc[j].z, acc[j].w);
            ((uint2*)h1b)[(size_t)n * 32 + colg] = pr;  // 32 uint2 per row
        }
    }
    int lane = t & 63;
    if ((lane & 15) == 0) {
        int head = (lane >> 4) & 1;
#pragma unroll
        for (int j = 0; j < 8; ++j) {
            int n = n0 + rowg * 8 + j;
            if (n < N) {
                as1[n * 2 + head] = ps[j];
                ad1[n * 2 + head] = pd[j];
            }
        }
    }
}

// ---- layer-1 fused: pass-1 stash (src,e0,e1); pass 2 LDS-fed; bf16 out ----
__global__ __launch_bounds__(256) void k_node_l1(const int* __restrict__ rs,
                                                 const int* __restrict__ csr,
                                                 const ushort_t* __restrict__ h1b,
                                                 const float* __restrict__ as1,
                                                 const float* __restrict__ ad1,
                                                 const float* __restrict__ b1,
                                                 unsigned* __restrict__ aggb, int N) {
    __shared__ float4 stashE[4][STASH_CAP];  // (src bits, e0, e1, -)
    __shared__ float2 stashA[4][128];        // [head][64] (src bits, alpha)
    int wid = threadIdx.x >> 6;
    int lane = threadIdx.x & 63;
    int n = (blockIdx.x * 256 + threadIdx.x) >> 6;
    if (n >= N) return;
    int row = rs[n], end = rs[n + 1];
    float2 adv = ((const float2*)ad1)[n];
    const float2* asp = (const float2*)as1;
    const unsigned* h1u = (const unsigned*)h1b;
    // ---- pass 1: final (m0,m1,l0,l1); stash (src,e0,e1) ----
    float m0 = -INFINITY, m1 = -INFINITY, l0 = 0.f, l1 = 0.f;
    for (int base = row; base < end; base += 64) {
        int idx = base + lane;
        bool act = idx < end;
        int src = act ? csr[idx] : 0;
        float2 av = asp[src];
        float e0 = av.x + adv.x, e1 = av.y + adv.y;
        e0 = e0 > 0.f ? e0 : NEG_SLOPE * e0;
        e1 = e1 > 0.f ? e1 : NEG_SLOPE * e1;
        int sidx = idx - row;
        if (act && sidx < STASH_CAP)
            stashE[wid][sidx] = make_float4(__int_as_float(src), e0, e1, 0.f);
        if (!act) { e0 = -INFINITY; e1 = -INFINITY; }
        float m0n = fmaxf(m0, wmax(e0));
        float m1n = fmaxf(m1, wmax(e1));
        float p0 = act ? __expf(e0 - m0n) : 0.f;
        float p1 = act ? __expf(e1 - m1n) : 0.f;
        l0 = l0 * __expf(m0 - m0n) + wsum(p0);
        l1 = l1 * __expf(m1 - m1n) + wsum(p1);
        m0 = m0n; m1 = m1n;
    }
    float inv0 = __builtin_amdgcn_rcpf(l0);
    float inv1 = __builtin_amdgcn_rcpf(l1);
    // ---- pass 2: alpha from stashed e (global only on overflow) ----
    bool head1 = lane >= 32;
    float accx = 0.f, accy = 0.f;
    const float2* sp = &stashA[wid][head1 ? 64 : 0];
    for (int base = row; base < end; base += 64) {
        int idx = base + lane;
        bool act = idx < end;
        int sidx = idx - row;
        int src; float e0, e1;
        if (sidx < STASH_CAP) {
            float4 se = stashE[wid][sidx];  // garbage for !act lanes; guarded below
            src = __float_as_int(se.x);
            e0 = se.y; e1 = se.z;
        } else {
            src = act ? csr[idx] : 0;
            float2 av = asp[src];
            e0 = av.x + adv.x; e1 = av.y + adv.y;
            e0 = e0 > 0.f ? e0 : NEG_SLOPE * e0;
            e1 = e1 > 0.f ? e1 : NEG_SLOPE * e1;
        }
        float a0 = act ? __expf(e0 - m0) * inv0 : 0.f;
        float a1 = act ? __expf(e1 - m1) * inv1 : 0.f;
        stashA[wid][lane] = make_float2(__int_as_float(src), a0);
        stashA[wid][64 + lane] = make_float2(__int_as_float(src), a1);
        // same-wave LDS write->read: in-order DS ops, no barrier needed
        int cnt = min(64, end - base);
#pragma unroll 4
        for (int j = 0; j < cnt; ++j) {
            float2 sa = sp[j];
            int sj = __float_as_int(sa.x);
            float aj = sa.y;
            unsigned u = h1u[(size_t)sj * 64 + lane];
            accx += bflo(u) * aj;
            accy += bfhi(u) * aj;
        }
    }
    float vx = accx + b1[lane * 2];
    float vy = accy + b1[lane * 2 + 1];
    vx = vx > 0.f ? vx : __expf(vx) - 1.f;   // ELU; expm1 cancellation < 1e-7
    vy = vy > 0.f ? vy : __expf(vy) - 1.f;
    aggb[(size_t)n * 64 + lane] = bfpack(vx, vy);
}

// h2 = agg1 @ W2 (agg bf16 in, h2 bf16 out) + att2 dots. 64 nodes/block.
__global__ __launch_bounds__(256, 4) void k_node2(const unsigned* __restrict__ aggb,
                                                  const float* __restrict__ W2,
                                                  const float* __restrict__ as_g,
                                                  const float* __restrict__ ad_g,
                                                  ushort_t* __restrict__ h2b,
                                                  float* __restrict__ a_s,
                                                  float* __restrict__ a_d, int N) {
    __shared__ float al[64 * 132];   // [node][k] padded
    __shared__ float w2t[20 * 132];  // [c][k] padded, cols 18,19 zero
    int t = threadIdx.x;
    int n0 = blockIdx.x * 64;
#pragma unroll
    for (int i = 0; i < 4; ++i) {
        int f = t + i * 256;            // 0..1023
        int node = f >> 4, q = f & 15;  // row = 64 uints = 16 uint4
        int ng = n0 + node; if (ng > N - 1) ng = N - 1;
        uint4 u = ((const uint4*)aggb)[(size_t)ng * 16 + q];
        float* dst = &al[node * 132 + q * 8];
        dst[0] = bflo(u.x); dst[1] = bfhi(u.x);
        dst[2] = bflo(u.y); dst[3] = bfhi(u.y);
        dst[4] = bflo(u.z); dst[5] = bfhi(u.z);
        dst[6] = bflo(u.w); dst[7] = bfhi(u.w);
    }
    for (int i = t; i < 2560; i += 256) {
        int c = i >> 7, k = i & 127;
        w2t[c * 132 + k] = (c < 18) ? W2[k * 18 + c] : 0.f;
    }
    __syncthreads();
    int node = t >> 2;
    int cq = t & 3;
    int c0 = cq * 5;  // cols c0..c0+4 (cq==3: cols 15..19, 18/19 dead)
    int n = n0 + node;
    float acc[5] = {0.f, 0.f, 0.f, 0.f, 0.f};
#pragma unroll 2
    for (int k4 = 0; k4 < 128; k4 += 4) {
        float4 a = *(float4*)&al[node * 132 + k4];
#pragma unroll
        for (int i = 0; i < 5; ++i) {
            float4 w = *(float4*)&w2t[(c0 + i) * 132 + k4];
            acc[i] += a.x * w.x + a.y * w.y + a.z * w.z + a.w * w.w;
        }
    }
    float ps = 0.f, pd = 0.f;
#pragma unroll
    for (int i = 0; i < 5; ++i) {
        int c = c0 + i;
        float asv = (c < 18) ? as_g[c] : 0.f;
        float adv = (c < 18) ? ad_g[c] : 0.f;
        ps += acc[i] * asv;
        pd += acc[i] * adv;
    }
    ps += __shfl_xor(ps, 1); ps += __shfl_xor(ps, 2);
    pd += __shfl_xor(pd, 1); pd += __shfl_xor(pd, 2);
    if (n < N) {
#pragma unroll
        for (int i = 0; i < 5; ++i) {
            int c = c0 + i;
            if (c < 18) h2b[(size_t)n * 24 + c] = bf16of(acc[i]);
        }
        if (cq == 0) { a_s[n] = ps; a_d[n] = pd; }
    }
}

// ---- layer-2 fused: phase A stashes (src,e); phase B LDS-fed ----
__global__ __launch_bounds__(256) void k_node_l2(const int* __restrict__ rs,
                                                 const int* __restrict__ csr,
                                                 const ushort_t* __restrict__ h2b,
                                                 const float* __restrict__ as2,
                                                 const float* __restrict__ ad2,
                                                 const float* __restrict__ b2,
                                                 float* __restrict__ out, int N) {
    __shared__ float2 stash[4][STASH_CAP];  // (src bits, e)
    int wid = threadIdx.x >> 6;
    int lane = threadIdx.x & 63;
    int n = (blockIdx.x * 256 + threadIdx.x) >> 6;
    if (n >= N) return;
    int row = rs[n], end = rs[n + 1];
    float adn = ad2[n];
    // ---- phase A: online (m, l), edge-parallel; stash (src, e) ----
    float m = -INFINITY, l = 0.f;
    for (int base = row; base < end; base += 64) {
        int idx = base + lane;
        bool act = idx < end;
        int src = act ? csr[idx] : 0;
        float e = as2[src] + adn;
        e = e > 0.f ? e : NEG_SLOPE * e;
        int sidx = idx - row;
        if (act && sidx < STASH_CAP)
            stash[wid][sidx] = make_float2(__int_as_float(src), e);
        if (!act) e = -INFINITY;
        float mn = fmaxf(m, wmax(e));
        float p = act ? __expf(e - mn) : 0.f;
        l = l * __expf(m - mn) + wsum(p);
        m = mn;
    }
    float invl = __builtin_amdgcn_rcpf(l);
    // ---- phase B: 3 edge-groups x 21 lanes, stash-fed ----
    int g = lane / 21;            // 0..3 (lane 63 -> g=3, acc discarded)
    int c = lane - g * 21;        // 0..20
    int cc = c < 18 ? c : 17;     // clamp for safe loads
    float acc = 0.f;
    int deg = end - row;
    int lim = deg < STASH_CAP ? deg : STASH_CAP;
    for (int o = g; o < lim; o += 3) {
        float2 se = stash[wid][o];   // broadcast within group, conflict-free
        int src = __float_as_int(se.x);
        float alpha = __expf(se.y - m) * invl;
        acc += alpha * bfval(h2b[(size_t)src * 24 + cc]);
    }
    // overflow fallback (deg > STASH_CAP: effectively never, kept for correctness)
    for (int pos = row + STASH_CAP + g; pos < end; pos += 3) {
        int src = csr[pos];
        float e = as2[src] + adn;
        e = e > 0.f ? e : NEG_SLOPE * e;
        float alpha = __expf(e - m) * invl;
        acc += alpha * bfval(h2b[(size_t)src * 24 + cc]);
    }
    // group-sum into lanes 0..17: both shfls read pre-mutation acc
    float t1 = __shfl(acc, (lane + 21) & 63);
    float t2 = __shfl(acc, (lane + 42) & 63);
    acc += t1 + t2;
    float bb = (lane < 18) ? b2[lane] : 0.f;
    float v = acc + bb;
    // ---- lane-parallel log-softmax over lanes 0..17 (32-lane xor net) ----
    float tmx = (lane < 18) ? v : -INFINITY;
    for (int o = 16; o; o >>= 1) tmx = fmaxf(tmx, __shfl_xor(tmx, o));
    float s = (lane < 18) ? __expf(v - tmx) : 0.f;
    for (int o = 16; o; o >>= 1) s += __shfl_xor(s, o);
    float lse = tmx + __logf(s);
    if (lane < 18) out[(size_t)n * 18 + lane] = v - lse;
}

extern "C" void kernel_launch(void* const* d_in, const int* in_sizes, int n_in,
                              void* d_out, int out_size, void* d_ws, size_t ws_size,
                              hipStream_t stream) {
    const float* x      = (const float*)d_in[0];
    const int*   ei     = (const int*)d_in[1];
    const float* W0     = (const float*)d_in[2];
    const float* b0     = (const float*)d_in[3];
    const float* W1     = (const float*)d_in[4];
    const float* att_s1 = (const float*)d_in[5];
    const float* att_d1 = (const float*)d_in[6];
    const float* b1     = (const float*)d_in[7];
    const float* W2     = (const float*)d_in[8];
    const float* att_s2 = (const float*)d_in[9];
    const float* att_d2 = (const float*)d_in[10];
    const float* b2     = (const float*)d_in[11];

    const int N = in_sizes[0] / 128;
    const int E = in_sizes[1] / 2;
    const int Etot = E + N;
    const int NB = (N + 1023) / 1024;  // scan blocks (<= 256)
    const int NBLK = (N + 63) / 64;    // dense tiles

    // workspace carve-up (~100 MB)
    char* w = (char*)d_ws;
    unsigned* h0b  = (unsigned*)w; w += (size_t)N * 64 * 2;   // bf16 x 64
    ushort_t* h1b  = (ushort_t*)w; w += (size_t)N * 128 * 2;
    unsigned* aggb = (unsigned*)w; w += (size_t)N * 128 * 2;  // bf16 x 128
    float* as1     = (float*)w;    w += (size_t)N * 2 * 4;
    float* ad1     = (float*)w;    w += (size_t)N * 2 * 4;
    ushort_t* h2b  = (ushort_t*)w; w += (size_t)N * 24 * 2;
    float* as2     = (float*)w;    w += (size_t)N * 4;
    float* ad2     = (float*)w;    w += (size_t)N * 4;
    int* deg       = (int*)w;      w += (size_t)N * 4;
    int* rs        = (int*)w;      w += (size_t)(N + 1) * 4;
    int* bsum      = (int*)w;      w += (size_t)256 * 4;
    int* boff      = (int*)w;      w += (size_t)256 * 4;
    int* eofs      = (int*)w;      w += (size_t)E * 4;
    int* csr       = (int*)w;      w += (size_t)Etot * 4;

    float* out = (float*)d_out;

    // ---- CSR build ----
    k_deg_init<<<(N + 255) / 256, 256, 0, stream>>>(deg, N);
    k_deg_edges<<<(E + 255) / 256, 256, 0, stream>>>(ei, deg, eofs, E);
    k_scan1<<<NB, 256, 0, stream>>>(deg, rs, bsum, N);
    k_scan2<<<1, 256, 0, stream>>>(bsum, boff, NB);
    k_scan3<<<(N + 255) / 256, 256, 0, stream>>>(rs, boff, N);
    const int cohortBlocks = 128;
    k_scatter<<<8 * cohortBlocks, 256, 0, stream>>>(ei, eofs, rs, csr, E, Etot, cohortBlocks);

    // ---- dense ----
    k_gemm1<<<NBLK, 256, 0, stream>>>(x, W0, b0, h0b, N);
    k_gemm2<<<NBLK, 256, 0, stream>>>(h0b, W1, att_s1, att_d1, h1b, as1, ad1, N);

    // ---- layer 1 fused edge pass ----
    k_node_l1<<<(N * 64 + 255) / 256, 256, 0, stream>>>(rs, csr, h1b, as1, ad1, b1, aggb, N);

    // ---- layer 2 dense + fused edge pass ----
    k_node2<<<NBLK, 256, 0, stream>>>(aggb, W2, att_s2, att_d2, h2b, as2, ad2, N);
    k_node_l2<<<(N * 64 + 255) / 256, 256, 0, stream>>>(rs, csr, h2b, as2, ad2, b2, out, N);
}

// Round 12
// 446.793 us; speedup vs baseline: 4.2339x; 1.0057x over previous
//
#include <hip/hip_runtime.h>
#include <math.h>

// GAT 2-layer: N=100000, E=1600000 (+N self loops), F_IN=128, HID=64, HEADS=2,
// OUT_HEADS=1, NUM_CLASS=18, NEG_SLOPE=0.2
// Round 11: deg<=64 always holds (Poisson mean 17) -> single-pass softmax in
// both edge kernels: stash UNNORMALIZED p=exp(e-m), scale by 1/l in epilogue
// (normalization is linear). l1 j-loop reworked: 4 edges/iter via dwordx4
// (16 lanes/edge, 8 features/lane), shfl_xor(16/32) merge per node.
// deg>64 slow paths kept for correctness (never taken on this input).

#define NEG_SLOPE 0.2f
#define STASH_CAP 128

typedef unsigned short ushort_t;

// ---------------- wave reductions (64 lanes) ----------------
__device__ __forceinline__ float wmax(float v) {
    for (int o = 32; o; o >>= 1) v = fmaxf(v, __shfl_xor(v, o));
    return v;
}
__device__ __forceinline__ float wsum(float v) {
    for (int o = 32; o; o >>= 1) v += __shfl_xor(v, o);
    return v;
}

// ---------------- bf16 helpers (RNE) ----------------
__device__ __forceinline__ unsigned bfpack(float a, float b) {
    unsigned ua = __float_as_uint(a);
    unsigned ub = __float_as_uint(b);
    ua = (ua + 0x7fffu + ((ua >> 16) & 1u)) >> 16;
    ub = (ub + 0x7fffu + ((ub >> 16) & 1u)) & 0xffff0000u;
    return ua | ub;
}
__device__ __forceinline__ ushort_t bf16of(float a) {
    unsigned ua = __float_as_uint(a);
    return (ushort_t)((ua + 0x7fffu + ((ua >> 16) & 1u)) >> 16);
}
__device__ __forceinline__ float bflo(unsigned u) { return __uint_as_float(u << 16); }
__device__ __forceinline__ float bfhi(unsigned u) { return __uint_as_float(u & 0xffff0000u); }
__device__ __forceinline__ float bfval(ushort_t u) { return __uint_as_float(((unsigned)u) << 16); }

// ---------------- CSR build ----------------
__global__ void k_deg_init(int* __restrict__ deg, int N) {
    int i = blockIdx.x * blockDim.x + threadIdx.x;
    if (i < N) deg[i] = 1;  // slot 0 reserved for self loop
}
__global__ void k_deg_edges(const int* __restrict__ ei, int* __restrict__ deg,
                            int* __restrict__ eofs, int E) {
    int e = blockIdx.x * blockDim.x + threadIdx.x;
    if (e < E) eofs[e] = atomicAdd(&deg[ei[E + e]], 1);
}

__global__ __launch_bounds__(256) void k_scan1(const int* __restrict__ deg, int* __restrict__ rs,
                                               int* __restrict__ bsum, int N) {
    __shared__ int s[256];
    int t = threadIdx.x;
    int base = blockIdx.x * 1024;
    int i0 = base + t * 4;
    int d0 = (i0 + 0 < N) ? deg[i0 + 0] : 0;
    int d1 = (i0 + 1 < N) ? deg[i0 + 1] : 0;
    int d2 = (i0 + 2 < N) ? deg[i0 + 2] : 0;
    int d3 = (i0 + 3 < N) ? deg[i0 + 3] : 0;
    int s0 = d0, s1 = s0 + d1, s2 = s1 + d2, s3 = s2 + d3;
    int tsum = s3;
    s[t] = tsum;
    __syncthreads();
    for (int off = 1; off < 256; off <<= 1) {
        int v = (t >= off) ? s[t - off] : 0;
        __syncthreads();
        s[t] += v;
        __syncthreads();
    }
    int excl = s[t] - tsum;
    if (i0 + 0 < N) rs[1 + i0 + 0] = excl + s0;
    if (i0 + 1 < N) rs[1 + i0 + 1] = excl + s1;
    if (i0 + 2 < N) rs[1 + i0 + 2] = excl + s2;
    if (i0 + 3 < N) rs[1 + i0 + 3] = excl + s3;
    if (t == 0) bsum[blockIdx.x] = s[255];
}

__global__ __launch_bounds__(256) void k_scan2(const int* __restrict__ bsum,
                                               int* __restrict__ boff, int NB) {
    __shared__ int s[256];
    int t = threadIdx.x;
    int orig = (t < NB) ? bsum[t] : 0;
    s[t] = orig;
    __syncthreads();
    for (int off = 1; off < 256; off <<= 1) {
        int v = (t >= off) ? s[t - off] : 0;
        __syncthreads();
        s[t] += v;
        __syncthreads();
    }
    if (t < NB) boff[t] = s[t] - orig;  // exclusive
}

__global__ void k_scan3(int* __restrict__ rs, const int* __restrict__ boff, int N) {
    int i = blockIdx.x * blockDim.x + threadIdx.x;
    if (i == 0) rs[0] = 0;
    if (i < N) rs[1 + i] += boff[i >> 10];
}

// slice-filtered, atomic-free scatter (csr lines stay in one XCD L2).
__global__ __launch_bounds__(256) void k_scatter(const int* __restrict__ ei,
                                                 const int* __restrict__ eofs,
                                                 const int* __restrict__ rs,
                                                 int* __restrict__ csr,
                                                 int E, int Etot, int cohortBlocks) {
    int c = blockIdx.x & 7;
    int pb = blockIdx.x >> 3;
    int tid = pb * 256 + threadIdx.x;
    int stride = cohortBlocks * 256;
    for (int e = tid; e < Etot; e += stride) {
        int dst = (e < E) ? ei[E + e] : (e - E);
        if (((dst >> 13) & 7) != c) continue;
        int src, ofs;
        if (e < E) { src = ei[e]; ofs = eofs[e]; } else { src = dst; ofs = 0; }
        csr[rs[dst] + ofs] = src;
    }
}

// ---------------- dense kernels (register-tiled) ----------------

// h0 = relu(x @ W0 + b0), stored bf16; x[N,128], W0[128,64]. 64 nodes/block.
__global__ __launch_bounds__(256) void k_gemm1(const float* __restrict__ x,
                                               const float* __restrict__ W0,
                                               const float* __restrict__ b0,
                                               unsigned* __restrict__ h0b, int N) {
    __shared__ float wl[128 * 64];   // [k][c]
    __shared__ float al[64 * 132];   // [node][k] padded
    int t = threadIdx.x;
    int n0 = blockIdx.x * 64;
    const float4* wg = (const float4*)W0;
    float4* wl4 = (float4*)wl;
#pragma unroll
    for (int i = 0; i < 8; ++i) wl4[t + i * 256] = wg[t + i * 256];
#pragma unroll
    for (int i = 0; i < 8; ++i) {
        int f = t + i * 256;
        int node = f >> 5, q = f & 31;
        int ng = n0 + node; if (ng > N - 1) ng = N - 1;
        float4 v = ((const float4*)x)[(size_t)ng * 32 + q];
        *(float4*)&al[node * 132 + q * 4] = v;
    }
    __syncthreads();
    int colg = t & 15;   // cols colg*4..+3
    int rowg = t >> 4;   // rows rowg*4..+3
    float4 acc[4];
#pragma unroll
    for (int j = 0; j < 4; ++j) acc[j] = make_float4(0.f, 0.f, 0.f, 0.f);
    for (int k4 = 0; k4 < 128; k4 += 4) {
        float4 w0 = *(float4*)&wl[(k4 + 0) * 64 + colg * 4];
        float4 w1 = *(float4*)&wl[(k4 + 1) * 64 + colg * 4];
        float4 w2 = *(float4*)&wl[(k4 + 2) * 64 + colg * 4];
        float4 w3 = *(float4*)&wl[(k4 + 3) * 64 + colg * 4];
#pragma unroll
        for (int j = 0; j < 4; ++j) {
            float4 a = *(float4*)&al[(rowg * 4 + j) * 132 + k4];
            acc[j].x += a.x * w0.x + a.y * w1.x + a.z * w2.x + a.w * w3.x;
            acc[j].y += a.x * w0.y + a.y * w1.y + a.z * w2.y + a.w * w3.y;
            acc[j].z += a.x * w0.z + a.y * w1.z + a.z * w2.z + a.w * w3.z;
            acc[j].w += a.x * w0.w + a.y * w1.w + a.z * w2.w + a.w * w3.w;
        }
    }
    float4 bb = ((const float4*)b0)[colg];
#pragma unroll
    for (int j = 0; j < 4; ++j) {
        int n = n0 + rowg * 4 + j;
        if (n < N) {
            float rx = fmaxf(acc[j].x + bb.x, 0.f);
            float ry = fmaxf(acc[j].y + bb.y, 0.f);
            float rz = fmaxf(acc[j].z + bb.z, 0.f);
            float rw = fmaxf(acc[j].w + bb.w, 0.f);
            uint2 pr; pr.x = bfpack(rx, ry); pr.y = bfpack(rz, rw);
            ((uint2*)h0b)[(size_t)n * 16 + colg] = pr;  // 64 bf16 = 16 uint2/row
        }
    }
}

// h1 = h0 @ W1 (stored bf16) + fused att1 dots. h0b[N,64] bf16, W1[64,128].
__global__ __launch_bounds__(256) void k_gemm2(const unsigned* __restrict__ h0b,
                                               const float* __restrict__ W1,
                                               const float* __restrict__ as_g,
                                               const float* __restrict__ ad_g,
                                               ushort_t* __restrict__ h1b,
                                               float* __restrict__ as1,
                                               float* __restrict__ ad1, int N) {
    __shared__ float wl[64 * 128];  // [k][c]
    __shared__ float al[64 * 68];   // [node][k] padded
    int t = threadIdx.x;
    int n0 = blockIdx.x * 64;
    const float4* wg = (const float4*)W1;
    float4* wl4 = (float4*)wl;
#pragma unroll
    for (int i = 0; i < 8; ++i) wl4[t + i * 256] = wg[t + i * 256];
#pragma unroll
    for (int i = 0; i < 2; ++i) {
        int f = t + i * 256;          // 0..511
        int node = f >> 3, q = f & 7; // row = 32 uints = 8 uint4
        int ng = n0 + node; if (ng > N - 1) ng = N - 1;
        uint4 u = ((const uint4*)h0b)[(size_t)ng * 8 + q];
        float* dst = &al[node * 68 + q * 8];
        dst[0] = bflo(u.x); dst[1] = bfhi(u.x);
        dst[2] = bflo(u.y); dst[3] = bfhi(u.y);
        dst[4] = bflo(u.z); dst[5] = bfhi(u.z);
        dst[6] = bflo(u.w); dst[7] = bfhi(u.w);
    }
    __syncthreads();
    int colg = t & 31;   // cols colg*4..+3 (head = colg>=16)
    int rowg = t >> 5;   // rows rowg*8..+7
    float4 acc[8];
#pragma unroll
    for (int j = 0; j < 8; ++j) acc[j] = make_float4(0.f, 0.f, 0.f, 0.f);
    for (int k4 = 0; k4 < 64; k4 += 4) {
        float4 w0 = *(float4*)&wl[(k4 + 0) * 128 + colg * 4];
        float4 w1 = *(float4*)&wl[(k4 + 1) * 128 + colg * 4];
        float4 w2 = *(float4*)&wl[(k4 + 2) * 128 + colg * 4];
        float4 w3 = *(float4*)&wl[(k4 + 3) * 128 + colg * 4];
#pragma unroll
        for (int j = 0; j < 8; ++j) {
            float4 a = *(float4*)&al[(rowg * 8 + j) * 68 + k4];
            acc[j].x += a.x * w0.x + a.y * w1.x + a.z * w2.x + a.w * w3.x;
            acc[j].y += a.x * w0.y + a.y * w1.y + a.z * w2.y + a.w * w3.y;
            acc[j].z += a.x * w0.z + a.y * w1.z + a.z * w2.z + a.w * w3.z;
            acc[j].w += a.x * w0.w + a.y * w1.w + a.z * w2.w + a.w * w3.w;
        }
    }
    float4 asv = ((const float4*)as_g)[colg];
    float4 adv = ((const float4*)ad_g)[colg];
    float ps[8], pd[8];
#pragma unroll
    for (int j = 0; j < 8; ++j) {
        ps[j] = acc[j].x * asv.x + acc[j].y * asv.y + acc[j].z * asv.z + acc[j].w * asv.w;
        pd[j] = acc[j].x * adv.x + acc[j].y * adv.y + acc[j].z * adv.z + acc[j].w * adv.w;
    }
    for (int o = 1; o < 16; o <<= 1) {
#pragma unroll
        for (int j = 0; j < 8; ++j) {
            ps[j] += __shfl_xor(ps[j], o);
            pd[j] += __shfl_xor(pd[j], o);
        }
    }
#pragma unroll
    for (int j = 0; j < 8; ++j) {
        int n = n0 + rowg * 8 + j;
        if (n < N) {
            uint2 pr;
            pr.x = bfpack(acc[j].x, acc[j].y);
            pr.y = bfpack(acc[j].z, acc[j].w);
            ((uint2*)h1b)[(size_t)n * 32 + colg] = pr;  // 32 uint2 per row
        }
    }
    int lane = t & 63;
    if ((lane & 15) == 0) {
        int head = (lane >> 4) & 1;
#pragma unroll
        for (int j = 0; j < 8; ++j) {
            int n = n0 + rowg * 8 + j;
            if (n < N) {
                as1[n * 2 + head] = ps[j];
                ad1[n * 2 + head] = pd[j];
            }
        }
    }
}

// ---- layer-1 fused, v5: single-pass softmax (deg<=64), 4-edge dwordx4 loop ----
// lane = eg(2b) x fl(4b): eg = edge subgroup, fl = feature quad (8 bf16).
// head = fl>=8. stashA[head*64+edge] = (src bits, p=exp(e-m)) UNNORMALIZED;
// epilogue scales by 1/l (normalization is linear). Merge eg groups via
// shfl_xor(16/32). deg>64 slow path: two-pass with normalized alpha.
__global__ __launch_bounds__(256) void k_node_l1(const int* __restrict__ rs,
                                                 const int* __restrict__ csr,
                                                 const ushort_t* __restrict__ h1b,
                                                 const float* __restrict__ as1,
                                                 const float* __restrict__ ad1,
                                                 const float* __restrict__ b1,
                                                 unsigned* __restrict__ aggb, int N) {
    __shared__ float2 stashA[4][128];        // [wid][head*64+edge]
    __shared__ float4 stashE[4][STASH_CAP];  // slow path only
    int wid = threadIdx.x >> 6;
    int lane = threadIdx.x & 63;
    int n = (blockIdx.x * 256 + threadIdx.x) >> 6;
    if (n >= N) return;
    int row = rs[n], end = rs[n + 1];
    int deg = end - row;
    float2 adv = ((const float2*)ad1)[n];
    const float2* asp = (const float2*)as1;
    const char* h1base = (const char*)h1b;
    int eg = lane >> 4;                 // 0..3
    int fl = lane & 15;                 // 0..15
    int head_off = (fl >= 8) ? 64 : 0;
    int flbase = fl * 16;               // byte offset within 256B row
    float acc[8] = {0.f, 0.f, 0.f, 0.f, 0.f, 0.f, 0.f, 0.f};
    float inv0, inv1;
    if (deg <= 64) {
        // ---- fast path: single pass ----
        bool act = lane < deg;
        int src = act ? csr[row + lane] : 0;
        float2 av = asp[src];
        float e0 = av.x + adv.x, e1 = av.y + adv.y;
        e0 = e0 > 0.f ? e0 : NEG_SLOPE * e0;
        e1 = e1 > 0.f ? e1 : NEG_SLOPE * e1;
        if (!act) { e0 = -INFINITY; e1 = -INFINITY; }
        float m0 = wmax(e0), m1 = wmax(e1);
        float p0 = act ? __expf(e0 - m0) : 0.f;
        float p1 = act ? __expf(e1 - m1) : 0.f;
        inv0 = __builtin_amdgcn_rcpf(wsum(p0));
        inv1 = __builtin_amdgcn_rcpf(wsum(p1));
        stashA[wid][lane] = make_float2(__int_as_float(src), p0);
        stashA[wid][64 + lane] = make_float2(__int_as_float(src), p1);
        for (int j = 0; j < deg; j += 4) {   // j+eg <= 63; entries >= deg have p=0
            float2 sa = stashA[wid][head_off + j + eg];
            int sj = __float_as_int(sa.x);
            float aj = sa.y;
            uint4 u = *(const uint4*)(h1base + (((unsigned)sj) << 8) + flbase);
            acc[0] += bflo(u.x) * aj; acc[1] += bfhi(u.x) * aj;
            acc[2] += bflo(u.y) * aj; acc[3] += bfhi(u.y) * aj;
            acc[4] += bflo(u.z) * aj; acc[5] += bfhi(u.z) * aj;
            acc[6] += bflo(u.w) * aj; acc[7] += bfhi(u.w) * aj;
        }
    } else {
        // ---- slow path (deg>64; not taken on this input): two-pass ----
        inv0 = 1.f; inv1 = 1.f;  // stash holds normalized alpha
        float m0 = -INFINITY, m1 = -INFINITY, l0 = 0.f, l1 = 0.f;
        for (int base = row; base < end; base += 64) {
            int idx = base + lane;
            bool act = idx < end;
            int src = act ? csr[idx] : 0;
            float2 av = asp[src];
            float e0 = av.x + adv.x, e1 = av.y + adv.y;
            e0 = e0 > 0.f ? e0 : NEG_SLOPE * e0;
            e1 = e1 > 0.f ? e1 : NEG_SLOPE * e1;
            int sidx = idx - row;
            if (act && sidx < STASH_CAP)
                stashE[wid][sidx] = make_float4(__int_as_float(src), e0, e1, 0.f);
            if (!act) { e0 = -INFINITY; e1 = -INFINITY; }
            float m0n = fmaxf(m0, wmax(e0));
            float m1n = fmaxf(m1, wmax(e1));
            float p0 = act ? __expf(e0 - m0n) : 0.f;
            float p1 = act ? __expf(e1 - m1n) : 0.f;
            l0 = l0 * __expf(m0 - m0n) + wsum(p0);
            l1 = l1 * __expf(m1 - m1n) + wsum(p1);
            m0 = m0n; m1 = m1n;
        }
        float r0 = __builtin_amdgcn_rcpf(l0);
        float r1 = __builtin_amdgcn_rcpf(l1);
        for (int base = row; base < end; base += 64) {
            int idx = base + lane;
            bool act = idx < end;
            int sidx = idx - row;
            int src; float e0, e1;
            if (sidx < STASH_CAP) {
                float4 se = stashE[wid][sidx];
                src = __float_as_int(se.x);
                e0 = se.y; e1 = se.z;
            } else {
                src = act ? csr[idx] : 0;
                float2 av = asp[src];
                e0 = av.x + adv.x; e1 = av.y + adv.y;
                e0 = e0 > 0.f ? e0 : NEG_SLOPE * e0;
                e1 = e1 > 0.f ? e1 : NEG_SLOPE * e1;
            }
            if (!act) src = 0;  // mask garbage LDS src (address safety)
            float a0 = act ? __expf(e0 - m0) * r0 : 0.f;
            float a1 = act ? __expf(e1 - m1) * r1 : 0.f;
            stashA[wid][lane] = make_float2(__int_as_float(src), a0);
            stashA[wid][64 + lane] = make_float2(__int_as_float(src), a1);
            int cnt = min(64, end - base);
            for (int j = 0; j < cnt; j += 4) {
                float2 sa = stashA[wid][head_off + j + eg];
                int sj = __float_as_int(sa.x);
                float aj = sa.y;
                uint4 u = *(const uint4*)(h1base + (((unsigned)sj) << 8) + flbase);
                acc[0] += bflo(u.x) * aj; acc[1] += bfhi(u.x) * aj;
                acc[2] += bflo(u.y) * aj; acc[3] += bfhi(u.y) * aj;
                acc[4] += bflo(u.z) * aj; acc[5] += bfhi(u.z) * aj;
                acc[6] += bflo(u.w) * aj; acc[7] += bfhi(u.w) * aj;
            }
        }
    }
    // merge the 4 edge subgroups (eg = lane bits 4,5)
#pragma unroll
    for (int i = 0; i < 8; ++i) {
        acc[i] += __shfl_xor(acc[i], 16);
        acc[i] += __shfl_xor(acc[i], 32);
    }
    if (lane < 16) {
        float inv = (lane >= 8) ? inv1 : inv0;
        float4 ba = ((const float4*)b1)[lane * 2];
        float4 bb4 = ((const float4*)b1)[lane * 2 + 1];
        float v[8];
        v[0] = acc[0] * inv + ba.x;  v[1] = acc[1] * inv + ba.y;
        v[2] = acc[2] * inv + ba.z;  v[3] = acc[3] * inv + ba.w;
        v[4] = acc[4] * inv + bb4.x; v[5] = acc[5] * inv + bb4.y;
        v[6] = acc[6] * inv + bb4.z; v[7] = acc[7] * inv + bb4.w;
#pragma unroll
        for (int i = 0; i < 8; ++i) v[i] = v[i] > 0.f ? v[i] : __expf(v[i]) - 1.f;
        uint4 pk;
        pk.x = bfpack(v[0], v[1]); pk.y = bfpack(v[2], v[3]);
        pk.z = bfpack(v[4], v[5]); pk.w = bfpack(v[6], v[7]);
        ((uint4*)aggb)[(size_t)n * 16 + lane] = pk;
    }
}

// h2 = agg1 @ W2 (agg bf16 in, h2 bf16 out) + att2 dots. 64 nodes/block.
__global__ __launch_bounds__(256, 4) void k_node2(const unsigned* __restrict__ aggb,
                                                  const float* __restrict__ W2,
                                                  const float* __restrict__ as_g,
                                                  const float* __restrict__ ad_g,
                                                  ushort_t* __restrict__ h2b,
                                                  float* __restrict__ a_s,
                                                  float* __restrict__ a_d, int N) {
    __shared__ float al[64 * 132];   // [node][k] padded
    __shared__ float w2t[20 * 132];  // [c][k] padded, cols 18,19 zero
    int t = threadIdx.x;
    int n0 = blockIdx.x * 64;
#pragma unroll
    for (int i = 0; i < 4; ++i) {
        int f = t + i * 256;            // 0..1023
        int node = f >> 4, q = f & 15;  // row = 64 uints = 16 uint4
        int ng = n0 + node; if (ng > N - 1) ng = N - 1;
        uint4 u = ((const uint4*)aggb)[(size_t)ng * 16 + q];
        float* dst = &al[node * 132 + q * 8];
        dst[0] = bflo(u.x); dst[1] = bfhi(u.x);
        dst[2] = bflo(u.y); dst[3] = bfhi(u.y);
        dst[4] = bflo(u.z); dst[5] = bfhi(u.z);
        dst[6] = bflo(u.w); dst[7] = bfhi(u.w);
    }
    for (int i = t; i < 2560; i += 256) {
        int c = i >> 7, k = i & 127;
        w2t[c * 132 + k] = (c < 18) ? W2[k * 18 + c] : 0.f;
    }
    __syncthreads();
    int node = t >> 2;
    int cq = t & 3;
    int c0 = cq * 5;  // cols c0..c0+4 (cq==3: cols 15..19, 18/19 dead)
    int n = n0 + node;
    float acc[5] = {0.f, 0.f, 0.f, 0.f, 0.f};
#pragma unroll 2
    for (int k4 = 0; k4 < 128; k4 += 4) {
        float4 a = *(float4*)&al[node * 132 + k4];
#pragma unroll
        for (int i = 0; i < 5; ++i) {
            float4 w = *(float4*)&w2t[(c0 + i) * 132 + k4];
            acc[i] += a.x * w.x + a.y * w.y + a.z * w.z + a.w * w.w;
        }
    }
    float ps = 0.f, pd = 0.f;
#pragma unroll
    for (int i = 0; i < 5; ++i) {
        int c = c0 + i;
        float asv = (c < 18) ? as_g[c] : 0.f;
        float adv = (c < 18) ? ad_g[c] : 0.f;
        ps += acc[i] * asv;
        pd += acc[i] * adv;
    }
    ps += __shfl_xor(ps, 1); ps += __shfl_xor(ps, 2);
    pd += __shfl_xor(pd, 1); pd += __shfl_xor(pd, 2);
    if (n < N) {
#pragma unroll
        for (int i = 0; i < 5; ++i) {
            int c = c0 + i;
            if (c < 18) h2b[(size_t)n * 24 + c] = bf16of(acc[i]);
        }
        if (cq == 0) { a_s[n] = ps; a_d[n] = pd; }
    }
}

// ---- layer-2 fused, v4: single-pass (deg<=64) stash p; phase B no exp ----
__global__ __launch_bounds__(256) void k_node_l2(const int* __restrict__ rs,
                                                 const int* __restrict__ csr,
                                                 const ushort_t* __restrict__ h2b,
                                                 const float* __restrict__ as2,
                                                 const float* __restrict__ ad2,
                                                 const float* __restrict__ b2,
                                                 float* __restrict__ out, int N) {
    __shared__ float2 stash[4][STASH_CAP];  // fast: (src,p); slow: (src,e)
    int wid = threadIdx.x >> 6;
    int lane = threadIdx.x & 63;
    int n = (blockIdx.x * 256 + threadIdx.x) >> 6;
    if (n >= N) return;
    int row = rs[n], end = rs[n + 1];
    int deg = end - row;
    float adn = ad2[n];
    int g = lane / 21;            // 0..3 (lane 63 -> g=3, acc discarded)
    int c = lane - g * 21;        // 0..20
    int cc = c < 18 ? c : 17;     // clamp for safe loads
    float acc = 0.f;
    float post;
    if (deg <= 64) {
        // ---- fast: single pass, unnormalized p; scale after group-sum ----
        bool act = lane < deg;
        int src = act ? csr[row + lane] : 0;
        float e = as2[src] + adn;
        e = e > 0.f ? e : NEG_SLOPE * e;
        if (!act) e = -INFINITY;
        float m = wmax(e);
        float p = act ? __expf(e - m) : 0.f;
        post = __builtin_amdgcn_rcpf(wsum(p));
        stash[wid][lane] = make_float2(__int_as_float(src), p);
        for (int o = g; o < deg; o += 3) {
            float2 se = stash[wid][o];
            int src2 = __float_as_int(se.x);
            acc += se.y * bfval(h2b[(size_t)src2 * 24 + cc]);
        }
    } else {
        // ---- slow path (deg>64; not taken on this input) ----
        post = 1.f;
        float m = -INFINITY, l = 0.f;
        for (int base = row; base < end; base += 64) {
            int idx = base + lane;
            bool act = idx < end;
            int src = act ? csr[idx] : 0;
            float e = as2[src] + adn;
            e = e > 0.f ? e : NEG_SLOPE * e;
            int sidx = idx - row;
            if (act && sidx < STASH_CAP)
                stash[wid][sidx] = make_float2(__int_as_float(src), e);
            if (!act) e = -INFINITY;
            float mn = fmaxf(m, wmax(e));
            float p = act ? __expf(e - mn) : 0.f;
            l = l * __expf(m - mn) + wsum(p);
            m = mn;
        }
        float invl = __builtin_amdgcn_rcpf(l);
        int lim = deg < STASH_CAP ? deg : STASH_CAP;
        for (int o = g; o < lim; o += 3) {
            float2 se = stash[wid][o];
            int src = __float_as_int(se.x);
            float alpha = __expf(se.y - m) * invl;
            acc += alpha * bfval(h2b[(size_t)src * 24 + cc]);
        }
        for (int pos = row + STASH_CAP + g; pos < end; pos += 3) {
            int src = csr[pos];
            float e = as2[src] + adn;
            e = e > 0.f ? e : NEG_SLOPE * e;
            float alpha = __expf(e - m) * invl;
            acc += alpha * bfval(h2b[(size_t)src * 24 + cc]);
        }
    }
    // group-sum into lanes 0..17: both shfls read pre-mutation acc
    float t1 = __shfl(acc, (lane + 21) & 63);
    float t2 = __shfl(acc, (lane + 42) & 63);
    acc += t1 + t2;
    float bb = (lane < 18) ? b2[lane] : 0.f;
    float v = acc * post + bb;
    // ---- lane-parallel log-softmax over lanes 0..17 (32-lane xor net) ----
    float tmx = (lane < 18) ? v : -INFINITY;
    for (int o = 16; o; o >>= 1) tmx = fmaxf(tmx, __shfl_xor(tmx, o));
    float s = (lane < 18) ? __expf(v - tmx) : 0.f;
    for (int o = 16; o; o >>= 1) s += __shfl_xor(s, o);
    float lse = tmx + __logf(s);
    if (lane < 18) out[(size_t)n * 18 + lane] = v - lse;
}

extern "C" void kernel_launch(void* const* d_in, const int* in_sizes, int n_in,
                              void* d_out, int out_size, void* d_ws, size_t ws_size,
                              hipStream_t stream) {
    const float* x      = (const float*)d_in[0];
    const int*   ei     = (const int*)d_in[1];
    const float* W0     = (const float*)d_in[2];
    const float* b0     = (const float*)d_in[3];
    const float* W1     = (const float*)d_in[4];
    const float* att_s1 = (const float*)d_in[5];
    const float* att_d1 = (const float*)d_in[6];
    const float* b1     = (const float*)d_in[7];
    const float* W2     = (const float*)d_in[8];
    const float* att_s2 = (const float*)d_in[9];
    const float* att_d2 = (const float*)d_in[10];
    const float* b2     = (const float*)d_in[11];

    const int N = in_sizes[0] / 128;
    const int E = in_sizes[1] / 2;
    const int Etot = E + N;
    const int NB = (N + 1023) / 1024;  // scan blocks (<= 256)
    const int NBLK = (N + 63) / 64;    // dense tiles

    // workspace carve-up (~100 MB)
    char* w = (char*)d_ws;
    unsigned* h0b  = (unsigned*)w; w += (size_t)N * 64 * 2;   // bf16 x 64
    ushort_t* h1b  = (ushort_t*)w; w += (size_t)N * 128 * 2;
    unsigned* aggb = (unsigned*)w; w += (size_t)N * 128 * 2;  // bf16 x 128
    float* as1     = (float*)w;    w += (size_t)N * 2 * 4;
    float* ad1     = (float*)w;    w += (size_t)N * 2 * 4;
    ushort_t* h2b  = (ushort_t*)w; w += (size_t)N * 24 * 2;
    float* as2     = (float*)w;    w += (size_t)N * 4;
    float* ad2     = (float*)w;    w += (size_t)N * 4;
    int* deg       = (int*)w;      w += (size_t)N * 4;
    int* rs        = (int*)w;      w += (size_t)(N + 1) * 4;
    int* bsum      = (int*)w;      w += (size_t)256 * 4;
    int* boff      = (int*)w;      w += (size_t)256 * 4;
    int* eofs      = (int*)w;      w += (size_t)E * 4;
    int* csr       = (int*)w;      w += (size_t)Etot * 4;

    float* out = (float*)d_out;

    // ---- CSR build ----
    k_deg_init<<<(N + 255) / 256, 256, 0, stream>>>(deg, N);
    k_deg_edges<<<(E + 255) / 256, 256, 0, stream>>>(ei, deg, eofs, E);
    k_scan1<<<NB, 256, 0, stream>>>(deg, rs, bsum, N);
    k_scan2<<<1, 256, 0, stream>>>(bsum, boff, NB);
    k_scan3<<<(N + 255) / 256, 256, 0, stream>>>(rs, boff, N);
    const int cohortBlocks = 128;
    k_scatter<<<8 * cohortBlocks, 256, 0, stream>>>(ei, eofs, rs, csr, E, Etot, cohortBlocks);

    // ---- dense ----
    k_gemm1<<<NBLK, 256, 0, stream>>>(x, W0, b0, h0b, N);
    k_gemm2<<<NBLK, 256, 0, stream>>>(h0b, W1, att_s1, att_d1, h1b, as1, ad1, N);

    // ---- layer 1 fused edge pass ----
    k_node_l1<<<(N * 64 + 255) / 256, 256, 0, stream>>>(rs, csr, h1b, as1, ad1, b1, aggb, N);

    // ---- layer 2 dense + fused edge pass ----
    k_node2<<<NBLK, 256, 0, stream>>>(aggb, W2, att_s2, att_d2, h2b, as2, ad2, N);
    k_node_l2<<<(N * 64 + 255) / 256, 256, 0, stream>>>(rs, csr, h2b, as2, ad2, b2, out, N);
}